// Round 2
// baseline (1181.504 us; speedup 1.0000x reference)
//
#include <hip/hip_runtime.h>
#include <hip/hip_bf16.h>
#include <cstddef>

// FFTformer block. FFTs reduced to 8x8 circular convolutions.
// B=2, d=48, H=W=256, P=8. fp32 compute, bf16 storage for big intermediates.
// Workspace layout (bytes):
//   [0,          75,497,472)  qkv bf16 [2,288,256,256]   -> later z bf16
//   [75,497,472, 100,663,296) hidden_chunk bf16 [2,96,HW] -> later out96 bf16
//   [100,663,296,125,829,120) X1 fp32 [2,48,HW]
//   [125,829,120,125,902,848) S fp32 [288,64]
// Peak ~126 MB.

constexpr int HWC = 65536;   // 256*256

__device__ inline unsigned short f2bf(float f) {
  __hip_bfloat16 h = __float2bfloat16(f);
  return *reinterpret_cast<unsigned short*>(&h);
}
__device__ inline float bf2f(unsigned short u) {
  __hip_bfloat16 h;
  *reinterpret_cast<unsigned short*>(&h) = u;
  return __bfloat162float(h);
}

// ---------------------------------------------------------------------------
// K1: per-pixel LayerNorm(48) + conv1x1 (48 -> 96 chunk). Thread = pixel.
__global__ __launch_bounds__(256) void k_ln_conv48(
    const float* __restrict__ x, const float* __restrict__ nw,
    const float* __restrict__ nb, const float* __restrict__ w,
    unsigned short* __restrict__ out) {
  int tid = threadIdx.x;
  long pix = (long)blockIdx.x * 256 + tid;     // 0..131071
  int b = (int)(pix >> 16);
  int hw = (int)(pix & 65535);
  const float* xp = x + (size_t)b * 48 * HWC + hw;
  float r[48];
  float s = 0.f, s2 = 0.f;
#pragma unroll
  for (int c = 0; c < 48; c++) {
    float v = xp[(size_t)c * HWC];
    r[c] = v; s += v; s2 += v * v;
  }
  float mu = s * (1.f / 48.f);
  float var = s2 * (1.f / 48.f) - mu * mu;
  float inv = rsqrtf(var + 1e-5f);
#pragma unroll
  for (int c = 0; c < 48; c++) r[c] = (r[c] - mu) * inv * nw[c] + nb[c];
  unsigned short* op = out + (size_t)b * 96 * HWC + hw;
  for (int o = 0; o < 96; o++) {
    const float* wo = w + (size_t)o * 48;
    float acc = 0.f;
#pragma unroll
    for (int c = 0; c < 48; c++) acc += r[c] * wo[c];
    op[(size_t)o * HWC] = f2bf(acc);
  }
}

// ---------------------------------------------------------------------------
// K2: depthwise 3x3, SAME zero pad, on a 96-channel chunk.
// Block = (b, c, 4-row band). 256 threads = W.
__global__ __launch_bounds__(256) void k_dwconv3(
    const unsigned short* __restrict__ in, const float* __restrict__ dw,
    unsigned short* __restrict__ out, int c_base) {
  __shared__ float rows[6][256];
  int tid = threadIdx.x;
  unsigned bid = blockIdx.x;
  int y0 = (int)(bid & 63) * 4;
  unsigned t = bid >> 6;
  int c = (int)(t % 96u);
  int b = (int)(t / 96u);
  const unsigned short* ip = in + ((size_t)(b * 96 + c)) * HWC;
  float wv[9];
#pragma unroll
  for (int k = 0; k < 9; k++) wv[k] = dw[(c_base + c) * 9 + k];
#pragma unroll
  for (int r = 0; r < 6; r++) {
    int yy = y0 + r - 1;
    rows[r][tid] = (yy >= 0 && yy < 256) ? bf2f(ip[yy * 256 + tid]) : 0.f;
  }
  __syncthreads();
  unsigned short* op = out + ((size_t)(b * 288 + c_base + c)) * HWC;
#pragma unroll
  for (int r = 0; r < 4; r++) {
    float acc = 0.f;
#pragma unroll
    for (int dy = 0; dy < 3; dy++) {
      const float* rw = rows[r + dy];
      float xm = (tid > 0) ? rw[tid - 1] : 0.f;
      float xc = rw[tid];
      float xq = (tid < 255) ? rw[tid + 1] : 0.f;
      acc += xm * wv[dy * 3] + xc * wv[dy * 3 + 1] + xq * wv[dy * 3 + 2];
    }
    op[(y0 + r) * 256 + tid] = f2bf(acc);
  }
}

// ---------------------------------------------------------------------------
// K3: FSAS spectral == per-patch 8x8 circular convolution q (*) k.
// Block = (b, c, patch-row py): 32 patches. Thread = (patch px, out row a).
__global__ __launch_bounds__(256) void k_fsas_patchconv(
    const unsigned short* __restrict__ qkv, unsigned short* __restrict__ out) {
  __shared__ float qs[8][266];
  __shared__ float ks[8][266];
  int tid = threadIdx.x;
  unsigned bid = blockIdx.x;                 // b*96*32 + c*32 + py
  int py = (int)(bid & 31);
  int c = (int)((bid >> 5) % 96u);
  int b = (int)((bid >> 5) / 96u);
  const unsigned short* qp = qkv + ((size_t)(b * 288 + c)) * HWC + py * 8 * 256;
  const unsigned short* kp = qkv + ((size_t)(b * 288 + 96 + c)) * HWC + py * 8 * 256;
#pragma unroll
  for (int it = 0; it < 8; it++) {
    int idx = it * 256 + tid;
    int i = idx >> 8, xx = idx & 255;
    qs[i][xx] = bf2f(qp[i * 256 + xx]);
    ks[i][xx] = bf2f(kp[i * 256 + xx]);
  }
  __syncthreads();
  int p = tid >> 3, a = tid & 7;
  float acc[8];
#pragma unroll
  for (int j = 0; j < 8; j++) acc[j] = 0.f;
#pragma unroll
  for (int i = 0; i < 8; i++) {
    float q8[8], k8[8];
#pragma unroll
    for (int j = 0; j < 8; j++) q8[j] = qs[i][p * 8 + j];
    int ar = (a - i) & 7;
#pragma unroll
    for (int j = 0; j < 8; j++) k8[j] = ks[ar][p * 8 + j];
#pragma unroll
    for (int j = 0; j < 8; j++)
#pragma unroll
      for (int bb = 0; bb < 8; bb++) acc[bb] += q8[j] * k8[(bb - j) & 7];
  }
  unsigned short* op =
      out + ((size_t)(b * 96 + c)) * HWC + (py * 8 + a) * 256 + p * 8;
  union { unsigned short us[8]; uint4 v; } pk;
#pragma unroll
  for (int j = 0; j < 8; j++) pk.us[j] = f2bf(acc[j]);
  *reinterpret_cast<uint4*>(op) = pk.v;   // 16B aligned: p*8 elements * 2B
}

// ---------------------------------------------------------------------------
// K4: LN(96) + v-gate + conv1x1(48x96) + residual. Thread = pixel.
__global__ __launch_bounds__(256) void k_attn_out(
    const unsigned short* __restrict__ conv96,
    const unsigned short* __restrict__ qkv, const float* __restrict__ x,
    const float* __restrict__ nw, const float* __restrict__ nb,
    const float* __restrict__ wout, float* __restrict__ x1) {
  int tid = threadIdx.x;
  long pix = (long)blockIdx.x * 256 + tid;
  int b = (int)(pix >> 16);
  int hw = (int)(pix & 65535);
  const unsigned short* cp = conv96 + (size_t)b * 96 * HWC + hw;
  const unsigned short* vp = qkv + ((size_t)(b * 288) + 192) * HWC + hw;
  float t[96];
  float s = 0.f, s2 = 0.f;
#pragma unroll
  for (int c = 0; c < 96; c++) {
    float u = bf2f(cp[(size_t)c * HWC]);
    t[c] = u; s += u; s2 += u * u;
  }
  float mu = s * (1.f / 96.f);
  float var = s2 * (1.f / 96.f) - mu * mu;
  float inv = rsqrtf(var + 1e-5f);
#pragma unroll
  for (int c = 0; c < 96; c++)
    t[c] = ((t[c] - mu) * inv * nw[c] + nb[c]) * bf2f(vp[(size_t)c * HWC]);
  const float* xp = x + (size_t)b * 48 * HWC + hw;
  float* op = x1 + (size_t)b * 48 * HWC + hw;
  for (int o = 0; o < 48; o++) {
    const float* wo = wout + o * 96;
    float acc = 0.f;
#pragma unroll
    for (int c = 0; c < 96; c++) acc += t[c] * wo[c];
    op[(size_t)o * HWC] = xp[(size_t)o * HWC] + acc;
  }
}

// ---------------------------------------------------------------------------
// K5: spatial kernels s[c][8][8] = irfft2(ffn_fft[c]), numpy c2r semantics:
// v=0,4 columns symmetrized in u (c2r drops their imaginary part).
__device__ const float c_cos8[8] = {
    1.f, 0.70710678118654752f, 0.f, -0.70710678118654752f,
    -1.f, -0.70710678118654752f, 0.f, 0.70710678118654752f};

__global__ __launch_bounds__(64) void k_make_skernel(
    const float* __restrict__ fftw, float* __restrict__ s) {
  int c = blockIdx.x;
  int a = threadIdx.x >> 3, b2 = threadIdx.x & 7;
  const float* W = fftw + c * 40;  // [8][5]
  float acc = 0.f;
  for (int u = 0; u < 8; u++) {
    for (int v = 0; v < 8; v++) {
      float wv;
      if (v <= 4) {
        if (v == 0 || v == 4)
          wv = 0.5f * (W[u * 5 + v] + W[((8 - u) & 7) * 5 + v]);
        else
          wv = W[u * 5 + v];
      } else {
        wv = W[((8 - u) & 7) * 5 + (8 - v)];
      }
      acc += wv * c_cos8[(u * a + v * b2) & 7];
    }
  }
  s[c * 64 + a * 8 + b2] = acc * (1.f / 64.f);
}

// ---------------------------------------------------------------------------
// K6: LN(48) + conv1x1(288x48) + per-patch circular conv with s_c, fused.
// Tile 16x16 px (2x2 patches, no halo needed). Phase A: 8 out-ch into LDS.
// Phase B: thread = (ch, patch, row) row-register spectral conv -> z bf16.
__global__ __launch_bounds__(256) void k_ffn_spectral(
    const float* __restrict__ x1, const float* __restrict__ nw,
    const float* __restrict__ nb, const float* __restrict__ win,
    const float* __restrict__ sk, unsigned short* __restrict__ z) {
  __shared__ float ys[8][264];
  __shared__ float ss[8][66];
  int tid = threadIdx.x;
  unsigned bid = blockIdx.x;                  // b*256 + ty*16 + tx
  int tx = (int)(bid & 15), ty = (int)((bid >> 4) & 15), b = (int)(bid >> 8);
  int y0 = ty * 16, x0 = tx * 16;
  int ly = tid >> 4, lx = tid & 15;
  size_t pixoff = (size_t)(y0 + ly) * 256 + x0 + lx;
  const float* xp = x1 + (size_t)b * 48 * HWC + pixoff;
  float r[48];
  float s = 0.f, s2 = 0.f;
#pragma unroll
  for (int c = 0; c < 48; c++) {
    float u = xp[(size_t)c * HWC];
    r[c] = u; s += u; s2 += u * u;
  }
  float mu = s * (1.f / 48.f);
  float var = s2 * (1.f / 48.f) - mu * mu;
  float inv = rsqrtf(var + 1e-5f);
#pragma unroll
  for (int c = 0; c < 48; c++) r[c] = (r[c] - mu) * inv * nw[c] + nb[c];

  int ch = tid >> 5, rem = tid & 31, pp = rem >> 3, a = rem & 7;
  int pr = pp >> 1, pc = pp & 1;
  int rowbase = pr * 128 + pc * 8;            // + i*16 within ys[ch]
  unsigned short* zbase = z + (size_t)b * 288 * HWC +
                          (size_t)(y0 + pr * 8 + a) * 256 + x0 + pc * 8;

  for (int o0 = 0; o0 < 288; o0 += 8) {
    __syncthreads();                           // prev phase B done
#pragma unroll
    for (int oc = 0; oc < 8; oc++) {
      const float* wo = win + (size_t)(o0 + oc) * 48;
      float acc = 0.f;
#pragma unroll
      for (int c = 0; c < 48; c++) acc += r[c] * wo[c];
      ys[oc][tid] = acc;
    }
    for (int idx = tid; idx < 512; idx += 256) {
      int k = idx >> 6, j = idx & 63;
      ss[k][j] = sk[(size_t)(o0 + k) * 64 + j];
    }
    __syncthreads();
    float zacc[8];
#pragma unroll
    for (int j = 0; j < 8; j++) zacc[j] = 0.f;
#pragma unroll
    for (int i = 0; i < 8; i++) {
      float y8[8], s8[8];
#pragma unroll
      for (int j = 0; j < 8; j++) y8[j] = ys[ch][rowbase + i * 16 + j];
      int ar = (a - i) & 7;
#pragma unroll
      for (int j = 0; j < 8; j++) s8[j] = ss[ch][ar * 8 + j];
#pragma unroll
      for (int j = 0; j < 8; j++)
#pragma unroll
        for (int bb = 0; bb < 8; bb++) zacc[bb] += y8[j] * s8[(bb - j) & 7];
    }
    union { unsigned short us[8]; uint4 v; } pk;
#pragma unroll
    for (int bb = 0; bb < 8; bb++) pk.us[bb] = f2bf(zacc[bb]);
    *reinterpret_cast<uint4*>(zbase + (size_t)(o0 + ch) * HWC) = pk.v;
  }
}

// ---------------------------------------------------------------------------
// K7: dwconv3 + exact GELU gate + conv1x1(48x144) + residual. Tile 16x16,
// halo 18x18, 8 channel-pairs per LDS chunk, acc[48] in registers.
__global__ __launch_bounds__(256) void k_ffn_out(
    const unsigned short* __restrict__ z, const float* __restrict__ dwf,
    const float* __restrict__ wout, const float* __restrict__ x1,
    float* __restrict__ out) {
  __shared__ float zs[16][326];
  int tid = threadIdx.x;
  unsigned bid = blockIdx.x;
  int tx = (int)(bid & 15), ty = (int)((bid >> 4) & 15), b = (int)(bid >> 8);
  int y0 = ty * 16, x0 = tx * 16;
  int ly = tid >> 4, lx = tid & 15;
  float acc[48];
#pragma unroll
  for (int o = 0; o < 48; o++) acc[o] = 0.f;
  for (int cc = 0; cc < 18; cc++) {
    __syncthreads();
#pragma unroll
    for (int k = 0; k < 16; k++) {
      int c = (k < 8) ? (cc * 8 + k) : (144 + cc * 8 + (k - 8));
      const unsigned short* zp = z + ((size_t)(b * 288 + c)) * HWC;
      for (int pos = tid; pos < 324; pos += 256) {
        int py = pos / 18, px = pos - py * 18;
        int gy = y0 + py - 1, gx = x0 + px - 1;
        float v = 0.f;
        if (gy >= 0 && gy < 256 && gx >= 0 && gx < 256)
          v = bf2f(zp[gy * 256 + gx]);
        zs[k][pos] = v;
      }
    }
    __syncthreads();
#pragma unroll
    for (int k = 0; k < 8; k++) {
      int c1 = cc * 8 + k;
      float d1 = 0.f, d2 = 0.f;
#pragma unroll
      for (int dy = 0; dy < 3; dy++)
#pragma unroll
        for (int dx = 0; dx < 3; dx++) {
          float w1 = dwf[c1 * 9 + dy * 3 + dx];
          float w2 = dwf[(c1 + 144) * 9 + dy * 3 + dx];
          d1 += zs[k][(ly + dy) * 18 + lx + dx] * w1;
          d2 += zs[8 + k][(ly + dy) * 18 + lx + dx] * w2;
        }
      float g = 0.5f * d1 * (1.f + erff(d1 * 0.70710678118654752f)) * d2;
#pragma unroll
      for (int o = 0; o < 48; o++) acc[o] += g * wout[o * 144 + c1];
    }
  }
  size_t pixoff = (size_t)(y0 + ly) * 256 + x0 + lx;
  const float* xp = x1 + (size_t)b * 48 * HWC + pixoff;
  float* op = out + (size_t)b * 48 * HWC + pixoff;
#pragma unroll
  for (int o = 0; o < 48; o++) op[(size_t)o * HWC] = xp[(size_t)o * HWC] + acc[o];
}

// ---------------------------------------------------------------------------
extern "C" void kernel_launch(void* const* d_in, const int* in_sizes, int n_in,
                              void* d_out, int out_size, void* d_ws,
                              size_t ws_size, hipStream_t stream) {
  (void)in_sizes; (void)n_in; (void)out_size; (void)ws_size;
  const float* x   = (const float*)d_in[0];
  const float* n1w = (const float*)d_in[1];
  const float* n1b = (const float*)d_in[2];
  const float* awh = (const float*)d_in[3];   // [288,48]
  const float* adw = (const float*)d_in[4];   // [288,1,3,3]
  const float* anw = (const float*)d_in[5];   // [96]
  const float* anb = (const float*)d_in[6];
  const float* awo = (const float*)d_in[7];   // [48,96]
  const float* n2w = (const float*)d_in[8];
  const float* n2b = (const float*)d_in[9];
  const float* fwi = (const float*)d_in[10];  // [288,48]
  const float* fff = (const float*)d_in[11];  // [288,1,1,8,5]
  const float* fdw = (const float*)d_in[12];  // [288,1,3,3]
  const float* fwo = (const float*)d_in[13];  // [48,144]

  unsigned short* QKV  = (unsigned short*)d_ws;                        // 75.5 MB
  unsigned short* REG2 = (unsigned short*)((char*)d_ws + 75497472);    // 25.2 MB
  float*          X1   = (float*)((char*)d_ws + 100663296);            // 25.2 MB
  float*          S    = (float*)((char*)d_ws + 125829120);            // 73 KB

  // FSAS: LN1 + conv1x1 + dwconv3, chunked 3x96 channels through REG2.
  for (int chunk = 0; chunk < 3; chunk++) {
    k_ln_conv48<<<512, 256, 0, stream>>>(x, n1w, n1b, awh + chunk * 96 * 48,
                                         REG2);
    k_dwconv3<<<2 * 96 * 64, 256, 0, stream>>>(REG2, adw, QKV, chunk * 96);
  }
  k_fsas_patchconv<<<2 * 96 * 32, 256, 0, stream>>>(QKV, REG2);
  k_attn_out<<<512, 256, 0, stream>>>(REG2, QKV, x, anw, anb, awo, X1);
  // DFFN
  k_make_skernel<<<288, 64, 0, stream>>>(fff, S);
  k_ffn_spectral<<<512, 256, 0, stream>>>(X1, n2w, n2b, fwi, S, QKV);
  k_ffn_out<<<512, 256, 0, stream>>>(QKV, fdw, fwo, X1, (float*)d_out);
}

// Round 3
// 639.959 us; speedup vs baseline: 1.8462x; 1.8462x over previous
//
#include <hip/hip_runtime.h>
#include <hip/hip_bf16.h>
#include <cstddef>

// FFTformer block. FFTs reduced to 8x8 circular convolutions.
// B=2, d=48, H=W=256, P=8. fp32 compute, bf16 storage for intermediates.
// Workspace layout (bytes), peak ~126 MB (same footprint as passing run):
//   [0,          75,497,472)  QKV bf16 [2,288,HW]  (qkv -> y -> z, in-place)
//   [75,497,472, 100,663,296) U   bf16 [2,96,HW]   (hidden chunk -> out96 -> u -> g[0:96))
//   [100,663,296,113,246,208) X1  bf16 [2,48,HW]
//   [113,246,208,125,829,120) G2  bf16 [2,48,HW]   (g[96:144))
//   [125,829,120,125,902,848) S   fp32 [288,64]

constexpr int HWC = 65536;   // 256*256

__device__ inline unsigned short f2bf(float f) {
  __hip_bfloat16 h = __float2bfloat16(f);
  return *reinterpret_cast<unsigned short*>(&h);
}
__device__ inline float bf2f(unsigned short u) {
  __hip_bfloat16 h;
  *reinterpret_cast<unsigned short*>(&h) = u;
  return __bfloat162float(h);
}

// ---------------------------------------------------------------------------
// K1: LayerNorm(48) + conv1x1 (48 -> 48 of the 96-chunk). Thread = pixel.
// Grid 1024: bit9 selects which half of the 96 chunk outputs this block does.
__global__ __launch_bounds__(256) void k_ln_conv48b(
    const float* __restrict__ x, const float* __restrict__ nw,
    const float* __restrict__ nb, const float* __restrict__ w,
    unsigned short* __restrict__ out) {
  int tid = threadIdx.x;
  unsigned bid = blockIdx.x;
  int half = (int)(bid >> 9);
  long pix = (long)(bid & 511) * 256 + tid;
  int b = (int)(pix >> 16);
  int hw = (int)(pix & 65535);
  const float* xp = x + (size_t)b * 48 * HWC + hw;
  float r[48];
  float s = 0.f, s2 = 0.f;
#pragma unroll
  for (int c = 0; c < 48; c++) {
    float v = xp[(size_t)c * HWC];
    r[c] = v; s += v; s2 += v * v;
  }
  float mu = s * (1.f / 48.f);
  float var = s2 * (1.f / 48.f) - mu * mu;
  float inv = rsqrtf(var + 1e-5f);
#pragma unroll
  for (int c = 0; c < 48; c++) r[c] = (r[c] - mu) * inv * nw[c] + nb[c];
  unsigned short* op = out + ((size_t)(b * 96) + half * 48) * HWC + hw;
  for (int o = 0; o < 48; o++) {
    const float* wo = w + (size_t)(half * 48 + o) * 48;
    float acc = 0.f;
#pragma unroll
    for (int c = 0; c < 48; c++) acc += r[c] * wo[c];
    op[(size_t)o * HWC] = f2bf(acc);
  }
}

// ---------------------------------------------------------------------------
// K2: depthwise 3x3 SAME on a 96-channel chunk. Block=(b,c,4-row band).
__global__ __launch_bounds__(256) void k_dwconv3(
    const unsigned short* __restrict__ in, const float* __restrict__ dw,
    unsigned short* __restrict__ out, int c_base) {
  __shared__ float rows[6][256];
  int tid = threadIdx.x;
  unsigned bid = blockIdx.x;
  int y0 = (int)(bid & 63) * 4;
  unsigned t = bid >> 6;
  int c = (int)(t % 96u);
  int b = (int)(t / 96u);
  const unsigned short* ip = in + ((size_t)(b * 96 + c)) * HWC;
  float wv[9];
#pragma unroll
  for (int k = 0; k < 9; k++) wv[k] = dw[(c_base + c) * 9 + k];
#pragma unroll
  for (int r = 0; r < 6; r++) {
    int yy = y0 + r - 1;
    rows[r][tid] = (yy >= 0 && yy < 256) ? bf2f(ip[yy * 256 + tid]) : 0.f;
  }
  __syncthreads();
  unsigned short* op = out + ((size_t)(b * 288 + c_base + c)) * HWC;
#pragma unroll
  for (int r = 0; r < 4; r++) {
    float acc = 0.f;
#pragma unroll
    for (int dy = 0; dy < 3; dy++) {
      const float* rw = rows[r + dy];
      float xm = (tid > 0) ? rw[tid - 1] : 0.f;
      float xc = rw[tid];
      float xq = (tid < 255) ? rw[tid + 1] : 0.f;
      acc += xm * wv[dy * 3] + xc * wv[dy * 3 + 1] + xq * wv[dy * 3 + 2];
    }
    op[(y0 + r) * 256 + tid] = f2bf(acc);
  }
}

// ---------------------------------------------------------------------------
// K3: FSAS spectral == per-patch 8x8 circular convolution q (*) k.
// Block = (b, c, patch-row py). Thread = (patch px, out row a).
__global__ __launch_bounds__(256) void k_fsas_patchconv(
    const unsigned short* __restrict__ qkv, unsigned short* __restrict__ out) {
  __shared__ float qs[8][266];
  __shared__ float ks[8][266];
  int tid = threadIdx.x;
  unsigned bid = blockIdx.x;                 // b*96*32 + c*32 + py
  int py = (int)(bid & 31);
  int c = (int)((bid >> 5) % 96u);
  int b = (int)((bid >> 5) / 96u);
  const unsigned short* qp = qkv + ((size_t)(b * 288 + c)) * HWC + py * 2048;
  const unsigned short* kp =
      qkv + ((size_t)(b * 288 + 96 + c)) * HWC + py * 2048;
#pragma unroll
  for (int it = 0; it < 8; it++) {
    int idx = it * 256 + tid;
    int i = idx >> 8, xx = idx & 255;
    qs[i][xx] = bf2f(qp[i * 256 + xx]);
    ks[i][xx] = bf2f(kp[i * 256 + xx]);
  }
  __syncthreads();
  int p = tid >> 3, a = tid & 7;
  float acc[8];
#pragma unroll
  for (int j = 0; j < 8; j++) acc[j] = 0.f;
#pragma unroll
  for (int i = 0; i < 8; i++) {
    float q8[8], k8[8];
#pragma unroll
    for (int j = 0; j < 8; j++) q8[j] = qs[i][p * 8 + j];
    int ar = (a - i) & 7;
#pragma unroll
    for (int j = 0; j < 8; j++) k8[j] = ks[ar][p * 8 + j];
#pragma unroll
    for (int j = 0; j < 8; j++)
#pragma unroll
      for (int bb = 0; bb < 8; bb++) acc[bb] += q8[j] * k8[(bb - j) & 7];
  }
  unsigned short* op =
      out + ((size_t)(b * 96 + c)) * HWC + (py * 8 + a) * 256 + p * 8;
  union { unsigned short us[8]; uint4 v; } pk;
#pragma unroll
  for (int j = 0; j < 8; j++) pk.us[j] = f2bf(acc[j]);
  *reinterpret_cast<uint4*>(op) = pk.v;
}

// ---------------------------------------------------------------------------
// K4a: LN(96) + v-gate, IN-PLACE on u (per-thread read-then-write, safe).
__global__ __launch_bounds__(256) void k_attn_gate(
    unsigned short* u, const unsigned short* __restrict__ qkv,
    const float* __restrict__ nw, const float* __restrict__ nb) {
  int tid = threadIdx.x;
  long pix = (long)blockIdx.x * 256 + tid;
  int b = (int)(pix >> 16);
  int hw = (int)(pix & 65535);
  unsigned short* cp = u + (size_t)b * 96 * HWC + hw;
  const unsigned short* vp = qkv + ((size_t)(b * 288) + 192) * HWC + hw;
  float t[96];
  float s = 0.f, s2 = 0.f;
#pragma unroll
  for (int c = 0; c < 96; c++) {
    float v = bf2f(cp[(size_t)c * HWC]);
    t[c] = v; s += v; s2 += v * v;
  }
  float mu = s * (1.f / 96.f);
  float var = s2 * (1.f / 96.f) - mu * mu;
  float inv = rsqrtf(var + 1e-5f);
#pragma unroll
  for (int c = 0; c < 96; c++) {
    float g = ((t[c] - mu) * inv * nw[c] + nb[c]) * bf2f(vp[(size_t)c * HWC]);
    cp[(size_t)c * HWC] = f2bf(g);
  }
}

// ---------------------------------------------------------------------------
// K4b: conv1x1 (48x96) + residual -> X1 bf16. Grid 1536: bits[10:9] = chunk
// of 16 outputs. Inner: 24-channel register tiles.
__global__ __launch_bounds__(256) void k_attn_out2(
    const unsigned short* __restrict__ u, const float* __restrict__ x,
    const float* __restrict__ wout, unsigned short* __restrict__ x1) {
  int tid = threadIdx.x;
  unsigned bid = blockIdx.x;
  int chunk = (int)(bid >> 9);                 // 0..2
  long pix = (long)(bid & 511) * 256 + tid;
  int b = (int)(pix >> 16);
  int hw = (int)(pix & 65535);
  int o0 = chunk * 16;
  const unsigned short* up = u + (size_t)b * 96 * HWC + hw;
  float acc[16];
#pragma unroll
  for (int o = 0; o < 16; o++) acc[o] = 0.f;
  for (int c0 = 0; c0 < 96; c0 += 24) {
    float uv[24];
#pragma unroll
    for (int cc = 0; cc < 24; cc++) uv[cc] = bf2f(up[(size_t)(c0 + cc) * HWC]);
#pragma unroll
    for (int o = 0; o < 16; o++) {
      const float* wo = wout + (size_t)(o0 + o) * 96 + c0;
#pragma unroll
      for (int cc = 0; cc < 24; cc++) acc[o] += uv[cc] * wo[cc];
    }
  }
  const float* xp = x + (size_t)b * 48 * HWC + hw;
  unsigned short* op = x1 + (size_t)b * 48 * HWC + hw;
#pragma unroll
  for (int o = 0; o < 16; o++)
    op[(size_t)(o0 + o) * HWC] = f2bf(xp[(size_t)(o0 + o) * HWC] + acc[o]);
}

// ---------------------------------------------------------------------------
// K5: s[c][8][8] = irfft2(ffn_fft[c]) with numpy c2r semantics
// (v=0,4 columns symmetrized in u).
__device__ const float c_cos8[8] = {
    1.f, 0.70710678118654752f, 0.f, -0.70710678118654752f,
    -1.f, -0.70710678118654752f, 0.f, 0.70710678118654752f};

__global__ __launch_bounds__(64) void k_make_skernel(
    const float* __restrict__ fftw, float* __restrict__ s) {
  int c = blockIdx.x;
  int a = threadIdx.x >> 3, b2 = threadIdx.x & 7;
  const float* W = fftw + c * 40;  // [8][5]
  float acc = 0.f;
  for (int u = 0; u < 8; u++) {
    for (int v = 0; v < 8; v++) {
      float wv;
      if (v <= 4) {
        if (v == 0 || v == 4)
          wv = 0.5f * (W[u * 5 + v] + W[((8 - u) & 7) * 5 + v]);
        else
          wv = W[u * 5 + v];
      } else {
        wv = W[((8 - u) & 7) * 5 + (8 - v)];
      }
      acc += wv * c_cos8[(u * a + v * b2) & 7];
    }
  }
  s[c * 64 + a * 8 + b2] = acc * (1.f / 64.f);
}

// ---------------------------------------------------------------------------
// K6a: LN(48) + conv1x1 (48 -> 96 of 288) -> y bf16. Grid 1536.
__global__ __launch_bounds__(256) void k_ffn_lnconv(
    const unsigned short* __restrict__ x1, const float* __restrict__ nw,
    const float* __restrict__ nb, const float* __restrict__ win,
    unsigned short* __restrict__ y) {
  int tid = threadIdx.x;
  unsigned bid = blockIdx.x;
  int chunk = (int)(bid >> 9);                 // 0..2 -> 96 outputs each
  long pix = (long)(bid & 511) * 256 + tid;
  int b = (int)(pix >> 16);
  int hw = (int)(pix & 65535);
  const unsigned short* xp = x1 + (size_t)b * 48 * HWC + hw;
  float r[48];
  float s = 0.f, s2 = 0.f;
#pragma unroll
  for (int c = 0; c < 48; c++) {
    float v = bf2f(xp[(size_t)c * HWC]);
    r[c] = v; s += v; s2 += v * v;
  }
  float mu = s * (1.f / 48.f);
  float var = s2 * (1.f / 48.f) - mu * mu;
  float inv = rsqrtf(var + 1e-5f);
#pragma unroll
  for (int c = 0; c < 48; c++) r[c] = (r[c] - mu) * inv * nw[c] + nb[c];
  unsigned short* op = y + ((size_t)(b * 288) + chunk * 96) * HWC + hw;
  for (int o = 0; o < 96; o++) {
    const float* wo = win + (size_t)(chunk * 96 + o) * 48;
    float acc = 0.f;
#pragma unroll
    for (int c = 0; c < 48; c++) acc += r[c] * wo[c];
    op[(size_t)o * HWC] = f2bf(acc);
  }
}

// ---------------------------------------------------------------------------
// K6b: per-patch 8x8 circular conv with fixed kernel s_c, IN-PLACE on y.
// Block = (b, c, patch-row py): reads its 8x256 strip to LDS, writes back.
__global__ __launch_bounds__(256) void k_patchconv_s(
    unsigned short* y, const float* __restrict__ sk) {
  __shared__ float ys[8][266];
  __shared__ float ss[64];
  int tid = threadIdx.x;
  unsigned bid = blockIdx.x;                 // b*288*32 + c*32 + py
  int py = (int)(bid & 31);
  int c = (int)((bid >> 5) % 288u);
  int b = (int)((bid >> 5) / 288u);
  unsigned short* yp = y + ((size_t)(b * 288 + c)) * HWC + py * 2048;
#pragma unroll
  for (int it = 0; it < 8; it++) {
    int idx = it * 256 + tid;
    int i = idx >> 8, xx = idx & 255;
    ys[i][xx] = bf2f(yp[i * 256 + xx]);
  }
  if (tid < 64) ss[tid] = sk[c * 64 + tid];
  __syncthreads();
  int p = tid >> 3, a = tid & 7;
  float acc[8];
#pragma unroll
  for (int j = 0; j < 8; j++) acc[j] = 0.f;
#pragma unroll
  for (int i = 0; i < 8; i++) {
    float y8[8], s8[8];
#pragma unroll
    for (int j = 0; j < 8; j++) y8[j] = ys[i][p * 8 + j];
    int ar = (a - i) & 7;
#pragma unroll
    for (int j = 0; j < 8; j++) s8[j] = ss[ar * 8 + j];
#pragma unroll
    for (int j = 0; j < 8; j++)
#pragma unroll
      for (int bb = 0; bb < 8; bb++) acc[bb] += y8[j] * s8[(bb - j) & 7];
  }
  union { unsigned short us[8]; uint4 v; } pk;
#pragma unroll
  for (int j = 0; j < 8; j++) pk.us[j] = f2bf(acc[j]);
  *reinterpret_cast<uint4*>(yp + a * 256 + p * 8) = pk.v;
}

// ---------------------------------------------------------------------------
// K7a: dwconv3 + exact GELU gate -> g bf16 (split g1[0:96) / g2[96:144)).
// Block = (b, c in [0,144), 4-row band).
__global__ __launch_bounds__(256) void k_ffn_gate(
    const unsigned short* __restrict__ z, const float* __restrict__ dwf,
    unsigned short* __restrict__ g1, unsigned short* __restrict__ g2) {
  __shared__ float r1[6][256];
  __shared__ float r2[6][256];
  int tid = threadIdx.x;
  unsigned bid = blockIdx.x;
  int y0 = (int)(bid & 63) * 4;
  unsigned t = bid >> 6;
  int c = (int)(t % 144u);
  int b = (int)(t / 144u);
  const unsigned short* zp1 = z + ((size_t)(b * 288 + c)) * HWC;
  const unsigned short* zp2 = z + ((size_t)(b * 288 + 144 + c)) * HWC;
  float w1[9], w2[9];
#pragma unroll
  for (int k = 0; k < 9; k++) {
    w1[k] = dwf[c * 9 + k];
    w2[k] = dwf[(144 + c) * 9 + k];
  }
#pragma unroll
  for (int r = 0; r < 6; r++) {
    int yy = y0 + r - 1;
    bool ok = (yy >= 0 && yy < 256);
    r1[r][tid] = ok ? bf2f(zp1[yy * 256 + tid]) : 0.f;
    r2[r][tid] = ok ? bf2f(zp2[yy * 256 + tid]) : 0.f;
  }
  __syncthreads();
  unsigned short* gp = (c < 96)
      ? g1 + ((size_t)(b * 96 + c)) * HWC
      : g2 + ((size_t)(b * 48 + (c - 96))) * HWC;
#pragma unroll
  for (int r = 0; r < 4; r++) {
    float d1 = 0.f, d2 = 0.f;
#pragma unroll
    for (int dy = 0; dy < 3; dy++) {
      const float* a1 = r1[r + dy];
      const float* a2 = r2[r + dy];
      float m1 = (tid > 0) ? a1[tid - 1] : 0.f;
      float q1 = (tid < 255) ? a1[tid + 1] : 0.f;
      float m2 = (tid > 0) ? a2[tid - 1] : 0.f;
      float q2 = (tid < 255) ? a2[tid + 1] : 0.f;
      d1 += m1 * w1[dy * 3] + a1[tid] * w1[dy * 3 + 1] + q1 * w1[dy * 3 + 2];
      d2 += m2 * w2[dy * 3] + a2[tid] * w2[dy * 3 + 1] + q2 * w2[dy * 3 + 2];
    }
    float g = 0.5f * d1 * (1.f + erff(d1 * 0.70710678118654752f)) * d2;
    gp[(y0 + r) * 256 + tid] = f2bf(g);
  }
}

// ---------------------------------------------------------------------------
// K7b: conv1x1 (48x144) + residual -> out fp32. Grid 1536 (16-output chunks).
__global__ __launch_bounds__(256) void k_ffn_out2(
    const unsigned short* __restrict__ g1, const unsigned short* __restrict__ g2,
    const float* __restrict__ wout, const unsigned short* __restrict__ x1,
    float* __restrict__ out) {
  int tid = threadIdx.x;
  unsigned bid = blockIdx.x;
  int chunk = (int)(bid >> 9);                 // 0..2
  long pix = (long)(bid & 511) * 256 + tid;
  int b = (int)(pix >> 16);
  int hw = (int)(pix & 65535);
  int o0 = chunk * 16;
  float acc[16];
#pragma unroll
  for (int o = 0; o < 16; o++) acc[o] = 0.f;
  for (int c0 = 0; c0 < 144; c0 += 24) {
    const unsigned short* base = (c0 < 96)
        ? g1 + ((size_t)(b * 96 + c0)) * HWC + hw
        : g2 + ((size_t)(b * 48 + (c0 - 96))) * HWC + hw;
    float gv[24];
#pragma unroll
    for (int cc = 0; cc < 24; cc++) gv[cc] = bf2f(base[(size_t)cc * HWC]);
#pragma unroll
    for (int o = 0; o < 16; o++) {
      const float* wo = wout + (size_t)(o0 + o) * 144 + c0;
#pragma unroll
      for (int cc = 0; cc < 24; cc++) acc[o] += gv[cc] * wo[cc];
    }
  }
  const unsigned short* xp = x1 + (size_t)b * 48 * HWC + hw;
  float* op = out + (size_t)b * 48 * HWC + hw;
#pragma unroll
  for (int o = 0; o < 16; o++)
    op[(size_t)(o0 + o) * HWC] = bf2f(xp[(size_t)(o0 + o) * HWC]) + acc[o];
}

// ---------------------------------------------------------------------------
extern "C" void kernel_launch(void* const* d_in, const int* in_sizes, int n_in,
                              void* d_out, int out_size, void* d_ws,
                              size_t ws_size, hipStream_t stream) {
  (void)in_sizes; (void)n_in; (void)out_size; (void)ws_size;
  const float* x   = (const float*)d_in[0];
  const float* n1w = (const float*)d_in[1];
  const float* n1b = (const float*)d_in[2];
  const float* awh = (const float*)d_in[3];   // [288,48]
  const float* adw = (const float*)d_in[4];   // [288,1,3,3]
  const float* anw = (const float*)d_in[5];   // [96]
  const float* anb = (const float*)d_in[6];
  const float* awo = (const float*)d_in[7];   // [48,96]
  const float* n2w = (const float*)d_in[8];
  const float* n2b = (const float*)d_in[9];
  const float* fwi = (const float*)d_in[10];  // [288,48]
  const float* fff = (const float*)d_in[11];  // [288,1,1,8,5]
  const float* fdw = (const float*)d_in[12];  // [288,1,3,3]
  const float* fwo = (const float*)d_in[13];  // [48,144]

  unsigned short* QKV = (unsigned short*)d_ws;                       // 75.5 MB
  unsigned short* U   = (unsigned short*)((char*)d_ws + 75497472);   // 25.2 MB
  unsigned short* X1  = (unsigned short*)((char*)d_ws + 100663296);  // 12.6 MB
  unsigned short* G2  = (unsigned short*)((char*)d_ws + 113246208);  // 12.6 MB
  float*          S   = (float*)((char*)d_ws + 125829120);           // 73 KB

  // FSAS
  for (int chunk = 0; chunk < 3; chunk++) {
    k_ln_conv48b<<<1024, 256, 0, stream>>>(x, n1w, n1b, awh + chunk * 96 * 48,
                                           U);
    k_dwconv3<<<2 * 96 * 64, 256, 0, stream>>>(U, adw, QKV, chunk * 96);
  }
  k_fsas_patchconv<<<2 * 96 * 32, 256, 0, stream>>>(QKV, U);
  k_attn_gate<<<512, 256, 0, stream>>>(U, QKV, anw, anb);
  k_attn_out2<<<1536, 256, 0, stream>>>(U, x, awo, X1);
  // DFFN
  k_make_skernel<<<288, 64, 0, stream>>>(fff, S);
  k_ffn_lnconv<<<1536, 256, 0, stream>>>(X1, n2w, n2b, fwi, QKV);
  k_patchconv_s<<<2 * 288 * 32, 256, 0, stream>>>(QKV, S);
  k_ffn_gate<<<2 * 144 * 64, 256, 0, stream>>>(QKV, fdw, U, G2);
  k_ffn_out2<<<1536, 256, 0, stream>>>(U, G2, fwo, X1, (float*)d_out);
}

// Round 4
// 608.008 us; speedup vs baseline: 1.9432x; 1.0526x over previous
//
#include <hip/hip_runtime.h>
#include <hip/hip_bf16.h>
#include <cstddef>

// FFTformer block. FFTs reduced to 8x8 circular convolutions; all conv1x1
// GEMMs on MFMA (bf16 in, fp32 acc). B=2, d=48, H=W=256, P=8.
// Workspace layout (bytes), peak ~126 MB:
//   [0,          75,497,472)  QKV bf16 [2,288,HW]  (qkv -> y -> z, in-place)
//   [75,497,472, 100,663,296) U   bf16 [2,96,HW]   (hidden chunk -> out96 -> u -> g1)
//   [100,663,296,113,246,208) X1  bf16 [2,48,HW]   (ln1 -> x1)
//   [113,246,208,125,829,120) G2  bf16 [2,48,HW]   (ln2 -> g2)
//   [125,829,120,125,902,848) S   fp32 [288,64]

constexpr int HWC = 65536;   // 256*256

typedef short short8 __attribute__((ext_vector_type(8)));
typedef __bf16 bf16x8 __attribute__((ext_vector_type(8)));
typedef float f32x4 __attribute__((ext_vector_type(4)));

__device__ inline unsigned short f2bf(float f) {
  __hip_bfloat16 h = __float2bfloat16(f);
  return *reinterpret_cast<unsigned short*>(&h);
}
__device__ inline float bf2f(unsigned short u) {
  __hip_bfloat16 h;
  *reinterpret_cast<unsigned short*>(&h) = u;
  return __bfloat162float(h);
}

// ---------------------------------------------------------------------------
// LN(48) per pixel, fp32 input -> bf16 output.
__global__ __launch_bounds__(256) void k_ln_f32(
    const float* __restrict__ x, const float* __restrict__ nw,
    const float* __restrict__ nb, unsigned short* __restrict__ dst) {
  int tid = threadIdx.x;
  long pix = (long)blockIdx.x * 256 + tid;
  int b = (int)(pix >> 16);
  int hw = (int)(pix & 65535);
  const float* xp = x + (size_t)b * 48 * HWC + hw;
  float r[48];
  float s = 0.f, s2 = 0.f;
#pragma unroll
  for (int c = 0; c < 48; c++) {
    float v = xp[(size_t)c * HWC];
    r[c] = v; s += v; s2 += v * v;
  }
  float mu = s * (1.f / 48.f);
  float var = s2 * (1.f / 48.f) - mu * mu;
  float inv = rsqrtf(var + 1e-5f);
  unsigned short* op = dst + (size_t)b * 48 * HWC + hw;
#pragma unroll
  for (int c = 0; c < 48; c++)
    op[(size_t)c * HWC] = f2bf((r[c] - mu) * inv * nw[c] + nb[c]);
}

// LN(48) per pixel, bf16 input -> bf16 output.
__global__ __launch_bounds__(256) void k_ln_bf16(
    const unsigned short* __restrict__ x, const float* __restrict__ nw,
    const float* __restrict__ nb, unsigned short* __restrict__ dst) {
  int tid = threadIdx.x;
  long pix = (long)blockIdx.x * 256 + tid;
  int b = (int)(pix >> 16);
  int hw = (int)(pix & 65535);
  const unsigned short* xp = x + (size_t)b * 48 * HWC + hw;
  float r[48];
  float s = 0.f, s2 = 0.f;
#pragma unroll
  for (int c = 0; c < 48; c++) {
    float v = bf2f(xp[(size_t)c * HWC]);
    r[c] = v; s += v; s2 += v * v;
  }
  float mu = s * (1.f / 48.f);
  float var = s2 * (1.f / 48.f) - mu * mu;
  float inv = rsqrtf(var + 1e-5f);
  unsigned short* op = dst + (size_t)b * 48 * HWC + hw;
#pragma unroll
  for (int c = 0; c < 48; c++)
    op[(size_t)c * HWC] = f2bf((r[c] - mu) * inv * nw[c] + nb[c]);
}

// ---------------------------------------------------------------------------
// MFMA GEMM: out[M x N] = W[M x K] * X[K x N], N tiled 64 cols per block.
// X source is bf16 with channel stride HWC (split across two buffers at C1).
// MODE 0: write bf16. MODE 1: += fp32 residual, write bf16 (M must be 48).
// MODE 2: += bf16 residual, write fp32 (M must be 48).
template <int M, int K, int C1, int KP, int MODE>
__global__ __launch_bounds__(256) void k_gemm(
    const float* __restrict__ w, const unsigned short* __restrict__ xs1,
    const unsigned short* __restrict__ xs2, const void* __restrict__ res,
    void* __restrict__ out) {
  constexpr int STRIDE = KP + 8;     // shorts; 2*STRIDE is an odd mult of 16B
  constexpr int KS = KP / 32;
  constexpr int NT = (M + 63) / 64;
  __shared__ __align__(16) short Ws[M * STRIDE];
  __shared__ __align__(16) short Xs[64 * STRIDE];
  int tid = threadIdx.x;
  unsigned bid = blockIdx.x;                 // 2048 blocks: 64 cols each
  int b = (int)(bid >> 10);
  int hw0 = (int)(bid & 1023) * 64;

  // stage W (fp32 -> bf16, zero-pad K..KP)
  for (int idx = tid; idx < M * KP; idx += 256) {
    int m = idx / KP, k = idx - m * KP;
    float v = (k < K) ? w[m * K + k] : 0.f;
    Ws[m * STRIDE + k] = (short)f2bf(v);
  }
  // stage X transposed: Xs[col][k]
  for (int i = tid; i < 64 * KP; i += 256) {
    int col = i & 63, c = i >> 6;
    unsigned short v = 0;
    if (c < C1)
      v = xs1[((size_t)(b * C1 + c)) * HWC + hw0 + col];
    else if (c < K)
      v = xs2[((size_t)(b * 48 + (c - C1))) * HWC + hw0 + col];
    Xs[col * STRIDE + c] = (short)v;
  }
  __syncthreads();

  int lane = tid & 63, wvi = tid >> 6;
  int quad = lane >> 4, mc = lane & 15;
  int kbase = quad * 8;

  // B fragments held in registers for the whole block
  short8 bfr[4][KS];
#pragma unroll
  for (int ns = 0; ns < 4; ns++)
#pragma unroll
    for (int ks = 0; ks < KS; ks++)
      bfr[ns][ks] =
          *(const short8*)(Xs + (ns * 16 + mc) * STRIDE + ks * 32 + kbase);

#pragma unroll
  for (int t = 0; t < NT; t++) {
    int mb = (wvi + 4 * t) * 16;
    if (mb >= M) continue;
    short8 afr[KS];
#pragma unroll
    for (int ks = 0; ks < KS; ks++)
      afr[ks] = *(const short8*)(Ws + (mb + mc) * STRIDE + ks * 32 + kbase);
#pragma unroll
    for (int ns = 0; ns < 4; ns++) {
      f32x4 acc = {0.f, 0.f, 0.f, 0.f};
#pragma unroll
      for (int ks = 0; ks < KS; ks++)
        acc = __builtin_amdgcn_mfma_f32_16x16x32_bf16(
            __builtin_bit_cast(bf16x8, afr[ks]),
            __builtin_bit_cast(bf16x8, bfr[ns][ks]), acc, 0, 0, 0);
      int hw = hw0 + ns * 16 + mc;
#pragma unroll
      for (int r = 0; r < 4; r++) {
        int m = mb + quad * 4 + r;
        if (MODE == 0) {
          ((unsigned short*)out)[((size_t)(b * M + m)) * HWC + hw] =
              f2bf(acc[r]);
        } else if (MODE == 1) {
          float rv = ((const float*)res)[((size_t)(b * 48 + m)) * HWC + hw];
          ((unsigned short*)out)[((size_t)(b * 48 + m)) * HWC + hw] =
              f2bf(rv + acc[r]);
        } else {
          float rv = bf2f(
              ((const unsigned short*)res)[((size_t)(b * 48 + m)) * HWC + hw]);
          ((float*)out)[((size_t)(b * 48 + m)) * HWC + hw] = rv + acc[r];
        }
      }
    }
  }
}

// ---------------------------------------------------------------------------
// depthwise 3x3 SAME on a 96-channel chunk. Block=(b,c,4-row band).
__global__ __launch_bounds__(256) void k_dwconv3(
    const unsigned short* __restrict__ in, const float* __restrict__ dw,
    unsigned short* __restrict__ out, int c_base) {
  __shared__ float rows[6][256];
  int tid = threadIdx.x;
  unsigned bid = blockIdx.x;
  int y0 = (int)(bid & 63) * 4;
  unsigned t = bid >> 6;
  int c = (int)(t % 96u);
  int b = (int)(t / 96u);
  const unsigned short* ip = in + ((size_t)(b * 96 + c)) * HWC;
  float wv[9];
#pragma unroll
  for (int k = 0; k < 9; k++) wv[k] = dw[(c_base + c) * 9 + k];
#pragma unroll
  for (int r = 0; r < 6; r++) {
    int yy = y0 + r - 1;
    rows[r][tid] = (yy >= 0 && yy < 256) ? bf2f(ip[yy * 256 + tid]) : 0.f;
  }
  __syncthreads();
  unsigned short* op = out + ((size_t)(b * 288 + c_base + c)) * HWC;
#pragma unroll
  for (int r = 0; r < 4; r++) {
    float acc = 0.f;
#pragma unroll
    for (int dy = 0; dy < 3; dy++) {
      const float* rw = rows[r + dy];
      float xm = (tid > 0) ? rw[tid - 1] : 0.f;
      float xc = rw[tid];
      float xq = (tid < 255) ? rw[tid + 1] : 0.f;
      acc += xm * wv[dy * 3] + xc * wv[dy * 3 + 1] + xq * wv[dy * 3 + 2];
    }
    op[(y0 + r) * 256 + tid] = f2bf(acc);
  }
}

// ---------------------------------------------------------------------------
// FSAS spectral == per-patch 8x8 circular convolution q (*) k.
__global__ __launch_bounds__(256) void k_fsas_patchconv(
    const unsigned short* __restrict__ qkv, unsigned short* __restrict__ out) {
  __shared__ float qs[8][266];
  __shared__ float ks[8][266];
  int tid = threadIdx.x;
  unsigned bid = blockIdx.x;                 // b*96*32 + c*32 + py
  int py = (int)(bid & 31);
  int c = (int)((bid >> 5) % 96u);
  int b = (int)((bid >> 5) / 96u);
  const unsigned short* qp = qkv + ((size_t)(b * 288 + c)) * HWC + py * 2048;
  const unsigned short* kp =
      qkv + ((size_t)(b * 288 + 96 + c)) * HWC + py * 2048;
#pragma unroll
  for (int it = 0; it < 8; it++) {
    int idx = it * 256 + tid;
    int i = idx >> 8, xx = idx & 255;
    qs[i][xx] = bf2f(qp[i * 256 + xx]);
    ks[i][xx] = bf2f(kp[i * 256 + xx]);
  }
  __syncthreads();
  int p = tid >> 3, a = tid & 7;
  float acc[8];
#pragma unroll
  for (int j = 0; j < 8; j++) acc[j] = 0.f;
#pragma unroll
  for (int i = 0; i < 8; i++) {
    float q8[8], k8[8];
#pragma unroll
    for (int j = 0; j < 8; j++) q8[j] = qs[i][p * 8 + j];
    int ar = (a - i) & 7;
#pragma unroll
    for (int j = 0; j < 8; j++) k8[j] = ks[ar][p * 8 + j];
#pragma unroll
    for (int j = 0; j < 8; j++)
#pragma unroll
      for (int bb = 0; bb < 8; bb++) acc[bb] += q8[j] * k8[(bb - j) & 7];
  }
  unsigned short* op =
      out + ((size_t)(b * 96 + c)) * HWC + (py * 8 + a) * 256 + p * 8;
  union { unsigned short us[8]; uint4 v; } pk;
#pragma unroll
  for (int j = 0; j < 8; j++) pk.us[j] = f2bf(acc[j]);
  *reinterpret_cast<uint4*>(op) = pk.v;
}

// ---------------------------------------------------------------------------
// LN(96) + v-gate, IN-PLACE on u.
__global__ __launch_bounds__(256) void k_attn_gate(
    unsigned short* u, const unsigned short* __restrict__ qkv,
    const float* __restrict__ nw, const float* __restrict__ nb) {
  int tid = threadIdx.x;
  long pix = (long)blockIdx.x * 256 + tid;
  int b = (int)(pix >> 16);
  int hw = (int)(pix & 65535);
  unsigned short* cp = u + (size_t)b * 96 * HWC + hw;
  const unsigned short* vp = qkv + ((size_t)(b * 288) + 192) * HWC + hw;
  float t[96];
  float s = 0.f, s2 = 0.f;
#pragma unroll
  for (int c = 0; c < 96; c++) {
    float v = bf2f(cp[(size_t)c * HWC]);
    t[c] = v; s += v; s2 += v * v;
  }
  float mu = s * (1.f / 96.f);
  float var = s2 * (1.f / 96.f) - mu * mu;
  float inv = rsqrtf(var + 1e-5f);
#pragma unroll
  for (int c = 0; c < 96; c++) {
    float g = ((t[c] - mu) * inv * nw[c] + nb[c]) * bf2f(vp[(size_t)c * HWC]);
    cp[(size_t)c * HWC] = f2bf(g);
  }
}

// ---------------------------------------------------------------------------
// s[c][8][8] = irfft2(ffn_fft[c]), numpy c2r semantics (v=0,4 symmetrized).
__device__ const float c_cos8[8] = {
    1.f, 0.70710678118654752f, 0.f, -0.70710678118654752f,
    -1.f, -0.70710678118654752f, 0.f, 0.70710678118654752f};

__global__ __launch_bounds__(64) void k_make_skernel(
    const float* __restrict__ fftw, float* __restrict__ s) {
  int c = blockIdx.x;
  int a = threadIdx.x >> 3, b2 = threadIdx.x & 7;
  const float* W = fftw + c * 40;  // [8][5]
  float acc = 0.f;
  for (int u = 0; u < 8; u++) {
    for (int v = 0; v < 8; v++) {
      float wv;
      if (v <= 4) {
        if (v == 0 || v == 4)
          wv = 0.5f * (W[u * 5 + v] + W[((8 - u) & 7) * 5 + v]);
        else
          wv = W[u * 5 + v];
      } else {
        wv = W[((8 - u) & 7) * 5 + (8 - v)];
      }
      acc += wv * c_cos8[(u * a + v * b2) & 7];
    }
  }
  s[c * 64 + a * 8 + b2] = acc * (1.f / 64.f);
}

// ---------------------------------------------------------------------------
// per-patch 8x8 circular conv with fixed kernel s_c, IN-PLACE on y.
__global__ __launch_bounds__(256) void k_patchconv_s(
    unsigned short* y, const float* __restrict__ sk) {
  __shared__ float ys[8][266];
  __shared__ float ss[64];
  int tid = threadIdx.x;
  unsigned bid = blockIdx.x;                 // b*288*32 + c*32 + py
  int py = (int)(bid & 31);
  int c = (int)((bid >> 5) % 288u);
  int b = (int)((bid >> 5) / 288u);
  unsigned short* yp = y + ((size_t)(b * 288 + c)) * HWC + py * 2048;
#pragma unroll
  for (int it = 0; it < 8; it++) {
    int idx = it * 256 + tid;
    int i = idx >> 8, xx = idx & 255;
    ys[i][xx] = bf2f(yp[i * 256 + xx]);
  }
  if (tid < 64) ss[tid] = sk[c * 64 + tid];
  __syncthreads();
  int p = tid >> 3, a = tid & 7;
  float acc[8];
#pragma unroll
  for (int j = 0; j < 8; j++) acc[j] = 0.f;
#pragma unroll
  for (int i = 0; i < 8; i++) {
    float y8[8], s8[8];
#pragma unroll
    for (int j = 0; j < 8; j++) y8[j] = ys[i][p * 8 + j];
    int ar = (a - i) & 7;
#pragma unroll
    for (int j = 0; j < 8; j++) s8[j] = ss[ar * 8 + j];
#pragma unroll
    for (int j = 0; j < 8; j++)
#pragma unroll
      for (int bb = 0; bb < 8; bb++) acc[bb] += y8[j] * s8[(bb - j) & 7];
  }
  union { unsigned short us[8]; uint4 v; } pk;
#pragma unroll
  for (int j = 0; j < 8; j++) pk.us[j] = f2bf(acc[j]);
  *reinterpret_cast<uint4*>(yp + a * 256 + p * 8) = pk.v;
}

// ---------------------------------------------------------------------------
// dwconv3 + exact GELU gate -> g bf16 (split g1[0:96) / g2[96:144)).
__global__ __launch_bounds__(256) void k_ffn_gate(
    const unsigned short* __restrict__ z, const float* __restrict__ dwf,
    unsigned short* __restrict__ g1, unsigned short* __restrict__ g2) {
  __shared__ float r1[6][256];
  __shared__ float r2[6][256];
  int tid = threadIdx.x;
  unsigned bid = blockIdx.x;
  int y0 = (int)(bid & 63) * 4;
  unsigned t = bid >> 6;
  int c = (int)(t % 144u);
  int b = (int)(t / 144u);
  const unsigned short* zp1 = z + ((size_t)(b * 288 + c)) * HWC;
  const unsigned short* zp2 = z + ((size_t)(b * 288 + 144 + c)) * HWC;
  float w1[9], w2[9];
#pragma unroll
  for (int k = 0; k < 9; k++) {
    w1[k] = dwf[c * 9 + k];
    w2[k] = dwf[(144 + c) * 9 + k];
  }
#pragma unroll
  for (int r = 0; r < 6; r++) {
    int yy = y0 + r - 1;
    bool ok = (yy >= 0 && yy < 256);
    r1[r][tid] = ok ? bf2f(zp1[yy * 256 + tid]) : 0.f;
    r2[r][tid] = ok ? bf2f(zp2[yy * 256 + tid]) : 0.f;
  }
  __syncthreads();
  unsigned short* gp = (c < 96)
      ? g1 + ((size_t)(b * 96 + c)) * HWC
      : g2 + ((size_t)(b * 48 + (c - 96))) * HWC;
#pragma unroll
  for (int r = 0; r < 4; r++) {
    float d1 = 0.f, d2 = 0.f;
#pragma unroll
    for (int dy = 0; dy < 3; dy++) {
      const float* a1 = r1[r + dy];
      const float* a2 = r2[r + dy];
      float m1 = (tid > 0) ? a1[tid - 1] : 0.f;
      float q1 = (tid < 255) ? a1[tid + 1] : 0.f;
      float m2 = (tid > 0) ? a2[tid - 1] : 0.f;
      float q2 = (tid < 255) ? a2[tid + 1] : 0.f;
      d1 += m1 * w1[dy * 3] + a1[tid] * w1[dy * 3 + 1] + q1 * w1[dy * 3 + 2];
      d2 += m2 * w2[dy * 3] + a2[tid] * w2[dy * 3 + 1] + q2 * w2[dy * 3 + 2];
    }
    float g = 0.5f * d1 * (1.f + erff(d1 * 0.70710678118654752f)) * d2;
    gp[(y0 + r) * 256 + tid] = f2bf(g);
  }
}

// ---------------------------------------------------------------------------
extern "C" void kernel_launch(void* const* d_in, const int* in_sizes, int n_in,
                              void* d_out, int out_size, void* d_ws,
                              size_t ws_size, hipStream_t stream) {
  (void)in_sizes; (void)n_in; (void)out_size; (void)ws_size;
  const float* x   = (const float*)d_in[0];
  const float* n1w = (const float*)d_in[1];
  const float* n1b = (const float*)d_in[2];
  const float* awh = (const float*)d_in[3];   // [288,48]
  const float* adw = (const float*)d_in[4];   // [288,1,3,3]
  const float* anw = (const float*)d_in[5];   // [96]
  const float* anb = (const float*)d_in[6];
  const float* awo = (const float*)d_in[7];   // [48,96]
  const float* n2w = (const float*)d_in[8];
  const float* n2b = (const float*)d_in[9];
  const float* fwi = (const float*)d_in[10];  // [288,48]
  const float* fff = (const float*)d_in[11];  // [288,1,1,8,5]
  const float* fdw = (const float*)d_in[12];  // [288,1,3,3]
  const float* fwo = (const float*)d_in[13];  // [48,144]

  unsigned short* QKV = (unsigned short*)d_ws;                       // 75.5 MB
  unsigned short* U   = (unsigned short*)((char*)d_ws + 75497472);   // 25.2 MB
  unsigned short* X1  = (unsigned short*)((char*)d_ws + 100663296);  // 12.6 MB
  unsigned short* G2  = (unsigned short*)((char*)d_ws + 113246208);  // 12.6 MB
  float*          S   = (float*)((char*)d_ws + 125829120);           // 73 KB

  // FSAS: ln1 once into X1 region, then 3x (GEMM 96x48 -> dwconv3).
  k_ln_f32<<<512, 256, 0, stream>>>(x, n1w, n1b, X1);
  for (int chunk = 0; chunk < 3; chunk++) {
    k_gemm<96, 48, 48, 64, 0><<<2048, 256, 0, stream>>>(
        awh + chunk * 96 * 48, X1, nullptr, nullptr, U);
    k_dwconv3<<<2 * 96 * 64, 256, 0, stream>>>(U, adw, QKV, chunk * 96);
  }
  k_fsas_patchconv<<<2 * 96 * 32, 256, 0, stream>>>(QKV, U);
  k_attn_gate<<<512, 256, 0, stream>>>(U, QKV, anw, anb);
  // x1 = x + W_o * u   (overwrites ln1 in X1 region)
  k_gemm<48, 96, 96, 96, 1><<<2048, 256, 0, stream>>>(awo, U, nullptr, x, X1);
  // DFFN
  k_ln_bf16<<<512, 256, 0, stream>>>(X1, n2w, n2b, G2);
  k_make_skernel<<<288, 64, 0, stream>>>(fff, S);
  k_gemm<288, 48, 48, 64, 0><<<2048, 256, 0, stream>>>(fwi, G2, nullptr,
                                                       nullptr, QKV);
  k_patchconv_s<<<2 * 288 * 32, 256, 0, stream>>>(QKV, S);
  k_ffn_gate<<<2 * 144 * 64, 256, 0, stream>>>(QKV, fdw, U, G2);
  // out = x1 + W_out * g   (g split U/G2), fp32 output
  k_gemm<48, 144, 96, 160, 2><<<2048, 256, 0, stream>>>(fwo, U, G2, X1,
                                                        (float*)d_out);
}

// Round 6
// 506.477 us; speedup vs baseline: 2.3328x; 1.2005x over previous
//
#include <hip/hip_runtime.h>
#include <hip/hip_bf16.h>
#include <cstddef>

// FFTformer block. FFTs reduced to 8x8 circular convolutions; conv1x1 GEMMs
// on MFMA (bf16 in, fp32 acc) with LN/gate fused into GEMM staging.
// B=2, d=48, H=W=256, P=8.
// Workspace layout (bytes), peak ~126 MB:
//   [0,          75,497,472)  QKV bf16 [2,288,HW]  (qkv -> y -> z, in-place)
//   [75,497,472, 100,663,296) U   bf16 [2,96,HW]   (hidden chunk -> out96/u -> g1)
//   [100,663,296,113,246,208) X1  bf16 [2,48,HW]
//   [113,246,208,125,829,120) G2  bf16 [2,48,HW]   (g[96:144))
//   [125,829,120,125,902,848) S   fp32 [288,64]

constexpr int HWC = 65536;   // 256*256

typedef short short8 __attribute__((ext_vector_type(8)));
typedef __bf16 bf16x8 __attribute__((ext_vector_type(8)));
typedef float f32x4 __attribute__((ext_vector_type(4)));

__device__ inline unsigned short f2bf(float f) {
  __hip_bfloat16 h = __float2bfloat16(f);
  return *reinterpret_cast<unsigned short*>(&h);
}
__device__ inline float bf2f(unsigned short u) {
  __hip_bfloat16 h;
  *reinterpret_cast<unsigned short*>(&h) = u;
  return __bfloat162float(h);
}

union V8 { uint4 v; unsigned short us[8]; };

__device__ inline void load8f(const unsigned short* p, float* f) {
  V8 u; u.v = *reinterpret_cast<const uint4*>(p);
#pragma unroll
  for (int j = 0; j < 8; j++) f[j] = bf2f(u.us[j]);
}
__device__ inline void store8bf(unsigned short* p, const float* f) {
  V8 u;
#pragma unroll
  for (int j = 0; j < 8; j++) u.us[j] = f2bf(f[j]);
  *reinterpret_cast<uint4*>(p) = u.v;
}

// ---------------------------------------------------------------------------
// MFMA GEMM: out[M x N] = W[M x K] * X[K x N], 64 px per block, 2048 blocks.
// XF (input transform in staging): 0 none (bf16, K split 96/48 across s1/s2),
//   1 = LN48 on fp32 s1, 2 = LN96 + v-gate (s1=u bf16, v=s2 qkv ch192+),
//   3 = LN48 on bf16 s1.
// EPI: 0 write bf16[M]; 1 += fp32 res -> bf16 (M=48); 2 += bf16 res -> fp32.
template <int M, int K, int KP, int XF, int EPI>
__global__ __launch_bounds__(256) void k_gemm(
    const float* __restrict__ w, const void* __restrict__ s1,
    const unsigned short* __restrict__ s2, const float* __restrict__ lnw,
    const float* __restrict__ lnb, const void* __restrict__ res,
    void* __restrict__ out) {
  constexpr int STRIDE = KP + 8;     // shorts; multiple of 8 -> 16B-aligned rows
  constexpr int KS = KP / 32;
  constexpr int NT = (M + 63) / 64;
  constexpr int KP4 = KP / 4;
  __shared__ __align__(16) short Ws[M * STRIDE];
  __shared__ __align__(16) short Xs[64 * STRIDE];
  __shared__ __align__(16) short Vs[(XF == 2) ? 64 * STRIDE : 4];
  __shared__ float redS[4][64], redS2[4][64], mus[64], invs[64];

  int tid = threadIdx.x;
  unsigned bid = blockIdx.x;
  int b = (int)(bid >> 10);
  int hw0 = (int)(bid & 1023) * 64;

  // stage W (fp32 -> bf16, zero-pad K..KP), float4 reads
  for (int idx = tid; idx < M * KP4; idx += 256) {
    int m = idx / KP4, k4 = (idx - m * KP4) * 4;
    short4 sv = {0, 0, 0, 0};
    if (k4 < K) {
      float4 f = *reinterpret_cast<const float4*>(w + (size_t)m * K + k4);
      sv.x = (short)f2bf(f.x); sv.y = (short)f2bf(f.y);
      sv.z = (short)f2bf(f.z); sv.w = (short)f2bf(f.w);
    }
    *reinterpret_cast<short4*>(Ws + m * STRIDE + k4) = sv;
  }

  // stage X transposed: Xs[col][k], vectorized over 4 consecutive px
  if (XF == 1) {
    const float* xp = (const float*)s1 + (size_t)b * 48 * HWC + hw0;
    for (int idx = tid; idx < 48 * 16; idx += 256) {
      int c = idx >> 4, colg = (idx & 15) * 4;
      float4 f = *reinterpret_cast<const float4*>(xp + (size_t)c * HWC + colg);
      Xs[(colg + 0) * STRIDE + c] = (short)f2bf(f.x);
      Xs[(colg + 1) * STRIDE + c] = (short)f2bf(f.y);
      Xs[(colg + 2) * STRIDE + c] = (short)f2bf(f.z);
      Xs[(colg + 3) * STRIDE + c] = (short)f2bf(f.w);
    }
  } else if (XF == 2) {
    const unsigned short* up =
        (const unsigned short*)s1 + (size_t)b * 96 * HWC + hw0;
    const unsigned short* vp = s2 + ((size_t)(b * 288 + 192)) * HWC + hw0;
    for (int idx = tid; idx < 96 * 16; idx += 256) {
      int c = idx >> 4, colg = (idx & 15) * 4;
      ushort4 uv = *reinterpret_cast<const ushort4*>(up + (size_t)c * HWC + colg);
      Xs[(colg + 0) * STRIDE + c] = (short)uv.x;
      Xs[(colg + 1) * STRIDE + c] = (short)uv.y;
      Xs[(colg + 2) * STRIDE + c] = (short)uv.z;
      Xs[(colg + 3) * STRIDE + c] = (short)uv.w;
      ushort4 vv = *reinterpret_cast<const ushort4*>(vp + (size_t)c * HWC + colg);
      Vs[(colg + 0) * STRIDE + c] = (short)vv.x;
      Vs[(colg + 1) * STRIDE + c] = (short)vv.y;
      Vs[(colg + 2) * STRIDE + c] = (short)vv.z;
      Vs[(colg + 3) * STRIDE + c] = (short)vv.w;
    }
  } else if (XF == 3) {
    const unsigned short* xp =
        (const unsigned short*)s1 + (size_t)b * 48 * HWC + hw0;
    for (int idx = tid; idx < 48 * 16; idx += 256) {
      int c = idx >> 4, colg = (idx & 15) * 4;
      ushort4 uv = *reinterpret_cast<const ushort4*>(xp + (size_t)c * HWC + colg);
      Xs[(colg + 0) * STRIDE + c] = (short)uv.x;
      Xs[(colg + 1) * STRIDE + c] = (short)uv.y;
      Xs[(colg + 2) * STRIDE + c] = (short)uv.z;
      Xs[(colg + 3) * STRIDE + c] = (short)uv.w;
    }
  } else {  // XF 0: K channels split s1[0:96) / s2[96:144)
    const unsigned short* p1 =
        (const unsigned short*)s1 + (size_t)b * 96 * HWC + hw0;
    const unsigned short* p2 = s2 + (size_t)b * 48 * HWC + hw0;
    for (int idx = tid; idx < K * 16; idx += 256) {
      int c = idx >> 4, colg = (idx & 15) * 4;
      const unsigned short* p =
          (c < 96) ? (p1 + (size_t)c * HWC + colg)
                   : (p2 + (size_t)(c - 96) * HWC + colg);
      ushort4 uv = *reinterpret_cast<const ushort4*>(p);
      Xs[(colg + 0) * STRIDE + c] = (short)uv.x;
      Xs[(colg + 1) * STRIDE + c] = (short)uv.y;
      Xs[(colg + 2) * STRIDE + c] = (short)uv.z;
      Xs[(colg + 3) * STRIDE + c] = (short)uv.w;
    }
  }

  // CRITICAL: zero the K..KP pad rows of Xs (staging above only writes c<K).
  if constexpr (KP > K) {
    constexpr int PAD = KP - K;
    for (int idx = tid; idx < 64 * PAD; idx += 256) {
      int col = idx / PAD, c = K + (idx % PAD);
      Xs[col * STRIDE + c] = 0;
    }
  }

  if (XF != 0) {
    constexpr int KC = (XF == 2) ? 96 : 48;
    __syncthreads();
    // per-column LN stats: 4 partial sums per column
    {
      int col = tid & 63, q = tid >> 6;
      float s = 0.f, s2 = 0.f;
      for (int c = q * (KC / 4); c < (q + 1) * (KC / 4); c++) {
        float v = bf2f((unsigned short)Xs[col * STRIDE + c]);
        s += v; s2 += v * v;
      }
      redS[q][col] = s; redS2[q][col] = s2;
    }
    __syncthreads();
    if (tid < 64) {
      float ss = redS[0][tid] + redS[1][tid] + redS[2][tid] + redS[3][tid];
      float ss2 = redS2[0][tid] + redS2[1][tid] + redS2[2][tid] + redS2[3][tid];
      float mu = ss * (1.f / KC);
      float var = ss2 * (1.f / KC) - mu * mu;
      mus[tid] = mu; invs[tid] = rsqrtf(var + 1e-5f);
    }
    __syncthreads();
    // normalize (+gate) in place
    for (int idx = tid; idx < KC * 64; idx += 256) {
      int c = idx >> 6, col = idx & 63;
      float v = bf2f((unsigned short)Xs[col * STRIDE + c]);
      v = (v - mus[col]) * invs[col] * lnw[c] + lnb[c];
      if (XF == 2) v *= bf2f((unsigned short)Vs[col * STRIDE + c]);
      Xs[col * STRIDE + c] = (short)f2bf(v);
    }
  }
  __syncthreads();

  int lane = tid & 63, wvi = tid >> 6;
  int quad = lane >> 4, mc = lane & 15;
  int kbase = quad * 8;

  short8 bfr[4][KS];
#pragma unroll
  for (int ns = 0; ns < 4; ns++)
#pragma unroll
    for (int ks = 0; ks < KS; ks++)
      bfr[ns][ks] = *reinterpret_cast<const short8*>(
          Xs + (ns * 16 + mc) * STRIDE + ks * 32 + kbase);

#pragma unroll
  for (int t = 0; t < NT; t++) {
    int mb = (wvi + 4 * t) * 16;
    if (mb >= M) continue;
    short8 afr[KS];
#pragma unroll
    for (int ks = 0; ks < KS; ks++)
      afr[ks] = *reinterpret_cast<const short8*>(
          Ws + (mb + mc) * STRIDE + ks * 32 + kbase);
#pragma unroll
    for (int ns = 0; ns < 4; ns++) {
      f32x4 acc = {0.f, 0.f, 0.f, 0.f};
#pragma unroll
      for (int ks = 0; ks < KS; ks++)
        acc = __builtin_amdgcn_mfma_f32_16x16x32_bf16(
            __builtin_bit_cast(bf16x8, afr[ks]),
            __builtin_bit_cast(bf16x8, bfr[ns][ks]), acc, 0, 0, 0);
      int hw = hw0 + ns * 16 + mc;
#pragma unroll
      for (int r = 0; r < 4; r++) {
        int m = mb + quad * 4 + r;
        if (EPI == 0) {
          ((unsigned short*)out)[((size_t)(b * M + m)) * HWC + hw] =
              f2bf(acc[r]);
        } else if (EPI == 1) {
          float rv = ((const float*)res)[((size_t)(b * 48 + m)) * HWC + hw];
          ((unsigned short*)out)[((size_t)(b * 48 + m)) * HWC + hw] =
              f2bf(rv + acc[r]);
        } else {
          float rv = bf2f(
              ((const unsigned short*)res)[((size_t)(b * 48 + m)) * HWC + hw]);
          ((float*)out)[((size_t)(b * 48 + m)) * HWC + hw] = rv + acc[r];
        }
      }
    }
  }
}

// ---------------------------------------------------------------------------
// depthwise 3x3 SAME on a 96-channel chunk. Block=(b,c,8-row band), vec 16B.
__global__ __launch_bounds__(256) void k_dwconv3(
    const unsigned short* __restrict__ in, const float* __restrict__ dw,
    unsigned short* __restrict__ out, int c_base) {
  __shared__ float rows[10][264];
  int tid = threadIdx.x;
  unsigned bid = blockIdx.x;
  int y0 = (int)(bid & 31) * 8;
  unsigned t = bid >> 5;
  int c = (int)(t % 96u);
  int b = (int)(t / 96u);
  const unsigned short* ip = in + ((size_t)(b * 96 + c)) * HWC;
  float wv[9];
#pragma unroll
  for (int k = 0; k < 9; k++) wv[k] = dw[(c_base + c) * 9 + k];
  for (int vi = tid; vi < 320; vi += 256) {
    int rr = vi >> 5, seg = vi & 31;
    int yy = y0 + rr - 1;
    float f[8] = {0.f, 0.f, 0.f, 0.f, 0.f, 0.f, 0.f, 0.f};
    if (yy >= 0 && yy < 256) load8f(ip + yy * 256 + seg * 8, f);
#pragma unroll
    for (int j = 0; j < 8; j++) rows[rr][seg * 8 + j] = f[j];
  }
  __syncthreads();
  int r = tid >> 5, seg = tid & 31, px0 = seg * 8;
  float o[8];
#pragma unroll
  for (int j = 0; j < 8; j++) {
    int px = px0 + j;
    float acc = 0.f;
#pragma unroll
    for (int dy = 0; dy < 3; dy++) {
      const float* rw = rows[r + dy];
      float xl = (px > 0) ? rw[px - 1] : 0.f;
      float xr = (px < 255) ? rw[px + 1] : 0.f;
      acc += xl * wv[dy * 3] + rw[px] * wv[dy * 3 + 1] + xr * wv[dy * 3 + 2];
    }
    o[j] = acc;
  }
  store8bf(out + ((size_t)(b * 288 + c_base + c)) * HWC + (y0 + r) * 256 + px0,
           o);
}

// ---------------------------------------------------------------------------
// FSAS spectral == per-patch 8x8 circular convolution q (*) k.
__global__ __launch_bounds__(256) void k_fsas_patchconv(
    const unsigned short* __restrict__ qkv, unsigned short* __restrict__ out) {
  __shared__ float qs[8][266];
  __shared__ float ks[8][266];
  int tid = threadIdx.x;
  unsigned bid = blockIdx.x;                 // b*96*32 + c*32 + py
  int py = (int)(bid & 31);
  int c = (int)((bid >> 5) % 96u);
  int b = (int)((bid >> 5) / 96u);
  const unsigned short* qp = qkv + ((size_t)(b * 288 + c)) * HWC + py * 2048;
  const unsigned short* kp =
      qkv + ((size_t)(b * 288 + 96 + c)) * HWC + py * 2048;
  {
    int rr = tid >> 5, seg = tid & 31;
    float fq[8], fk[8];
    load8f(qp + rr * 256 + seg * 8, fq);
    load8f(kp + rr * 256 + seg * 8, fk);
#pragma unroll
    for (int j = 0; j < 8; j++) {
      qs[rr][seg * 8 + j] = fq[j];
      ks[rr][seg * 8 + j] = fk[j];
    }
  }
  __syncthreads();
  int p = tid >> 3, a = tid & 7;
  float acc[8];
#pragma unroll
  for (int j = 0; j < 8; j++) acc[j] = 0.f;
#pragma unroll
  for (int i = 0; i < 8; i++) {
    float q8[8], k8[8];
#pragma unroll
    for (int j = 0; j < 8; j++) q8[j] = qs[i][p * 8 + j];
    int ar = (a - i) & 7;
#pragma unroll
    for (int j = 0; j < 8; j++) k8[j] = ks[ar][p * 8 + j];
#pragma unroll
    for (int j = 0; j < 8; j++)
#pragma unroll
      for (int bb = 0; bb < 8; bb++) acc[bb] += q8[j] * k8[(bb - j) & 7];
  }
  store8bf(out + ((size_t)(b * 96 + c)) * HWC + (py * 8 + a) * 256 + p * 8,
           acc);
}

// ---------------------------------------------------------------------------
// s[c][8][8] = irfft2(ffn_fft[c]), numpy c2r semantics (v=0,4 symmetrized).
__device__ const float c_cos8[8] = {
    1.f, 0.70710678118654752f, 0.f, -0.70710678118654752f,
    -1.f, -0.70710678118654752f, 0.f, 0.70710678118654752f};

__global__ __launch_bounds__(64) void k_make_skernel(
    const float* __restrict__ fftw, float* __restrict__ s) {
  int c = blockIdx.x;
  int a = threadIdx.x >> 3, b2 = threadIdx.x & 7;
  const float* W = fftw + c * 40;  // [8][5]
  float acc = 0.f;
  for (int u = 0; u < 8; u++) {
    for (int v = 0; v < 8; v++) {
      float wv;
      if (v <= 4) {
        if (v == 0 || v == 4)
          wv = 0.5f * (W[u * 5 + v] + W[((8 - u) & 7) * 5 + v]);
        else
          wv = W[u * 5 + v];
      } else {
        wv = W[((8 - u) & 7) * 5 + (8 - v)];
      }
      acc += wv * c_cos8[(u * a + v * b2) & 7];
    }
  }
  s[c * 64 + a * 8 + b2] = acc * (1.f / 64.f);
}

// ---------------------------------------------------------------------------
// per-patch 8x8 circular conv with fixed kernel s_c, IN-PLACE on y.
__global__ __launch_bounds__(256) void k_patchconv_s(
    unsigned short* y, const float* __restrict__ sk) {
  __shared__ float ys[8][266];
  __shared__ float ss[64];
  int tid = threadIdx.x;
  unsigned bid = blockIdx.x;                 // b*288*32 + c*32 + py
  int py = (int)(bid & 31);
  int c = (int)((bid >> 5) % 288u);
  int b = (int)((bid >> 5) / 288u);
  unsigned short* yp = y + ((size_t)(b * 288 + c)) * HWC + py * 2048;
  {
    int rr = tid >> 5, seg = tid & 31;
    float fy[8];
    load8f(yp + rr * 256 + seg * 8, fy);
#pragma unroll
    for (int j = 0; j < 8; j++) ys[rr][seg * 8 + j] = fy[j];
  }
  if (tid < 64) ss[tid] = sk[c * 64 + tid];
  __syncthreads();
  int p = tid >> 3, a = tid & 7;
  float acc[8];
#pragma unroll
  for (int j = 0; j < 8; j++) acc[j] = 0.f;
#pragma unroll
  for (int i = 0; i < 8; i++) {
    float y8[8], s8[8];
#pragma unroll
    for (int j = 0; j < 8; j++) y8[j] = ys[i][p * 8 + j];
    int ar = (a - i) & 7;
#pragma unroll
    for (int j = 0; j < 8; j++) s8[j] = ss[ar * 8 + j];
#pragma unroll
    for (int j = 0; j < 8; j++)
#pragma unroll
      for (int bb = 0; bb < 8; bb++) acc[bb] += y8[j] * s8[(bb - j) & 7];
  }
  store8bf(yp + a * 256 + p * 8, acc);
}

// ---------------------------------------------------------------------------
// dwconv3 + exact GELU gate -> g bf16 (split g1[0:96) / g2[96:144)).
// Block = (b, c in [0,144), 8-row band), vec 16B.
__global__ __launch_bounds__(256) void k_ffn_gate(
    const unsigned short* __restrict__ z, const float* __restrict__ dwf,
    unsigned short* __restrict__ g1, unsigned short* __restrict__ g2) {
  __shared__ float r1[10][264];
  __shared__ float r2[10][264];
  int tid = threadIdx.x;
  unsigned bid = blockIdx.x;
  int y0 = (int)(bid & 31) * 8;
  unsigned t = bid >> 5;
  int c = (int)(t % 144u);
  int b = (int)(t / 144u);
  const unsigned short* zp1 = z + ((size_t)(b * 288 + c)) * HWC;
  const unsigned short* zp2 = z + ((size_t)(b * 288 + 144 + c)) * HWC;
  float w1[9], w2[9];
#pragma unroll
  for (int k = 0; k < 9; k++) {
    w1[k] = dwf[c * 9 + k];
    w2[k] = dwf[(144 + c) * 9 + k];
  }
  for (int vi = tid; vi < 320; vi += 256) {
    int rr = vi >> 5, seg = vi & 31;
    int yy = y0 + rr - 1;
    float f1[8] = {0.f, 0.f, 0.f, 0.f, 0.f, 0.f, 0.f, 0.f};
    float f2[8] = {0.f, 0.f, 0.f, 0.f, 0.f, 0.f, 0.f, 0.f};
    if (yy >= 0 && yy < 256) {
      load8f(zp1 + yy * 256 + seg * 8, f1);
      load8f(zp2 + yy * 256 + seg * 8, f2);
    }
#pragma unroll
    for (int j = 0; j < 8; j++) {
      r1[rr][seg * 8 + j] = f1[j];
      r2[rr][seg * 8 + j] = f2[j];
    }
  }
  __syncthreads();
  int r = tid >> 5, seg = tid & 31, px0 = seg * 8;
  float o[8];
#pragma unroll
  for (int j = 0; j < 8; j++) {
    int px = px0 + j;
    float d1 = 0.f, d2 = 0.f;
#pragma unroll
    for (int dy = 0; dy < 3; dy++) {
      const float* a1 = r1[r + dy];
      const float* a2 = r2[r + dy];
      float l1 = (px > 0) ? a1[px - 1] : 0.f;
      float q1 = (px < 255) ? a1[px + 1] : 0.f;
      float l2 = (px > 0) ? a2[px - 1] : 0.f;
      float q2 = (px < 255) ? a2[px + 1] : 0.f;
      d1 += l1 * w1[dy * 3] + a1[px] * w1[dy * 3 + 1] + q1 * w1[dy * 3 + 2];
      d2 += l2 * w2[dy * 3] + a2[px] * w2[dy * 3 + 1] + q2 * w2[dy * 3 + 2];
    }
    o[j] = 0.5f * d1 * (1.f + erff(d1 * 0.70710678118654752f)) * d2;
  }
  unsigned short* gp = (c < 96)
      ? g1 + ((size_t)(b * 96 + c)) * HWC
      : g2 + ((size_t)(b * 48 + (c - 96))) * HWC;
  store8bf(gp + (y0 + r) * 256 + px0, o);
}

// ---------------------------------------------------------------------------
extern "C" void kernel_launch(void* const* d_in, const int* in_sizes, int n_in,
                              void* d_out, int out_size, void* d_ws,
                              size_t ws_size, hipStream_t stream) {
  (void)in_sizes; (void)n_in; (void)out_size; (void)ws_size;
  const float* x   = (const float*)d_in[0];
  const float* n1w = (const float*)d_in[1];
  const float* n1b = (const float*)d_in[2];
  const float* awh = (const float*)d_in[3];   // [288,48]
  const float* adw = (const float*)d_in[4];   // [288,1,3,3]
  const float* anw = (const float*)d_in[5];   // [96]
  const float* anb = (const float*)d_in[6];
  const float* awo = (const float*)d_in[7];   // [48,96]
  const float* n2w = (const float*)d_in[8];
  const float* n2b = (const float*)d_in[9];
  const float* fwi = (const float*)d_in[10];  // [288,48]
  const float* fff = (const float*)d_in[11];  // [288,1,1,8,5]
  const float* fdw = (const float*)d_in[12];  // [288,1,3,3]
  const float* fwo = (const float*)d_in[13];  // [48,144]

  unsigned short* QKV = (unsigned short*)d_ws;                       // 75.5 MB
  unsigned short* U   = (unsigned short*)((char*)d_ws + 75497472);   // 25.2 MB
  unsigned short* X1  = (unsigned short*)((char*)d_ws + 100663296);  // 12.6 MB
  unsigned short* G2  = (unsigned short*)((char*)d_ws + 113246208);  // 12.6 MB
  float*          S   = (float*)((char*)d_ws + 125829120);           // 73 KB

  k_make_skernel<<<288, 64, 0, stream>>>(fff, S);
  // FSAS: 3x (LN1+conv1x1 GEMM chunk -> dwconv3)
  for (int chunk = 0; chunk < 3; chunk++) {
    k_gemm<96, 48, 64, 1, 0><<<2048, 256, 0, stream>>>(
        awh + chunk * 96 * 48, x, nullptr, n1w, n1b, nullptr, U);
    k_dwconv3<<<2 * 96 * 32, 256, 0, stream>>>(U, adw, QKV, chunk * 96);
  }
  k_fsas_patchconv<<<2 * 96 * 32, 256, 0, stream>>>(QKV, U);
  // x1 = x + W_o * (LN(out96) * v)   [LN+gate fused in staging]
  k_gemm<48, 96, 96, 2, 1><<<2048, 256, 0, stream>>>(awo, U, QKV, anw, anb, x,
                                                     X1);
  // DFFN: y = W_in * LN(x1)  [LN fused]
  k_gemm<288, 48, 64, 3, 0><<<2048, 256, 0, stream>>>(fwi, X1, nullptr, n2w,
                                                      n2b, nullptr, QKV);
  k_patchconv_s<<<2 * 288 * 32, 256, 0, stream>>>(QKV, S);
  k_ffn_gate<<<2 * 144 * 32, 256, 0, stream>>>(QKV, fdw, U, G2);
  // out = x1 + W_out * g  (g split U/G2), fp32 output
  k_gemm<48, 144, 160, 0, 2><<<2048, 256, 0, stream>>>(fwo, U, G2, nullptr,
                                                       nullptr, X1,
                                                       (float*)d_out);
}

// Round 7
// 396.728 us; speedup vs baseline: 2.9781x; 1.2766x over previous
//
#include <hip/hip_runtime.h>
#include <hip/hip_bf16.h>
#include <cstddef>

// FFTformer block. FFTs reduced to 8x8 circular convolutions; conv1x1 GEMMs
// on MFMA (bf16 in, fp32 acc) with LN/gate fused into GEMM staging.
// Depthwise convs are LDS-free (shuffle halo); patchconv LDS uses stride-9
// groups (row 296) for conflict-free banks. B=2, d=48, H=W=256, P=8.
// Workspace layout (bytes), peak ~126 MB:
//   [0,          75,497,472)  QKV bf16 [2,288,HW]  (qkv -> y -> z, in-place)
//   [75,497,472, 100,663,296) U   bf16 [2,96,HW]   (hidden chunk -> out96/u -> g1)
//   [100,663,296,113,246,208) X1  bf16 [2,48,HW]
//   [113,246,208,125,829,120) G2  bf16 [2,48,HW]   (g[96:144))
//   [125,829,120,125,902,848) S   fp32 [288,64]

constexpr int HWC = 65536;   // 256*256

typedef short short8 __attribute__((ext_vector_type(8)));
typedef __bf16 bf16x8 __attribute__((ext_vector_type(8)));
typedef float f32x4 __attribute__((ext_vector_type(4)));

__device__ inline unsigned short f2bf(float f) {
  __hip_bfloat16 h = __float2bfloat16(f);
  return *reinterpret_cast<unsigned short*>(&h);
}
__device__ inline float bf2f(unsigned short u) {
  __hip_bfloat16 h;
  *reinterpret_cast<unsigned short*>(&h) = u;
  return __bfloat162float(h);
}

union V8 { uint4 v; unsigned short us[8]; };

__device__ inline void load8f(const unsigned short* p, float* f) {
  V8 u; u.v = *reinterpret_cast<const uint4*>(p);
#pragma unroll
  for (int j = 0; j < 8; j++) f[j] = bf2f(u.us[j]);
}
__device__ inline void store8bf(unsigned short* p, const float* f) {
  V8 u;
#pragma unroll
  for (int j = 0; j < 8; j++) u.us[j] = f2bf(f[j]);
  *reinterpret_cast<uint4*>(p) = u.v;
}

// ---------------------------------------------------------------------------
// MFMA GEMM: out[M x N] = W[M x K] * X[K x N], 64 px per block, 2048 blocks.
// XF: 0 none (K split 96/48 across s1/s2), 1 = LN48 on fp32 s1,
//     2 = LN96 + v-gate (s1=u bf16, v=s2 qkv ch192+), 3 = LN48 on bf16 s1.
// EPI: 0 write bf16[M]; 1 += fp32 res -> bf16 (M=48); 2 += bf16 res -> fp32.
template <int M, int K, int KP, int XF, int EPI>
__global__ __launch_bounds__(256) void k_gemm(
    const float* __restrict__ w, const void* __restrict__ s1,
    const unsigned short* __restrict__ s2, const float* __restrict__ lnw,
    const float* __restrict__ lnb, const void* __restrict__ res,
    void* __restrict__ out) {
  constexpr int STRIDE = KP + 8;     // shorts; multiple of 8 -> 16B-aligned rows
  constexpr int KS = KP / 32;
  constexpr int NT = (M + 63) / 64;
  constexpr int KP4 = KP / 4;
  __shared__ __align__(16) short Ws[M * STRIDE];
  __shared__ __align__(16) short Xs[64 * STRIDE];
  __shared__ __align__(16) short Vs[(XF == 2) ? 64 * STRIDE : 4];
  __shared__ float redS[4][64], redS2[4][64], mus[64], invs[64];

  int tid = threadIdx.x;
  unsigned bid = blockIdx.x;
  int b = (int)(bid >> 10);
  int hw0 = (int)(bid & 1023) * 64;

  // stage W (fp32 -> bf16, zero-pad K..KP), float4 reads
  for (int idx = tid; idx < M * KP4; idx += 256) {
    int m = idx / KP4, k4 = (idx - m * KP4) * 4;
    short4 sv = {0, 0, 0, 0};
    if (k4 < K) {
      float4 f = *reinterpret_cast<const float4*>(w + (size_t)m * K + k4);
      sv.x = (short)f2bf(f.x); sv.y = (short)f2bf(f.y);
      sv.z = (short)f2bf(f.z); sv.w = (short)f2bf(f.w);
    }
    *reinterpret_cast<short4*>(Ws + m * STRIDE + k4) = sv;
  }

  // stage X transposed: Xs[col][k], vectorized over 4 consecutive px
  if (XF == 1) {
    const float* xp = (const float*)s1 + (size_t)b * 48 * HWC + hw0;
    for (int idx = tid; idx < 48 * 16; idx += 256) {
      int c = idx >> 4, colg = (idx & 15) * 4;
      float4 f = *reinterpret_cast<const float4*>(xp + (size_t)c * HWC + colg);
      Xs[(colg + 0) * STRIDE + c] = (short)f2bf(f.x);
      Xs[(colg + 1) * STRIDE + c] = (short)f2bf(f.y);
      Xs[(colg + 2) * STRIDE + c] = (short)f2bf(f.z);
      Xs[(colg + 3) * STRIDE + c] = (short)f2bf(f.w);
    }
  } else if (XF == 2) {
    const unsigned short* up =
        (const unsigned short*)s1 + (size_t)b * 96 * HWC + hw0;
    const unsigned short* vp = s2 + ((size_t)(b * 288 + 192)) * HWC + hw0;
    for (int idx = tid; idx < 96 * 16; idx += 256) {
      int c = idx >> 4, colg = (idx & 15) * 4;
      ushort4 uv = *reinterpret_cast<const ushort4*>(up + (size_t)c * HWC + colg);
      Xs[(colg + 0) * STRIDE + c] = (short)uv.x;
      Xs[(colg + 1) * STRIDE + c] = (short)uv.y;
      Xs[(colg + 2) * STRIDE + c] = (short)uv.z;
      Xs[(colg + 3) * STRIDE + c] = (short)uv.w;
      ushort4 vv = *reinterpret_cast<const ushort4*>(vp + (size_t)c * HWC + colg);
      Vs[(colg + 0) * STRIDE + c] = (short)vv.x;
      Vs[(colg + 1) * STRIDE + c] = (short)vv.y;
      Vs[(colg + 2) * STRIDE + c] = (short)vv.z;
      Vs[(colg + 3) * STRIDE + c] = (short)vv.w;
    }
  } else if (XF == 3) {
    const unsigned short* xp =
        (const unsigned short*)s1 + (size_t)b * 48 * HWC + hw0;
    for (int idx = tid; idx < 48 * 16; idx += 256) {
      int c = idx >> 4, colg = (idx & 15) * 4;
      ushort4 uv = *reinterpret_cast<const ushort4*>(xp + (size_t)c * HWC + colg);
      Xs[(colg + 0) * STRIDE + c] = (short)uv.x;
      Xs[(colg + 1) * STRIDE + c] = (short)uv.y;
      Xs[(colg + 2) * STRIDE + c] = (short)uv.z;
      Xs[(colg + 3) * STRIDE + c] = (short)uv.w;
    }
  } else {  // XF 0: K channels split s1[0:96) / s2[96:144)
    const unsigned short* p1 =
        (const unsigned short*)s1 + (size_t)b * 96 * HWC + hw0;
    const unsigned short* p2 = s2 + (size_t)b * 48 * HWC + hw0;
    for (int idx = tid; idx < K * 16; idx += 256) {
      int c = idx >> 4, colg = (idx & 15) * 4;
      const unsigned short* p =
          (c < 96) ? (p1 + (size_t)c * HWC + colg)
                   : (p2 + (size_t)(c - 96) * HWC + colg);
      ushort4 uv = *reinterpret_cast<const ushort4*>(p);
      Xs[(colg + 0) * STRIDE + c] = (short)uv.x;
      Xs[(colg + 1) * STRIDE + c] = (short)uv.y;
      Xs[(colg + 2) * STRIDE + c] = (short)uv.z;
      Xs[(colg + 3) * STRIDE + c] = (short)uv.w;
    }
  }

  // zero the K..KP pad rows of Xs (staging above only writes c<K).
  if constexpr (KP > K) {
    constexpr int PAD = KP - K;
    for (int idx = tid; idx < 64 * PAD; idx += 256) {
      int col = idx / PAD, c = K + (idx % PAD);
      Xs[col * STRIDE + c] = 0;
    }
  }

  if (XF != 0) {
    constexpr int KC = (XF == 2) ? 96 : 48;
    __syncthreads();
    {
      int col = tid & 63, q = tid >> 6;
      float s = 0.f, s2 = 0.f;
      for (int c = q * (KC / 4); c < (q + 1) * (KC / 4); c++) {
        float v = bf2f((unsigned short)Xs[col * STRIDE + c]);
        s += v; s2 += v * v;
      }
      redS[q][col] = s; redS2[q][col] = s2;
    }
    __syncthreads();
    if (tid < 64) {
      float ss = redS[0][tid] + redS[1][tid] + redS[2][tid] + redS[3][tid];
      float ss2 = redS2[0][tid] + redS2[1][tid] + redS2[2][tid] + redS2[3][tid];
      float mu = ss * (1.f / KC);
      float var = ss2 * (1.f / KC) - mu * mu;
      mus[tid] = mu; invs[tid] = rsqrtf(var + 1e-5f);
    }
    __syncthreads();
    for (int idx = tid; idx < KC * 64; idx += 256) {
      int c = idx >> 6, col = idx & 63;
      float v = bf2f((unsigned short)Xs[col * STRIDE + c]);
      v = (v - mus[col]) * invs[col] * lnw[c] + lnb[c];
      if (XF == 2) v *= bf2f((unsigned short)Vs[col * STRIDE + c]);
      Xs[col * STRIDE + c] = (short)f2bf(v);
    }
  }
  __syncthreads();

  int lane = tid & 63, wvi = tid >> 6;
  int quad = lane >> 4, mc = lane & 15;
  int kbase = quad * 8;

  short8 bfr[4][KS];
#pragma unroll
  for (int ns = 0; ns < 4; ns++)
#pragma unroll
    for (int ks = 0; ks < KS; ks++)
      bfr[ns][ks] = *reinterpret_cast<const short8*>(
          Xs + (ns * 16 + mc) * STRIDE + ks * 32 + kbase);

#pragma unroll
  for (int t = 0; t < NT; t++) {
    int mb = (wvi + 4 * t) * 16;
    if (mb >= M) continue;
    short8 afr[KS];
#pragma unroll
    for (int ks = 0; ks < KS; ks++)
      afr[ks] = *reinterpret_cast<const short8*>(
          Ws + (mb + mc) * STRIDE + ks * 32 + kbase);
#pragma unroll
    for (int ns = 0; ns < 4; ns++) {
      f32x4 acc = {0.f, 0.f, 0.f, 0.f};
#pragma unroll
      for (int ks = 0; ks < KS; ks++)
        acc = __builtin_amdgcn_mfma_f32_16x16x32_bf16(
            __builtin_bit_cast(bf16x8, afr[ks]),
            __builtin_bit_cast(bf16x8, bfr[ns][ks]), acc, 0, 0, 0);
      int hw = hw0 + ns * 16 + mc;
#pragma unroll
      for (int r = 0; r < 4; r++) {
        int m = mb + quad * 4 + r;
        if (EPI == 0) {
          ((unsigned short*)out)[((size_t)(b * M + m)) * HWC + hw] =
              f2bf(acc[r]);
        } else if (EPI == 1) {
          float rv = ((const float*)res)[((size_t)(b * 48 + m)) * HWC + hw];
          ((unsigned short*)out)[((size_t)(b * 48 + m)) * HWC + hw] =
              f2bf(rv + acc[r]);
        } else {
          float rv = bf2f(
              ((const unsigned short*)res)[((size_t)(b * 48 + m)) * HWC + hw]);
          ((float*)out)[((size_t)(b * 48 + m)) * HWC + hw] = rv + acc[r];
        }
      }
    }
  }
}

// ---------------------------------------------------------------------------
// depthwise 3x3 SAME, LDS-free: per-thread 8px, halo via __shfl lane +-1.
// Block = (b, c of 96-chunk, 8-row band). Thread = (row r, 8px segment seg).
__global__ __launch_bounds__(256) void k_dwconv3(
    const unsigned short* __restrict__ in, const float* __restrict__ dw,
    unsigned short* __restrict__ out, int c_base) {
  int tid = threadIdx.x;
  unsigned bid = blockIdx.x;
  int y0 = (int)(bid & 31) * 8;
  unsigned t = bid >> 5;
  int c = (int)(t % 96u);
  int b = (int)(t / 96u);
  const unsigned short* ip = in + ((size_t)(b * 96 + c)) * HWC;
  float wv[9];
#pragma unroll
  for (int k = 0; k < 9; k++) wv[k] = dw[(c_base + c) * 9 + k];
  int r = tid >> 5, seg = tid & 31, lane = tid & 63;
  int y = y0 + r;
  float f[3][8];
#pragma unroll
  for (int dy = 0; dy < 3; dy++) {
    int yy = y + dy - 1;
    if (yy >= 0 && yy < 256) {
      load8f(ip + yy * 256 + seg * 8, f[dy]);
    } else {
#pragma unroll
      for (int j = 0; j < 8; j++) f[dy][j] = 0.f;
    }
  }
  float o[8];
#pragma unroll
  for (int dy = 0; dy < 3; dy++) {
    float lv = __shfl(f[dy][7], lane - 1, 64);
    float rv = __shfl(f[dy][0], lane + 1, 64);
    if (seg == 0) lv = 0.f;
    if (seg == 31) rv = 0.f;
#pragma unroll
    for (int j = 0; j < 8; j++) {
      float xl = (j == 0) ? lv : f[dy][j - 1];
      float xr = (j == 7) ? rv : f[dy][j + 1];
      float v = xl * wv[dy * 3] + f[dy][j] * wv[dy * 3 + 1] + xr * wv[dy * 3 + 2];
      o[j] = (dy == 0) ? v : o[j] + v;
    }
  }
  store8bf(out + ((size_t)(b * 288 + c_base + c)) * HWC + y * 256 + seg * 8, o);
}

// ---------------------------------------------------------------------------
// FSAS spectral == per-patch 8x8 circular convolution q (*) k.
// LDS rows 296 (=8 mod 32), groups at stride 9 -> conflict-free banks.
__global__ __launch_bounds__(256) void k_fsas_patchconv(
    const unsigned short* __restrict__ qkv, unsigned short* __restrict__ out) {
  __shared__ float qs[8][296];
  __shared__ float kt[8][296];
  int tid = threadIdx.x;
  unsigned bid = blockIdx.x;                 // b*96*32 + c*32 + py
  int py = (int)(bid & 31);
  int c = (int)((bid >> 5) % 96u);
  int b = (int)((bid >> 5) / 96u);
  const unsigned short* qp = qkv + ((size_t)(b * 288 + c)) * HWC + py * 2048;
  const unsigned short* kp =
      qkv + ((size_t)(b * 288 + 96 + c)) * HWC + py * 2048;
  {
    int rr = tid >> 5, seg = tid & 31;
    float fq[8], fk[8];
    load8f(qp + rr * 256 + seg * 8, fq);
    load8f(kp + rr * 256 + seg * 8, fk);
#pragma unroll
    for (int j = 0; j < 8; j++) {
      qs[rr][seg * 9 + j] = fq[j];
      kt[rr][seg * 9 + j] = fk[j];
    }
  }
  __syncthreads();
  int p = tid >> 3, a = tid & 7;
  float acc[8];
#pragma unroll
  for (int j = 0; j < 8; j++) acc[j] = 0.f;
#pragma unroll
  for (int i = 0; i < 8; i++) {
    float q8[8], k8[8];
#pragma unroll
    for (int j = 0; j < 8; j++) q8[j] = qs[i][p * 9 + j];
    int ar = (a - i) & 7;
#pragma unroll
    for (int j = 0; j < 8; j++) k8[j] = kt[ar][p * 9 + j];
#pragma unroll
    for (int j = 0; j < 8; j++)
#pragma unroll
      for (int bb = 0; bb < 8; bb++) acc[bb] += q8[j] * k8[(bb - j) & 7];
  }
  store8bf(out + ((size_t)(b * 96 + c)) * HWC + (py * 8 + a) * 256 + p * 8,
           acc);
}

// ---------------------------------------------------------------------------
// s[c][8][8] = irfft2(ffn_fft[c]), numpy c2r semantics (v=0,4 symmetrized).
__device__ const float c_cos8[8] = {
    1.f, 0.70710678118654752f, 0.f, -0.70710678118654752f,
    -1.f, -0.70710678118654752f, 0.f, 0.70710678118654752f};

__global__ __launch_bounds__(64) void k_make_skernel(
    const float* __restrict__ fftw, float* __restrict__ s) {
  int c = blockIdx.x;
  int a = threadIdx.x >> 3, b2 = threadIdx.x & 7;
  const float* W = fftw + c * 40;  // [8][5]
  float acc = 0.f;
  for (int u = 0; u < 8; u++) {
    for (int v = 0; v < 8; v++) {
      float wv;
      if (v <= 4) {
        if (v == 0 || v == 4)
          wv = 0.5f * (W[u * 5 + v] + W[((8 - u) & 7) * 5 + v]);
        else
          wv = W[u * 5 + v];
      } else {
        wv = W[((8 - u) & 7) * 5 + (8 - v)];
      }
      acc += wv * c_cos8[(u * a + v * b2) & 7];
    }
  }
  s[c * 64 + a * 8 + b2] = acc * (1.f / 64.f);
}

// ---------------------------------------------------------------------------
// per-patch 8x8 circular conv with fixed kernel s_c, IN-PLACE on y.
__global__ __launch_bounds__(256) void k_patchconv_s(
    unsigned short* y, const float* __restrict__ sk) {
  __shared__ float ys[8][296];
  __shared__ float ss[64];
  int tid = threadIdx.x;
  unsigned bid = blockIdx.x;                 // b*288*32 + c*32 + py
  int py = (int)(bid & 31);
  int c = (int)((bid >> 5) % 288u);
  int b = (int)((bid >> 5) / 288u);
  unsigned short* yp = y + ((size_t)(b * 288 + c)) * HWC + py * 2048;
  {
    int rr = tid >> 5, seg = tid & 31;
    float fy[8];
    load8f(yp + rr * 256 + seg * 8, fy);
#pragma unroll
    for (int j = 0; j < 8; j++) ys[rr][seg * 9 + j] = fy[j];
  }
  if (tid < 64) ss[tid] = sk[c * 64 + tid];
  __syncthreads();
  int p = tid >> 3, a = tid & 7;
  float acc[8];
#pragma unroll
  for (int j = 0; j < 8; j++) acc[j] = 0.f;
#pragma unroll
  for (int i = 0; i < 8; i++) {
    float y8[8], s8[8];
#pragma unroll
    for (int j = 0; j < 8; j++) y8[j] = ys[i][p * 9 + j];
    int ar = (a - i) & 7;
#pragma unroll
    for (int j = 0; j < 8; j++) s8[j] = ss[ar * 8 + j];
#pragma unroll
    for (int j = 0; j < 8; j++)
#pragma unroll
      for (int bb = 0; bb < 8; bb++) acc[bb] += y8[j] * s8[(bb - j) & 7];
  }
  store8bf(yp + a * 256 + p * 8, acc);
}

// ---------------------------------------------------------------------------
// dwconv3 + exact GELU gate -> g bf16 (split g1[0:96) / g2[96:144)).
// LDS-free: per-thread 8px, halo via __shfl. Block=(b, c in [0,144), 8-row band).
__global__ __launch_bounds__(256) void k_ffn_gate(
    const unsigned short* __restrict__ z, const float* __restrict__ dwf,
    unsigned short* __restrict__ g1, unsigned short* __restrict__ g2) {
  int tid = threadIdx.x;
  unsigned bid = blockIdx.x;
  int y0 = (int)(bid & 31) * 8;
  unsigned t = bid >> 5;
  int c = (int)(t % 144u);
  int b = (int)(t / 144u);
  const unsigned short* zp1 = z + ((size_t)(b * 288 + c)) * HWC;
  const unsigned short* zp2 = z + ((size_t)(b * 288 + 144 + c)) * HWC;
  float w1[9], w2[9];
#pragma unroll
  for (int k = 0; k < 9; k++) {
    w1[k] = dwf[c * 9 + k];
    w2[k] = dwf[(144 + c) * 9 + k];
  }
  int r = tid >> 5, seg = tid & 31, lane = tid & 63;
  int y = y0 + r;
  float f1[3][8], f2[3][8];
#pragma unroll
  for (int dy = 0; dy < 3; dy++) {
    int yy = y + dy - 1;
    if (yy >= 0 && yy < 256) {
      load8f(zp1 + yy * 256 + seg * 8, f1[dy]);
      load8f(zp2 + yy * 256 + seg * 8, f2[dy]);
    } else {
#pragma unroll
      for (int j = 0; j < 8; j++) { f1[dy][j] = 0.f; f2[dy][j] = 0.f; }
    }
  }
  float d1[8], d2[8];
#pragma unroll
  for (int j = 0; j < 8; j++) { d1[j] = 0.f; d2[j] = 0.f; }
#pragma unroll
  for (int dy = 0; dy < 3; dy++) {
    float lv1 = __shfl(f1[dy][7], lane - 1, 64);
    float rv1 = __shfl(f1[dy][0], lane + 1, 64);
    float lv2 = __shfl(f2[dy][7], lane - 1, 64);
    float rv2 = __shfl(f2[dy][0], lane + 1, 64);
    if (seg == 0) { lv1 = 0.f; lv2 = 0.f; }
    if (seg == 31) { rv1 = 0.f; rv2 = 0.f; }
#pragma unroll
    for (int j = 0; j < 8; j++) {
      float xl1 = (j == 0) ? lv1 : f1[dy][j - 1];
      float xr1 = (j == 7) ? rv1 : f1[dy][j + 1];
      float xl2 = (j == 0) ? lv2 : f2[dy][j - 1];
      float xr2 = (j == 7) ? rv2 : f2[dy][j + 1];
      d1[j] += xl1 * w1[dy * 3] + f1[dy][j] * w1[dy * 3 + 1] + xr1 * w1[dy * 3 + 2];
      d2[j] += xl2 * w2[dy * 3] + f2[dy][j] * w2[dy * 3 + 1] + xr2 * w2[dy * 3 + 2];
    }
  }
  float o[8];
#pragma unroll
  for (int j = 0; j < 8; j++)
    o[j] = 0.5f * d1[j] * (1.f + erff(d1[j] * 0.70710678118654752f)) * d2[j];
  unsigned short* gp = (c < 96)
      ? g1 + ((size_t)(b * 96 + c)) * HWC
      : g2 + ((size_t)(b * 48 + (c - 96))) * HWC;
  store8bf(gp + y * 256 + seg * 8, o);
}

// ---------------------------------------------------------------------------
extern "C" void kernel_launch(void* const* d_in, const int* in_sizes, int n_in,
                              void* d_out, int out_size, void* d_ws,
                              size_t ws_size, hipStream_t stream) {
  (void)in_sizes; (void)n_in; (void)out_size; (void)ws_size;
  const float* x   = (const float*)d_in[0];
  const float* n1w = (const float*)d_in[1];
  const float* n1b = (const float*)d_in[2];
  const float* awh = (const float*)d_in[3];   // [288,48]
  const float* adw = (const float*)d_in[4];   // [288,1,3,3]
  const float* anw = (const float*)d_in[5];   // [96]
  const float* anb = (const float*)d_in[6];
  const float* awo = (const float*)d_in[7];   // [48,96]
  const float* n2w = (const float*)d_in[8];
  const float* n2b = (const float*)d_in[9];
  const float* fwi = (const float*)d_in[10];  // [288,48]
  const float* fff = (const float*)d_in[11];  // [288,1,1,8,5]
  const float* fdw = (const float*)d_in[12];  // [288,1,3,3]
  const float* fwo = (const float*)d_in[13];  // [48,144]

  unsigned short* QKV = (unsigned short*)d_ws;                       // 75.5 MB
  unsigned short* U   = (unsigned short*)((char*)d_ws + 75497472);   // 25.2 MB
  unsigned short* X1  = (unsigned short*)((char*)d_ws + 100663296);  // 12.6 MB
  unsigned short* G2  = (unsigned short*)((char*)d_ws + 113246208);  // 12.6 MB
  float*          S   = (float*)((char*)d_ws + 125829120);           // 73 KB

  k_make_skernel<<<288, 64, 0, stream>>>(fff, S);
  // FSAS: 3x (LN1+conv1x1 GEMM chunk -> dwconv3)
  for (int chunk = 0; chunk < 3; chunk++) {
    k_gemm<96, 48, 64, 1, 0><<<2048, 256, 0, stream>>>(
        awh + chunk * 96 * 48, x, nullptr, n1w, n1b, nullptr, U);
    k_dwconv3<<<2 * 96 * 32, 256, 0, stream>>>(U, adw, QKV, chunk * 96);
  }
  k_fsas_patchconv<<<2 * 96 * 32, 256, 0, stream>>>(QKV, U);
  // x1 = x + W_o * (LN(out96) * v)   [LN+gate fused in staging]
  k_gemm<48, 96, 96, 2, 1><<<2048, 256, 0, stream>>>(awo, U, QKV, anw, anb, x,
                                                     X1);
  // DFFN: y = W_in * LN(x1)  [LN fused]
  k_gemm<288, 48, 64, 3, 0><<<2048, 256, 0, stream>>>(fwi, X1, nullptr, n2w,
                                                      n2b, nullptr, QKV);
  k_patchconv_s<<<2 * 288 * 32, 256, 0, stream>>>(QKV, S);
  k_ffn_gate<<<2 * 144 * 32, 256, 0, stream>>>(QKV, fdw, U, G2);
  // out = x1 + W_out * g  (g split U/G2), fp32 output
  k_gemm<48, 144, 160, 0, 2><<<2048, 256, 0, stream>>>(fwo, U, G2, nullptr,
                                                       nullptr, X1,
                                                       (float*)d_out);
}

// Round 8
// 352.627 us; speedup vs baseline: 3.3506x; 1.1251x over previous
//
#include <hip/hip_runtime.h>
#include <hip/hip_bf16.h>
#include <cstddef>

// FFTformer block. FFTs reduced to 8x8 circular convolutions; conv1x1 GEMMs
// on MFMA (bf16 in, fp32 acc) with LN/gate fused into GEMM staging. DFFN
// spectral filter = per-channel 64x64 circulant matmul on MFMA (precomputed
// C_c table). Depthwise convs are LDS-free (shuffle halo). B=2,d=48,HW=256,P=8.
// Workspace layout (bytes), peak ~125.9 MB:
//   [0,          75,497,472)  QKV bf16 [2,288,HW]  (qkv -> y -> z, in-place)
//   [75,497,472, 100,663,296) U   bf16 [2,96,HW]   (hidden chunk -> out96/u -> g1)
//   [100,663,296,113,246,208) X1  bf16 [2,48,HW]
//   [113,246,208,125,829,120) G2  bf16 [2,48,HW]   (Cmat 2.36MB until ffn_gate
//                                                   overwrites with g[96:144))

constexpr int HWC = 65536;   // 256*256

typedef short short8 __attribute__((ext_vector_type(8)));
typedef __bf16 bf16x8 __attribute__((ext_vector_type(8)));
typedef float f32x4 __attribute__((ext_vector_type(4)));

__device__ inline unsigned short f2bf(float f) {
  __hip_bfloat16 h = __float2bfloat16(f);
  return *reinterpret_cast<unsigned short*>(&h);
}
__device__ inline float bf2f(unsigned short u) {
  __hip_bfloat16 h;
  *reinterpret_cast<unsigned short*>(&h) = u;
  return __bfloat162float(h);
}

union V8 { uint4 v; unsigned short us[8]; };

__device__ inline void load8f(const unsigned short* p, float* f) {
  V8 u; u.v = *reinterpret_cast<const uint4*>(p);
#pragma unroll
  for (int j = 0; j < 8; j++) f[j] = bf2f(u.us[j]);
}
__device__ inline void store8bf(unsigned short* p, const float* f) {
  V8 u;
#pragma unroll
  for (int j = 0; j < 8; j++) u.us[j] = f2bf(f[j]);
  *reinterpret_cast<uint4*>(p) = u.v;
}

// ---------------------------------------------------------------------------
// MFMA GEMM: out[M x N] = W[M x K] * X[K x N], 64 px per block, 2048 blocks.
// XF: 0 none (K split 96/48 across s1/s2), 1 = LN48 on fp32 s1,
//     2 = LN96 + v-gate (s1=u bf16, v=s2 qkv ch192+), 3 = LN48 on bf16 s1.
// EPI: 0 write bf16[M]; 1 += fp32 res -> bf16 (M=48); 2 += bf16 res -> fp32.
template <int M, int K, int KP, int XF, int EPI>
__global__ __launch_bounds__(256) void k_gemm(
    const float* __restrict__ w, const void* __restrict__ s1,
    const unsigned short* __restrict__ s2, const float* __restrict__ lnw,
    const float* __restrict__ lnb, const void* __restrict__ res,
    void* __restrict__ out) {
  constexpr int STRIDE = KP + 8;     // shorts; multiple of 8 -> 16B-aligned rows
  constexpr int KS = KP / 32;
  constexpr int NT = (M + 63) / 64;
  constexpr int KP4 = KP / 4;
  __shared__ __align__(16) short Ws[M * STRIDE];
  __shared__ __align__(16) short Xs[64 * STRIDE];
  __shared__ __align__(16) short Vs[(XF == 2) ? 64 * STRIDE : 4];
  __shared__ float redS[4][64], redS2[4][64], mus[64], invs[64];

  int tid = threadIdx.x;
  unsigned bid = blockIdx.x;
  int b = (int)(bid >> 10);
  int hw0 = (int)(bid & 1023) * 64;

  // stage W (fp32 -> bf16, zero-pad K..KP), float4 reads
  for (int idx = tid; idx < M * KP4; idx += 256) {
    int m = idx / KP4, k4 = (idx - m * KP4) * 4;
    short4 sv = {0, 0, 0, 0};
    if (k4 < K) {
      float4 f = *reinterpret_cast<const float4*>(w + (size_t)m * K + k4);
      sv.x = (short)f2bf(f.x); sv.y = (short)f2bf(f.y);
      sv.z = (short)f2bf(f.z); sv.w = (short)f2bf(f.w);
    }
    *reinterpret_cast<short4*>(Ws + m * STRIDE + k4) = sv;
  }

  // stage X transposed: Xs[col][k], vectorized over 4 consecutive px
  if (XF == 1) {
    const float* xp = (const float*)s1 + (size_t)b * 48 * HWC + hw0;
    for (int idx = tid; idx < 48 * 16; idx += 256) {
      int c = idx >> 4, colg = (idx & 15) * 4;
      float4 f = *reinterpret_cast<const float4*>(xp + (size_t)c * HWC + colg);
      Xs[(colg + 0) * STRIDE + c] = (short)f2bf(f.x);
      Xs[(colg + 1) * STRIDE + c] = (short)f2bf(f.y);
      Xs[(colg + 2) * STRIDE + c] = (short)f2bf(f.z);
      Xs[(colg + 3) * STRIDE + c] = (short)f2bf(f.w);
    }
  } else if (XF == 2) {
    const unsigned short* up =
        (const unsigned short*)s1 + (size_t)b * 96 * HWC + hw0;
    const unsigned short* vp = s2 + ((size_t)(b * 288 + 192)) * HWC + hw0;
    for (int idx = tid; idx < 96 * 16; idx += 256) {
      int c = idx >> 4, colg = (idx & 15) * 4;
      ushort4 uv = *reinterpret_cast<const ushort4*>(up + (size_t)c * HWC + colg);
      Xs[(colg + 0) * STRIDE + c] = (short)uv.x;
      Xs[(colg + 1) * STRIDE + c] = (short)uv.y;
      Xs[(colg + 2) * STRIDE + c] = (short)uv.z;
      Xs[(colg + 3) * STRIDE + c] = (short)uv.w;
      ushort4 vv = *reinterpret_cast<const ushort4*>(vp + (size_t)c * HWC + colg);
      Vs[(colg + 0) * STRIDE + c] = (short)vv.x;
      Vs[(colg + 1) * STRIDE + c] = (short)vv.y;
      Vs[(colg + 2) * STRIDE + c] = (short)vv.z;
      Vs[(colg + 3) * STRIDE + c] = (short)vv.w;
    }
  } else if (XF == 3) {
    const unsigned short* xp =
        (const unsigned short*)s1 + (size_t)b * 48 * HWC + hw0;
    for (int idx = tid; idx < 48 * 16; idx += 256) {
      int c = idx >> 4, colg = (idx & 15) * 4;
      ushort4 uv = *reinterpret_cast<const ushort4*>(xp + (size_t)c * HWC + colg);
      Xs[(colg + 0) * STRIDE + c] = (short)uv.x;
      Xs[(colg + 1) * STRIDE + c] = (short)uv.y;
      Xs[(colg + 2) * STRIDE + c] = (short)uv.z;
      Xs[(colg + 3) * STRIDE + c] = (short)uv.w;
    }
  } else {  // XF 0: K channels split s1[0:96) / s2[96:144)
    const unsigned short* p1 =
        (const unsigned short*)s1 + (size_t)b * 96 * HWC + hw0;
    const unsigned short* p2 = s2 + (size_t)b * 48 * HWC + hw0;
    for (int idx = tid; idx < K * 16; idx += 256) {
      int c = idx >> 4, colg = (idx & 15) * 4;
      const unsigned short* p =
          (c < 96) ? (p1 + (size_t)c * HWC + colg)
                   : (p2 + (size_t)(c - 96) * HWC + colg);
      ushort4 uv = *reinterpret_cast<const ushort4*>(p);
      Xs[(colg + 0) * STRIDE + c] = (short)uv.x;
      Xs[(colg + 1) * STRIDE + c] = (short)uv.y;
      Xs[(colg + 2) * STRIDE + c] = (short)uv.z;
      Xs[(colg + 3) * STRIDE + c] = (short)uv.w;
    }
  }

  // zero the K..KP pad rows of Xs (staging above only writes c<K).
  if constexpr (KP > K) {
    constexpr int PAD = KP - K;
    for (int idx = tid; idx < 64 * PAD; idx += 256) {
      int col = idx / PAD, c = K + (idx % PAD);
      Xs[col * STRIDE + c] = 0;
    }
  }

  if (XF != 0) {
    constexpr int KC = (XF == 2) ? 96 : 48;
    __syncthreads();
    {
      int col = tid & 63, q = tid >> 6;
      float s = 0.f, s2 = 0.f;
      for (int c = q * (KC / 4); c < (q + 1) * (KC / 4); c++) {
        float v = bf2f((unsigned short)Xs[col * STRIDE + c]);
        s += v; s2 += v * v;
      }
      redS[q][col] = s; redS2[q][col] = s2;
    }
    __syncthreads();
    if (tid < 64) {
      float ss = redS[0][tid] + redS[1][tid] + redS[2][tid] + redS[3][tid];
      float ss2 = redS2[0][tid] + redS2[1][tid] + redS2[2][tid] + redS2[3][tid];
      float mu = ss * (1.f / KC);
      float var = ss2 * (1.f / KC) - mu * mu;
      mus[tid] = mu; invs[tid] = rsqrtf(var + 1e-5f);
    }
    __syncthreads();
    for (int idx = tid; idx < KC * 64; idx += 256) {
      int c = idx >> 6, col = idx & 63;
      float v = bf2f((unsigned short)Xs[col * STRIDE + c]);
      v = (v - mus[col]) * invs[col] * lnw[c] + lnb[c];
      if (XF == 2) v *= bf2f((unsigned short)Vs[col * STRIDE + c]);
      Xs[col * STRIDE + c] = (short)f2bf(v);
    }
  }
  __syncthreads();

  int lane = tid & 63, wvi = tid >> 6;
  int quad = lane >> 4, mc = lane & 15;
  int kbase = quad * 8;

  short8 bfr[4][KS];
#pragma unroll
  for (int ns = 0; ns < 4; ns++)
#pragma unroll
    for (int ks = 0; ks < KS; ks++)
      bfr[ns][ks] = *reinterpret_cast<const short8*>(
          Xs + (ns * 16 + mc) * STRIDE + ks * 32 + kbase);

#pragma unroll
  for (int t = 0; t < NT; t++) {
    int mb = (wvi + 4 * t) * 16;
    if (mb >= M) continue;
    short8 afr[KS];
#pragma unroll
    for (int ks = 0; ks < KS; ks++)
      afr[ks] = *reinterpret_cast<const short8*>(
          Ws + (mb + mc) * STRIDE + ks * 32 + kbase);
#pragma unroll
    for (int ns = 0; ns < 4; ns++) {
      f32x4 acc = {0.f, 0.f, 0.f, 0.f};
#pragma unroll
      for (int ks = 0; ks < KS; ks++)
        acc = __builtin_amdgcn_mfma_f32_16x16x32_bf16(
            __builtin_bit_cast(bf16x8, afr[ks]),
            __builtin_bit_cast(bf16x8, bfr[ns][ks]), acc, 0, 0, 0);
      int hw = hw0 + ns * 16 + mc;
#pragma unroll
      for (int r = 0; r < 4; r++) {
        int m = mb + quad * 4 + r;
        if (EPI == 0) {
          ((unsigned short*)out)[((size_t)(b * M + m)) * HWC + hw] =
              f2bf(acc[r]);
        } else if (EPI == 1) {
          float rv = ((const float*)res)[((size_t)(b * 48 + m)) * HWC + hw];
          ((unsigned short*)out)[((size_t)(b * 48 + m)) * HWC + hw] =
              f2bf(rv + acc[r]);
        } else {
          float rv = bf2f(
              ((const unsigned short*)res)[((size_t)(b * 48 + m)) * HWC + hw]);
          ((float*)out)[((size_t)(b * 48 + m)) * HWC + hw] = rv + acc[r];
        }
      }
    }
  }
}

// ---------------------------------------------------------------------------
// depthwise 3x3 SAME, LDS-free: per-thread 8px, halo via __shfl lane +-1.
__global__ __launch_bounds__(256) void k_dwconv3(
    const unsigned short* __restrict__ in, const float* __restrict__ dw,
    unsigned short* __restrict__ out, int c_base) {
  int tid = threadIdx.x;
  unsigned bid = blockIdx.x;
  int y0 = (int)(bid & 31) * 8;
  unsigned t = bid >> 5;
  int c = (int)(t % 96u);
  int b = (int)(t / 96u);
  const unsigned short* ip = in + ((size_t)(b * 96 + c)) * HWC;
  float wv[9];
#pragma unroll
  for (int k = 0; k < 9; k++) wv[k] = dw[(c_base + c) * 9 + k];
  int r = tid >> 5, seg = tid & 31, lane = tid & 63;
  int y = y0 + r;
  float f[3][8];
#pragma unroll
  for (int dy = 0; dy < 3; dy++) {
    int yy = y + dy - 1;
    if (yy >= 0 && yy < 256) {
      load8f(ip + yy * 256 + seg * 8, f[dy]);
    } else {
#pragma unroll
      for (int j = 0; j < 8; j++) f[dy][j] = 0.f;
    }
  }
  float o[8];
#pragma unroll
  for (int dy = 0; dy < 3; dy++) {
    float lv = __shfl(f[dy][7], lane - 1, 64);
    float rv = __shfl(f[dy][0], lane + 1, 64);
    if (seg == 0) lv = 0.f;
    if (seg == 31) rv = 0.f;
#pragma unroll
    for (int j = 0; j < 8; j++) {
      float xl = (j == 0) ? lv : f[dy][j - 1];
      float xr = (j == 7) ? rv : f[dy][j + 1];
      float v = xl * wv[dy * 3] + f[dy][j] * wv[dy * 3 + 1] + xr * wv[dy * 3 + 2];
      o[j] = (dy == 0) ? v : o[j] + v;
    }
  }
  store8bf(out + ((size_t)(b * 288 + c_base + c)) * HWC + y * 256 + seg * 8, o);
}

// ---------------------------------------------------------------------------
// FSAS spectral == per-patch 8x8 circular convolution q (*) k.
// LDS rows 296 (=8 mod 32), groups at stride 9 -> conflict-free banks.
__global__ __launch_bounds__(256) void k_fsas_patchconv(
    const unsigned short* __restrict__ qkv, unsigned short* __restrict__ out) {
  __shared__ float qs[8][296];
  __shared__ float kt[8][296];
  int tid = threadIdx.x;
  unsigned bid = blockIdx.x;                 // b*96*32 + c*32 + py
  int py = (int)(bid & 31);
  int c = (int)((bid >> 5) % 96u);
  int b = (int)((bid >> 5) / 96u);
  const unsigned short* qp = qkv + ((size_t)(b * 288 + c)) * HWC + py * 2048;
  const unsigned short* kp =
      qkv + ((size_t)(b * 288 + 96 + c)) * HWC + py * 2048;
  {
    int rr = tid >> 5, seg = tid & 31;
    float fq[8], fk[8];
    load8f(qp + rr * 256 + seg * 8, fq);
    load8f(kp + rr * 256 + seg * 8, fk);
#pragma unroll
    for (int j = 0; j < 8; j++) {
      qs[rr][seg * 9 + j] = fq[j];
      kt[rr][seg * 9 + j] = fk[j];
    }
  }
  __syncthreads();
  int p = tid >> 3, a = tid & 7;
  float acc[8];
#pragma unroll
  for (int j = 0; j < 8; j++) acc[j] = 0.f;
#pragma unroll
  for (int i = 0; i < 8; i++) {
    float q8[8], k8[8];
#pragma unroll
    for (int j = 0; j < 8; j++) q8[j] = qs[i][p * 9 + j];
    int ar = (a - i) & 7;
#pragma unroll
    for (int j = 0; j < 8; j++) k8[j] = kt[ar][p * 9 + j];
#pragma unroll
    for (int j = 0; j < 8; j++)
#pragma unroll
      for (int bb = 0; bb < 8; bb++) acc[bb] += q8[j] * k8[(bb - j) & 7];
  }
  store8bf(out + ((size_t)(b * 96 + c)) * HWC + (py * 8 + a) * 256 + p * 8,
           acc);
}

// ---------------------------------------------------------------------------
// Cmat[c][m][k] (bf16): 64x64 circulant of s_c = irfft2(ffn_fft[c]) (numpy c2r
// semantics: v=0,4 columns symmetrized). z = Cmat[c] * y_patch.
__device__ const float c_cos8[8] = {
    1.f, 0.70710678118654752f, 0.f, -0.70710678118654752f,
    -1.f, -0.70710678118654752f, 0.f, 0.70710678118654752f};

__global__ __launch_bounds__(64) void k_make_cmat(
    const float* __restrict__ fftw, unsigned short* __restrict__ cmat) {
  __shared__ float sf[64];
  int c = blockIdx.x;
  int a = threadIdx.x >> 3, b2 = threadIdx.x & 7;
  const float* W = fftw + c * 40;  // [8][5]
  float acc = 0.f;
  for (int u = 0; u < 8; u++) {
    for (int v = 0; v < 8; v++) {
      float wv;
      if (v <= 4) {
        if (v == 0 || v == 4)
          wv = 0.5f * (W[u * 5 + v] + W[((8 - u) & 7) * 5 + v]);
        else
          wv = W[u * 5 + v];
      } else {
        wv = W[((8 - u) & 7) * 5 + (8 - v)];
      }
      acc += wv * c_cos8[(u * a + v * b2) & 7];
    }
  }
  sf[threadIdx.x] = acc * (1.f / 64.f);
  __syncthreads();
  // row m = tid = (a,b2): C[m][k] = s[(a-ka)&7][(b2-kb)&7]
  unsigned short* cp = cmat + (size_t)c * 4096 + threadIdx.x * 64;
  for (int k8 = 0; k8 < 64; k8 += 8) {
    float v[8];
    int ka = k8 >> 3;
    int ia = ((a - ka) & 7) * 8;
#pragma unroll
    for (int j = 0; j < 8; j++) v[j] = sf[ia + ((b2 - j) & 7)];
    store8bf(cp + k8, v);
  }
}

// ---------------------------------------------------------------------------
// DFFN spectral: z = C_c * y per patch, MFMA. Block = (b, c, strip py):
// 32 patches (N) x 64 elems (M=K=64). IN-PLACE on y.
__global__ __launch_bounds__(256) void k_patchconv_mfma(
    unsigned short* y, const unsigned short* __restrict__ cmat) {
  __shared__ __align__(16) short Bs[32 * 72];   // [patch][elem]
  __shared__ __align__(16) short As[64 * 72];   // [m][k] circulant
  int tid = threadIdx.x;
  unsigned bid = blockIdx.x;                 // b*288*32 + c*32 + py
  int py = (int)(bid & 31);
  int c = (int)((bid >> 5) % 288u);
  int b = (int)((bid >> 5) / 288u);
  unsigned short* yp = y + ((size_t)(b * 288 + c)) * HWC + py * 2048;
  {
    int rr = tid >> 5, seg = tid & 31;   // row rr of strip, patch seg
    *reinterpret_cast<uint4*>(Bs + seg * 72 + rr * 8) =
        *reinterpret_cast<const uint4*>(yp + rr * 256 + seg * 8);
  }
  {
    const unsigned short* cp = cmat + (size_t)c * 4096;
    int m = tid >> 2, kq = (tid & 3) * 16;
    *reinterpret_cast<uint4*>(As + m * 72 + kq) =
        *reinterpret_cast<const uint4*>(cp + m * 64 + kq);
    *reinterpret_cast<uint4*>(As + m * 72 + kq + 8) =
        *reinterpret_cast<const uint4*>(cp + m * 64 + kq + 8);
  }
  __syncthreads();
  int lane = tid & 63, wvi = tid >> 6;       // wvi = m-tile 0..3
  int quad = lane >> 4, mc = lane & 15;
  int kbase = quad * 8;
  short8 afr[2];
#pragma unroll
  for (int ks = 0; ks < 2; ks++)
    afr[ks] = *reinterpret_cast<const short8*>(
        As + (wvi * 16 + mc) * 72 + ks * 32 + kbase);
#pragma unroll
  for (int nt = 0; nt < 2; nt++) {
    short8 bfr[2];
#pragma unroll
    for (int ks = 0; ks < 2; ks++)
      bfr[ks] = *reinterpret_cast<const short8*>(
          Bs + (nt * 16 + mc) * 72 + ks * 32 + kbase);
    f32x4 acc = {0.f, 0.f, 0.f, 0.f};
#pragma unroll
    for (int ks = 0; ks < 2; ks++)
      acc = __builtin_amdgcn_mfma_f32_16x16x32_bf16(
          __builtin_bit_cast(bf16x8, afr[ks]),
          __builtin_bit_cast(bf16x8, bfr[ks]), acc, 0, 0, 0);
    // C/D: col = patch p = nt*16+mc; row m = wvi*16 + quad*4 + r
    int p = nt * 16 + mc;
    int m0 = wvi * 16 + quad * 4;
    int a = m0 >> 3, b8 = m0 & 7;            // 4 consecutive b at fixed a
    ushort4 pk;
    pk.x = f2bf(acc[0]); pk.y = f2bf(acc[1]);
    pk.z = f2bf(acc[2]); pk.w = f2bf(acc[3]);
    *reinterpret_cast<ushort4*>(yp + a * 256 + p * 8 + b8) = pk;
  }
}

// ---------------------------------------------------------------------------
// dwconv3 + exact GELU gate -> g bf16 (split g1[0:96) / g2[96:144)).
// LDS-free: per-thread 8px, halo via __shfl. Block=(b, c in [0,144), 8-row band).
__global__ __launch_bounds__(256) void k_ffn_gate(
    const unsigned short* __restrict__ z, const float* __restrict__ dwf,
    unsigned short* __restrict__ g1, unsigned short* __restrict__ g2) {
  int tid = threadIdx.x;
  unsigned bid = blockIdx.x;
  int y0 = (int)(bid & 31) * 8;
  unsigned t = bid >> 5;
  int c = (int)(t % 144u);
  int b = (int)(t / 144u);
  const unsigned short* zp1 = z + ((size_t)(b * 288 + c)) * HWC;
  const unsigned short* zp2 = z + ((size_t)(b * 288 + 144 + c)) * HWC;
  float w1[9], w2[9];
#pragma unroll
  for (int k = 0; k < 9; k++) {
    w1[k] = dwf[c * 9 + k];
    w2[k] = dwf[(144 + c) * 9 + k];
  }
  int r = tid >> 5, seg = tid & 31, lane = tid & 63;
  int y = y0 + r;
  float f1[3][8], f2[3][8];
#pragma unroll
  for (int dy = 0; dy < 3; dy++) {
    int yy = y + dy - 1;
    if (yy >= 0 && yy < 256) {
      load8f(zp1 + yy * 256 + seg * 8, f1[dy]);
      load8f(zp2 + yy * 256 + seg * 8, f2[dy]);
    } else {
#pragma unroll
      for (int j = 0; j < 8; j++) { f1[dy][j] = 0.f; f2[dy][j] = 0.f; }
    }
  }
  float d1[8], d2[8];
#pragma unroll
  for (int j = 0; j < 8; j++) { d1[j] = 0.f; d2[j] = 0.f; }
#pragma unroll
  for (int dy = 0; dy < 3; dy++) {
    float lv1 = __shfl(f1[dy][7], lane - 1, 64);
    float rv1 = __shfl(f1[dy][0], lane + 1, 64);
    float lv2 = __shfl(f2[dy][7], lane - 1, 64);
    float rv2 = __shfl(f2[dy][0], lane + 1, 64);
    if (seg == 0) { lv1 = 0.f; lv2 = 0.f; }
    if (seg == 31) { rv1 = 0.f; rv2 = 0.f; }
#pragma unroll
    for (int j = 0; j < 8; j++) {
      float xl1 = (j == 0) ? lv1 : f1[dy][j - 1];
      float xr1 = (j == 7) ? rv1 : f1[dy][j + 1];
      float xl2 = (j == 0) ? lv2 : f2[dy][j - 1];
      float xr2 = (j == 7) ? rv2 : f2[dy][j + 1];
      d1[j] += xl1 * w1[dy * 3] + f1[dy][j] * w1[dy * 3 + 1] + xr1 * w1[dy * 3 + 2];
      d2[j] += xl2 * w2[dy * 3] + f2[dy][j] * w2[dy * 3 + 1] + xr2 * w2[dy * 3 + 2];
    }
  }
  float o[8];
#pragma unroll
  for (int j = 0; j < 8; j++)
    o[j] = 0.5f * d1[j] * (1.f + erff(d1[j] * 0.70710678118654752f)) * d2[j];
  unsigned short* gp = (c < 96)
      ? g1 + ((size_t)(b * 96 + c)) * HWC
      : g2 + ((size_t)(b * 48 + (c - 96))) * HWC;
  store8bf(gp + y * 256 + seg * 8, o);
}

// ---------------------------------------------------------------------------
extern "C" void kernel_launch(void* const* d_in, const int* in_sizes, int n_in,
                              void* d_out, int out_size, void* d_ws,
                              size_t ws_size, hipStream_t stream) {
  (void)in_sizes; (void)n_in; (void)out_size; (void)ws_size;
  const float* x   = (const float*)d_in[0];
  const float* n1w = (const float*)d_in[1];
  const float* n1b = (const float*)d_in[2];
  const float* awh = (const float*)d_in[3];   // [288,48]
  const float* adw = (const float*)d_in[4];   // [288,1,3,3]
  const float* anw = (const float*)d_in[5];   // [96]
  const float* anb = (const float*)d_in[6];
  const float* awo = (const float*)d_in[7];   // [48,96]
  const float* n2w = (const float*)d_in[8];
  const float* n2b = (const float*)d_in[9];
  const float* fwi = (const float*)d_in[10];  // [288,48]
  const float* fff = (const float*)d_in[11];  // [288,1,1,8,5]
  const float* fdw = (const float*)d_in[12];  // [288,1,3,3]
  const float* fwo = (const float*)d_in[13];  // [48,144]

  unsigned short* QKV  = (unsigned short*)d_ws;                       // 75.5 MB
  unsigned short* U    = (unsigned short*)((char*)d_ws + 75497472);   // 25.2 MB
  unsigned short* X1   = (unsigned short*)((char*)d_ws + 100663296);  // 12.6 MB
  unsigned short* G2   = (unsigned short*)((char*)d_ws + 113246208);  // 12.6 MB
  unsigned short* CMAT = G2;  // 2.36 MB; dead before ffn_gate writes g2

  k_make_cmat<<<288, 64, 0, stream>>>(fff, CMAT);
  // FSAS: 3x (LN1+conv1x1 GEMM chunk -> dwconv3)
  for (int chunk = 0; chunk < 3; chunk++) {
    k_gemm<96, 48, 64, 1, 0><<<2048, 256, 0, stream>>>(
        awh + chunk * 96 * 48, x, nullptr, n1w, n1b, nullptr, U);
    k_dwconv3<<<2 * 96 * 32, 256, 0, stream>>>(U, adw, QKV, chunk * 96);
  }
  k_fsas_patchconv<<<2 * 96 * 32, 256, 0, stream>>>(QKV, U);
  // x1 = x + W_o * (LN(out96) * v)   [LN+gate fused in staging]
  k_gemm<48, 96, 96, 2, 1><<<2048, 256, 0, stream>>>(awo, U, QKV, anw, anb, x,
                                                     X1);
  // DFFN: y = W_in * LN(x1)  [LN fused]
  k_gemm<288, 48, 64, 3, 0><<<2048, 256, 0, stream>>>(fwi, X1, nullptr, n2w,
                                                      n2b, nullptr, QKV);
  // z = C_c * y per patch (MFMA circulant), in-place on QKV
  k_patchconv_mfma<<<2 * 288 * 32, 256, 0, stream>>>(QKV, CMAT);
  k_ffn_gate<<<2 * 144 * 32, 256, 0, stream>>>(QKV, fdw, U, G2);
  // out = x1 + W_out * g  (g split U/G2), fp32 output
  k_gemm<48, 144, 160, 0, 2><<<2048, 256, 0, stream>>>(fwo, U, G2, nullptr,
                                                       nullptr, X1,
                                                       (float*)d_out);
}

// Round 9
// 298.029 us; speedup vs baseline: 3.9644x; 1.1832x over previous
//
#include <hip/hip_runtime.h>
#include <hip/hip_bf16.h>
#include <cstddef>

// FFTformer block. FFTs reduced to 8x8 circular convolutions; conv1x1 GEMMs
// on MFMA (bf16 in, fp32 acc), LN/gate fused into GEMM staging, weights
// pre-converted to padded bf16 (A-fragments load straight from global).
// DFFN spectral filter = per-channel 64x64 circulant matmul on MFMA.
// Depthwise convs LDS-free (shuffle halo). B=2, d=48, H=W=256, P=8.
// Workspace layout (bytes), ws_size = 256 MiB:
//   [0,           75,497,472)  QKV bf16 [2,288,HW]  (qkv -> y -> z in-place)
//   [75,497,472, 150,994,944)  HID bf16 [2,288,HW]  (full hidden)
//   [150,994,944,176,160,768)  U   bf16 [2,96,HW]   (out96/u -> g1)
//   [176,160,768,188,743,680)  X1  bf16 [2,48,HW]
//   [188,743,680,201,326,592)  G2  bf16 [2,48,HW]   (CMAT 2.36MB until ffn_gate)
//   [201,326,592,201,424,896)  WPAD bf16 (awh64 | awo96 | fwi64 | fwo160)

constexpr int HWC = 65536;   // 256*256

typedef short short8 __attribute__((ext_vector_type(8)));
typedef __bf16 bf16x8 __attribute__((ext_vector_type(8)));
typedef float f32x4 __attribute__((ext_vector_type(4)));

__device__ inline unsigned short f2bf(float f) {
  __hip_bfloat16 h = __float2bfloat16(f);
  return *reinterpret_cast<unsigned short*>(&h);
}
__device__ inline float bf2f(unsigned short u) {
  __hip_bfloat16 h;
  *reinterpret_cast<unsigned short*>(&h) = u;
  return __bfloat162float(h);
}

union V8 { uint4 v; unsigned short us[8]; };

__device__ inline void load8f(const unsigned short* p, float* f) {
  V8 u; u.v = *reinterpret_cast<const uint4*>(p);
#pragma unroll
  for (int j = 0; j < 8; j++) f[j] = bf2f(u.us[j]);
}
__device__ inline void store8bf(unsigned short* p, const float* f) {
  V8 u;
#pragma unroll
  for (int j = 0; j < 8; j++) u.us[j] = f2bf(f[j]);
  *reinterpret_cast<uint4*>(p) = u.v;
}

// ---------------------------------------------------------------------------
// Pre-convert weights fp32 -> bf16, zero-padded rows (offsets in shorts):
// awh [288][48]->@0 [288][64]; awo [48][96]->@18432 [48][96];
// fwi [288][48]->@23040 [288][64]; fwo [48][144]->@41472 [48][160].
__global__ __launch_bounds__(64) void k_prep_w(
    const float* __restrict__ awh, const float* __restrict__ awo,
    const float* __restrict__ fwi, const float* __restrict__ fwo,
    unsigned short* __restrict__ wp) {
  int row = blockIdx.x, t = threadIdx.x;
  const float* src; int K, KP; unsigned short* dst;
  if (row < 288)      { src = awh + row * 48;        K = 48;  KP = 64;
                        dst = wp + row * 64; }
  else if (row < 336) { int r = row - 288; src = awo + r * 96; K = 96; KP = 96;
                        dst = wp + 18432 + r * 96; }
  else if (row < 624) { int r = row - 336; src = fwi + r * 48; K = 48; KP = 64;
                        dst = wp + 23040 + r * 64; }
  else                { int r = row - 624; src = fwo + r * 144; K = 144; KP = 160;
                        dst = wp + 41472 + r * 160; }
  for (int k = t; k < KP; k += 64) dst[k] = f2bf(k < K ? src[k] : 0.f);
}

// ---------------------------------------------------------------------------
// MFMA GEMM: out[M x N] = Wb[M x KP(bf16)] * X[K x N], 64 px/block, 2048 blocks.
// A-fragments load directly from global padded-bf16 weights (no W LDS).
// XF: 0 none (K split 96/48 across s1/s2), 1 = LN48 on fp32 s1,
//     2 = LN96 + v-gate (s1=u bf16, v=s2 qkv ch192+), 3 = LN48 on bf16 s1.
// EPI: 0 write bf16[M]; 1 += fp32 res -> bf16 (M=48); 2 += bf16 res -> fp32.
template <int M, int K, int KP, int XF, int EPI>
__global__ __launch_bounds__(256) void k_gemm(
    const unsigned short* __restrict__ wb, const void* __restrict__ s1,
    const unsigned short* __restrict__ s2, const float* __restrict__ lnw,
    const float* __restrict__ lnb, const void* __restrict__ res,
    void* __restrict__ out) {
  constexpr int STRIDE = KP + 8;
  constexpr int KS = KP / 32;
  constexpr int NT = (M + 63) / 64;
  __shared__ __align__(16) short Xs[64 * STRIDE];
  __shared__ __align__(16) short Vs[(XF == 2) ? 64 * STRIDE : 4];
  __shared__ float redS[4][64], redS2[4][64], mus[64], invs[64];

  int tid = threadIdx.x;
  unsigned bid = blockIdx.x;
  int b = (int)(bid >> 10);
  int hw0 = (int)(bid & 1023) * 64;

  // stage X transposed: Xs[col][k], vectorized over 4 consecutive px
  if (XF == 1) {
    const float* xp = (const float*)s1 + (size_t)b * 48 * HWC + hw0;
    for (int idx = tid; idx < 48 * 16; idx += 256) {
      int c = idx >> 4, colg = (idx & 15) * 4;
      float4 f = *reinterpret_cast<const float4*>(xp + (size_t)c * HWC + colg);
      Xs[(colg + 0) * STRIDE + c] = (short)f2bf(f.x);
      Xs[(colg + 1) * STRIDE + c] = (short)f2bf(f.y);
      Xs[(colg + 2) * STRIDE + c] = (short)f2bf(f.z);
      Xs[(colg + 3) * STRIDE + c] = (short)f2bf(f.w);
    }
  } else if (XF == 2) {
    const unsigned short* up =
        (const unsigned short*)s1 + (size_t)b * 96 * HWC + hw0;
    const unsigned short* vp = s2 + ((size_t)(b * 288 + 192)) * HWC + hw0;
    for (int idx = tid; idx < 96 * 16; idx += 256) {
      int c = idx >> 4, colg = (idx & 15) * 4;
      ushort4 uv = *reinterpret_cast<const ushort4*>(up + (size_t)c * HWC + colg);
      Xs[(colg + 0) * STRIDE + c] = (short)uv.x;
      Xs[(colg + 1) * STRIDE + c] = (short)uv.y;
      Xs[(colg + 2) * STRIDE + c] = (short)uv.z;
      Xs[(colg + 3) * STRIDE + c] = (short)uv.w;
      ushort4 vv = *reinterpret_cast<const ushort4*>(vp + (size_t)c * HWC + colg);
      Vs[(colg + 0) * STRIDE + c] = (short)vv.x;
      Vs[(colg + 1) * STRIDE + c] = (short)vv.y;
      Vs[(colg + 2) * STRIDE + c] = (short)vv.z;
      Vs[(colg + 3) * STRIDE + c] = (short)vv.w;
    }
  } else if (XF == 3) {
    const unsigned short* xp =
        (const unsigned short*)s1 + (size_t)b * 48 * HWC + hw0;
    for (int idx = tid; idx < 48 * 16; idx += 256) {
      int c = idx >> 4, colg = (idx & 15) * 4;
      ushort4 uv = *reinterpret_cast<const ushort4*>(xp + (size_t)c * HWC + colg);
      Xs[(colg + 0) * STRIDE + c] = (short)uv.x;
      Xs[(colg + 1) * STRIDE + c] = (short)uv.y;
      Xs[(colg + 2) * STRIDE + c] = (short)uv.z;
      Xs[(colg + 3) * STRIDE + c] = (short)uv.w;
    }
  } else {  // XF 0: K channels split s1[0:96) / s2[96:144)
    const unsigned short* p1 =
        (const unsigned short*)s1 + (size_t)b * 96 * HWC + hw0;
    const unsigned short* p2 = s2 + (size_t)b * 48 * HWC + hw0;
    for (int idx = tid; idx < K * 16; idx += 256) {
      int c = idx >> 4, colg = (idx & 15) * 4;
      const unsigned short* p =
          (c < 96) ? (p1 + (size_t)c * HWC + colg)
                   : (p2 + (size_t)(c - 96) * HWC + colg);
      ushort4 uv = *reinterpret_cast<const ushort4*>(p);
      Xs[(colg + 0) * STRIDE + c] = (short)uv.x;
      Xs[(colg + 1) * STRIDE + c] = (short)uv.y;
      Xs[(colg + 2) * STRIDE + c] = (short)uv.z;
      Xs[(colg + 3) * STRIDE + c] = (short)uv.w;
    }
  }

  // zero the K..KP pad rows of Xs
  if constexpr (KP > K) {
    constexpr int PAD = KP - K;
    for (int idx = tid; idx < 64 * PAD; idx += 256) {
      int col = idx / PAD, c = K + (idx % PAD);
      Xs[col * STRIDE + c] = 0;
    }
  }

  if (XF != 0) {
    constexpr int KC = (XF == 2) ? 96 : 48;
    __syncthreads();
    {
      int col = tid & 63, q = tid >> 6;
      float s = 0.f, s2 = 0.f;
      for (int c = q * (KC / 4); c < (q + 1) * (KC / 4); c++) {
        float v = bf2f((unsigned short)Xs[col * STRIDE + c]);
        s += v; s2 += v * v;
      }
      redS[q][col] = s; redS2[q][col] = s2;
    }
    __syncthreads();
    if (tid < 64) {
      float ss = redS[0][tid] + redS[1][tid] + redS[2][tid] + redS[3][tid];
      float ss2 = redS2[0][tid] + redS2[1][tid] + redS2[2][tid] + redS2[3][tid];
      float mu = ss * (1.f / KC);
      float var = ss2 * (1.f / KC) - mu * mu;
      mus[tid] = mu; invs[tid] = rsqrtf(var + 1e-5f);
    }
    __syncthreads();
    for (int idx = tid; idx < KC * 64; idx += 256) {
      int c = idx >> 6, col = idx & 63;
      float v = bf2f((unsigned short)Xs[col * STRIDE + c]);
      v = (v - mus[col]) * invs[col] * lnw[c] + lnb[c];
      if (XF == 2) v *= bf2f((unsigned short)Vs[col * STRIDE + c]);
      Xs[col * STRIDE + c] = (short)f2bf(v);
    }
  }
  __syncthreads();

  int lane = tid & 63, wvi = tid >> 6;
  int quad = lane >> 4, mc = lane & 15;
  int kbase = quad * 8;

  short8 bfr[4][KS];
#pragma unroll
  for (int ns = 0; ns < 4; ns++)
#pragma unroll
    for (int ks = 0; ks < KS; ks++)
      bfr[ns][ks] = *reinterpret_cast<const short8*>(
          Xs + (ns * 16 + mc) * STRIDE + ks * 32 + kbase);

#pragma unroll
  for (int t = 0; t < NT; t++) {
    int mb = (wvi + 4 * t) * 16;
    if (mb >= M) continue;
    short8 afr[KS];
#pragma unroll
    for (int ks = 0; ks < KS; ks++)
      afr[ks] = *reinterpret_cast<const short8*>(
          wb + (size_t)(mb + mc) * KP + ks * 32 + kbase);
#pragma unroll
    for (int ns = 0; ns < 4; ns++) {
      f32x4 acc = {0.f, 0.f, 0.f, 0.f};
#pragma unroll
      for (int ks = 0; ks < KS; ks++)
        acc = __builtin_amdgcn_mfma_f32_16x16x32_bf16(
            __builtin_bit_cast(bf16x8, afr[ks]),
            __builtin_bit_cast(bf16x8, bfr[ns][ks]), acc, 0, 0, 0);
      int hw = hw0 + ns * 16 + mc;
#pragma unroll
      for (int r = 0; r < 4; r++) {
        int m = mb + quad * 4 + r;
        if (EPI == 0) {
          ((unsigned short*)out)[((size_t)(b * M + m)) * HWC + hw] =
              f2bf(acc[r]);
        } else if (EPI == 1) {
          float rv = ((const float*)res)[((size_t)(b * 48 + m)) * HWC + hw];
          ((unsigned short*)out)[((size_t)(b * 48 + m)) * HWC + hw] =
              f2bf(rv + acc[r]);
        } else {
          float rv = bf2f(
              ((const unsigned short*)res)[((size_t)(b * 48 + m)) * HWC + hw]);
          ((float*)out)[((size_t)(b * 48 + m)) * HWC + hw] = rv + acc[r];
        }
      }
    }
  }
}

// ---------------------------------------------------------------------------
// depthwise 3x3 SAME over 288 channels, LDS-free (shuffle halo).
__global__ __launch_bounds__(256) void k_dwconv3(
    const unsigned short* __restrict__ in, const float* __restrict__ dw,
    unsigned short* __restrict__ out) {
  int tid = threadIdx.x;
  unsigned bid = blockIdx.x;
  int y0 = (int)(bid & 31) * 8;
  unsigned t = bid >> 5;
  int c = (int)(t % 288u);
  int b = (int)(t / 288u);
  const unsigned short* ip = in + ((size_t)(b * 288 + c)) * HWC;
  float wv[9];
#pragma unroll
  for (int k = 0; k < 9; k++) wv[k] = dw[c * 9 + k];
  int r = tid >> 5, seg = tid & 31, lane = tid & 63;
  int y = y0 + r;
  float f[3][8];
#pragma unroll
  for (int dy = 0; dy < 3; dy++) {
    int yy = y + dy - 1;
    if (yy >= 0 && yy < 256) {
      load8f(ip + yy * 256 + seg * 8, f[dy]);
    } else {
#pragma unroll
      for (int j = 0; j < 8; j++) f[dy][j] = 0.f;
    }
  }
  float o[8];
#pragma unroll
  for (int dy = 0; dy < 3; dy++) {
    float lv = __shfl(f[dy][7], lane - 1, 64);
    float rv = __shfl(f[dy][0], lane + 1, 64);
    if (seg == 0) lv = 0.f;
    if (seg == 31) rv = 0.f;
#pragma unroll
    for (int j = 0; j < 8; j++) {
      float xl = (j == 0) ? lv : f[dy][j - 1];
      float xr = (j == 7) ? rv : f[dy][j + 1];
      float v = xl * wv[dy * 3] + f[dy][j] * wv[dy * 3 + 1] + xr * wv[dy * 3 + 2];
      o[j] = (dy == 0) ? v : o[j] + v;
    }
  }
  store8bf(out + ((size_t)(b * 288 + c)) * HWC + y * 256 + seg * 8, o);
}

// ---------------------------------------------------------------------------
// FSAS spectral == per-patch 8x8 circular convolution q (*) k.
__global__ __launch_bounds__(256) void k_fsas_patchconv(
    const unsigned short* __restrict__ qkv, unsigned short* __restrict__ out) {
  __shared__ float qs[8][296];
  __shared__ float kt[8][296];
  int tid = threadIdx.x;
  unsigned bid = blockIdx.x;                 // b*96*32 + c*32 + py
  int py = (int)(bid & 31);
  int c = (int)((bid >> 5) % 96u);
  int b = (int)((bid >> 5) / 96u);
  const unsigned short* qp = qkv + ((size_t)(b * 288 + c)) * HWC + py * 2048;
  const unsigned short* kp =
      qkv + ((size_t)(b * 288 + 96 + c)) * HWC + py * 2048;
  {
    int rr = tid >> 5, seg = tid & 31;
    float fq[8], fk[8];
    load8f(qp + rr * 256 + seg * 8, fq);
    load8f(kp + rr * 256 + seg * 8, fk);
#pragma unroll
    for (int j = 0; j < 8; j++) {
      qs[rr][seg * 9 + j] = fq[j];
      kt[rr][seg * 9 + j] = fk[j];
    }
  }
  __syncthreads();
  int p = tid >> 3, a = tid & 7;
  float acc[8];
#pragma unroll
  for (int j = 0; j < 8; j++) acc[j] = 0.f;
#pragma unroll
  for (int i = 0; i < 8; i++) {
    float q8[8], k8[8];
#pragma unroll
    for (int j = 0; j < 8; j++) q8[j] = qs[i][p * 9 + j];
    int ar = (a - i) & 7;
#pragma unroll
    for (int j = 0; j < 8; j++) k8[j] = kt[ar][p * 9 + j];
#pragma unroll
    for (int j = 0; j < 8; j++)
#pragma unroll
      for (int bb = 0; bb < 8; bb++) acc[bb] += q8[j] * k8[(bb - j) & 7];
  }
  store8bf(out + ((size_t)(b * 96 + c)) * HWC + (py * 8 + a) * 256 + p * 8,
           acc);
}

// ---------------------------------------------------------------------------
// Cmat[c][m][k] (bf16): 64x64 circulant of s_c = irfft2(ffn_fft[c]) (numpy c2r
// semantics: v=0,4 columns symmetrized).
__device__ const float c_cos8[8] = {
    1.f, 0.70710678118654752f, 0.f, -0.70710678118654752f,
    -1.f, -0.70710678118654752f, 0.f, 0.70710678118654752f};

__global__ __launch_bounds__(64) void k_make_cmat(
    const float* __restrict__ fftw, unsigned short* __restrict__ cmat) {
  __shared__ float sf[64];
  int c = blockIdx.x;
  int a = threadIdx.x >> 3, b2 = threadIdx.x & 7;
  const float* W = fftw + c * 40;  // [8][5]
  float acc = 0.f;
  for (int u = 0; u < 8; u++) {
    for (int v = 0; v < 8; v++) {
      float wv;
      if (v <= 4) {
        if (v == 0 || v == 4)
          wv = 0.5f * (W[u * 5 + v] + W[((8 - u) & 7) * 5 + v]);
        else
          wv = W[u * 5 + v];
      } else {
        wv = W[((8 - u) & 7) * 5 + (8 - v)];
      }
      acc += wv * c_cos8[(u * a + v * b2) & 7];
    }
  }
  sf[threadIdx.x] = acc * (1.f / 64.f);
  __syncthreads();
  unsigned short* cp = cmat + (size_t)c * 4096 + threadIdx.x * 64;
  for (int k8 = 0; k8 < 64; k8 += 8) {
    float v[8];
    int ka = k8 >> 3;
    int ia = ((a - ka) & 7) * 8;
#pragma unroll
    for (int j = 0; j < 8; j++) v[j] = sf[ia + ((b2 - j) & 7)];
    store8bf(cp + k8, v);
  }
}

// ---------------------------------------------------------------------------
// DFFN spectral: z = C_c * y per patch, MFMA. IN-PLACE on y.
__global__ __launch_bounds__(256) void k_patchconv_mfma(
    unsigned short* y, const unsigned short* __restrict__ cmat) {
  __shared__ __align__(16) short Bs[32 * 72];
  __shared__ __align__(16) short As[64 * 72];
  int tid = threadIdx.x;
  unsigned bid = blockIdx.x;                 // b*288*32 + c*32 + py
  int py = (int)(bid & 31);
  int c = (int)((bid >> 5) % 288u);
  int b = (int)((bid >> 5) / 288u);
  unsigned short* yp = y + ((size_t)(b * 288 + c)) * HWC + py * 2048;
  {
    int rr = tid >> 5, seg = tid & 31;
    *reinterpret_cast<uint4*>(Bs + seg * 72 + rr * 8) =
        *reinterpret_cast<const uint4*>(yp + rr * 256 + seg * 8);
  }
  {
    const unsigned short* cp = cmat + (size_t)c * 4096;
    int m = tid >> 2, kq = (tid & 3) * 16;
    *reinterpret_cast<uint4*>(As + m * 72 + kq) =
        *reinterpret_cast<const uint4*>(cp + m * 64 + kq);
    *reinterpret_cast<uint4*>(As + m * 72 + kq + 8) =
        *reinterpret_cast<const uint4*>(cp + m * 64 + kq + 8);
  }
  __syncthreads();
  int lane = tid & 63, wvi = tid >> 6;
  int quad = lane >> 4, mc = lane & 15;
  int kbase = quad * 8;
  short8 afr[2];
#pragma unroll
  for (int ks = 0; ks < 2; ks++)
    afr[ks] = *reinterpret_cast<const short8*>(
        As + (wvi * 16 + mc) * 72 + ks * 32 + kbase);
#pragma unroll
  for (int nt = 0; nt < 2; nt++) {
    short8 bfr[2];
#pragma unroll
    for (int ks = 0; ks < 2; ks++)
      bfr[ks] = *reinterpret_cast<const short8*>(
          Bs + (nt * 16 + mc) * 72 + ks * 32 + kbase);
    f32x4 acc = {0.f, 0.f, 0.f, 0.f};
#pragma unroll
    for (int ks = 0; ks < 2; ks++)
      acc = __builtin_amdgcn_mfma_f32_16x16x32_bf16(
          __builtin_bit_cast(bf16x8, afr[ks]),
          __builtin_bit_cast(bf16x8, bfr[ks]), acc, 0, 0, 0);
    int p = nt * 16 + mc;
    int m0 = wvi * 16 + quad * 4;
    int a = m0 >> 3, b8 = m0 & 7;
    ushort4 pk;
    pk.x = f2bf(acc[0]); pk.y = f2bf(acc[1]);
    pk.z = f2bf(acc[2]); pk.w = f2bf(acc[3]);
    *reinterpret_cast<ushort4*>(yp + a * 256 + p * 8 + b8) = pk;
  }
}

// ---------------------------------------------------------------------------
// dwconv3 + exact GELU gate -> g bf16 (split g1[0:96) / g2[96:144)). LDS-free.
__global__ __launch_bounds__(256) void k_ffn_gate(
    const unsigned short* __restrict__ z, const float* __restrict__ dwf,
    unsigned short* __restrict__ g1, unsigned short* __restrict__ g2) {
  int tid = threadIdx.x;
  unsigned bid = blockIdx.x;
  int y0 = (int)(bid & 31) * 8;
  unsigned t = bid >> 5;
  int c = (int)(t % 144u);
  int b = (int)(t / 144u);
  const unsigned short* zp1 = z + ((size_t)(b * 288 + c)) * HWC;
  const unsigned short* zp2 = z + ((size_t)(b * 288 + 144 + c)) * HWC;
  float w1[9], w2[9];
#pragma unroll
  for (int k = 0; k < 9; k++) {
    w1[k] = dwf[c * 9 + k];
    w2[k] = dwf[(144 + c) * 9 + k];
  }
  int r = tid >> 5, seg = tid & 31, lane = tid & 63;
  int y = y0 + r;
  float f1[3][8], f2[3][8];
#pragma unroll
  for (int dy = 0; dy < 3; dy++) {
    int yy = y + dy - 1;
    if (yy >= 0 && yy < 256) {
      load8f(zp1 + yy * 256 + seg * 8, f1[dy]);
      load8f(zp2 + yy * 256 + seg * 8, f2[dy]);
    } else {
#pragma unroll
      for (int j = 0; j < 8; j++) { f1[dy][j] = 0.f; f2[dy][j] = 0.f; }
    }
  }
  float d1[8], d2[8];
#pragma unroll
  for (int j = 0; j < 8; j++) { d1[j] = 0.f; d2[j] = 0.f; }
#pragma unroll
  for (int dy = 0; dy < 3; dy++) {
    float lv1 = __shfl(f1[dy][7], lane - 1, 64);
    float rv1 = __shfl(f1[dy][0], lane + 1, 64);
    float lv2 = __shfl(f2[dy][7], lane - 1, 64);
    float rv2 = __shfl(f2[dy][0], lane + 1, 64);
    if (seg == 0) { lv1 = 0.f; lv2 = 0.f; }
    if (seg == 31) { rv1 = 0.f; rv2 = 0.f; }
#pragma unroll
    for (int j = 0; j < 8; j++) {
      float xl1 = (j == 0) ? lv1 : f1[dy][j - 1];
      float xr1 = (j == 7) ? rv1 : f1[dy][j + 1];
      float xl2 = (j == 0) ? lv2 : f2[dy][j - 1];
      float xr2 = (j == 7) ? rv2 : f2[dy][j + 1];
      d1[j] += xl1 * w1[dy * 3] + f1[dy][j] * w1[dy * 3 + 1] + xr1 * w1[dy * 3 + 2];
      d2[j] += xl2 * w2[dy * 3] + f2[dy][j] * w2[dy * 3 + 1] + xr2 * w2[dy * 3 + 2];
    }
  }
  float o[8];
#pragma unroll
  for (int j = 0; j < 8; j++)
    o[j] = 0.5f * d1[j] * (1.f + erff(d1[j] * 0.70710678118654752f)) * d2[j];
  unsigned short* gp = (c < 96)
      ? g1 + ((size_t)(b * 96 + c)) * HWC
      : g2 + ((size_t)(b * 48 + (c - 96))) * HWC;
  store8bf(gp + y * 256 + seg * 8, o);
}

// ---------------------------------------------------------------------------
extern "C" void kernel_launch(void* const* d_in, const int* in_sizes, int n_in,
                              void* d_out, int out_size, void* d_ws,
                              size_t ws_size, hipStream_t stream) {
  (void)in_sizes; (void)n_in; (void)out_size; (void)ws_size;
  const float* x   = (const float*)d_in[0];
  const float* n1w = (const float*)d_in[1];
  const float* n1b = (const float*)d_in[2];
  const float* awh = (const float*)d_in[3];   // [288,48]
  const float* adw = (const float*)d_in[4];   // [288,1,3,3]
  const float* anw = (const float*)d_in[5];   // [96]
  const float* anb = (const float*)d_in[6];
  const float* awo = (const float*)d_in[7];   // [48,96]
  const float* n2w = (const float*)d_in[8];
  const float* n2b = (const float*)d_in[9];
  const float* fwi = (const float*)d_in[10];  // [288,48]
  const float* fff = (const float*)d_in[11];  // [288,1,1,8,5]
  const float* fdw = (const float*)d_in[12];  // [288,1,3,3]
  const float* fwo = (const float*)d_in[13];  // [48,144]

  unsigned short* QKV  = (unsigned short*)d_ws;                       // 75.5 MB
  unsigned short* HID  = (unsigned short*)((char*)d_ws + 75497472);   // 75.5 MB
  unsigned short* U    = (unsigned short*)((char*)d_ws + 150994944);  // 25.2 MB
  unsigned short* X1   = (unsigned short*)((char*)d_ws + 176160768);  // 12.6 MB
  unsigned short* G2   = (unsigned short*)((char*)d_ws + 188743680);  // 12.6 MB
  unsigned short* CMAT = G2;  // 2.36 MB; dead before ffn_gate writes g2
  unsigned short* WP   = (unsigned short*)((char*)d_ws + 201326592);  // 96 KB
  unsigned short* WA = WP;             // awh padded [288][64]
  unsigned short* WO = WP + 18432;     // awo [48][96]
  unsigned short* WI = WP + 23040;     // fwi padded [288][64]
  unsigned short* WF = WP + 41472;     // fwo padded [48][160]

  k_prep_w<<<672, 64, 0, stream>>>(awh, awo, fwi, fwo, WP);
  k_make_cmat<<<288, 64, 0, stream>>>(fff, CMAT);
  // FSAS: hidden = W_h * LN1(x)  [LN fused], then dwconv3 -> qkv
  k_gemm<288, 48, 64, 1, 0><<<2048, 256, 0, stream>>>(WA, x, nullptr, n1w,
                                                      n1b, nullptr, HID);
  k_dwconv3<<<2 * 288 * 32, 256, 0, stream>>>(HID, adw, QKV);
  k_fsas_patchconv<<<2 * 96 * 32, 256, 0, stream>>>(QKV, U);
  // x1 = x + W_o * (LN(out96) * v)   [LN+gate fused in staging]
  k_gemm<48, 96, 96, 2, 1><<<2048, 256, 0, stream>>>(WO, U, QKV, anw, anb, x,
                                                     X1);
  // DFFN: y = W_in * LN(x1)  [LN fused]
  k_gemm<288, 48, 64, 3, 0><<<2048, 256, 0, stream>>>(WI, X1, nullptr, n2w,
                                                      n2b, nullptr, QKV);
  // z = C_c * y per patch (MFMA circulant), in-place
  k_patchconv_mfma<<<2 * 288 * 32, 256, 0, stream>>>(QKV, CMAT);
  k_ffn_gate<<<2 * 144 * 32, 256, 0, stream>>>(QKV, fdw, U, G2);
  // out = x1 + W_out * g  (g split U/G2), fp32 output
  k_gemm<48, 144, 160, 0, 2><<<2048, 256, 0, stream>>>(WF, U, G2, nullptr,
                                                       nullptr, X1,
                                                       (float*)d_out);
}

// Round 10
// 293.080 us; speedup vs baseline: 4.0313x; 1.0169x over previous
//
#include <hip/hip_runtime.h>
#include <hip/hip_bf16.h>
#include <cstddef>

// FFTformer block. FFTs reduced to 8x8 circular convolutions; conv1x1 GEMMs
// on MFMA (bf16 in, fp32 acc), LN/gate fused into GEMM staging, weights
// pre-converted to padded bf16 (A-frags from global), vectorized epilogue via
// LDS transpose (16B stores). FSAS dwconv(q,k) fused into the patchconv.
// DFFN spectral filter = per-channel 64x64 circulant matmul on MFMA.
// B=2, d=48, H=W=256, P=8.  Workspace (ws_size = 256 MiB):
//   [0,           75,497,472)  QKV bf16 [2,288,HW]  (v + later y -> z in-place)
//   [75,497,472, 150,994,944)  HID bf16 [2,288,HW]
//   [150,994,944,176,160,768)  U   bf16 [2,96,HW]   (out96/u -> g1)
//   [176,160,768,188,743,680)  X1  bf16 [2,48,HW]
//   [188,743,680,201,326,592)  G2  bf16 [2,48,HW]   (CMAT 2.36MB until ffn_gate)
//   [201,326,592,201,424,896)  WPAD bf16 (awh64 | awo96 | fwi64 | fwo160)

constexpr int HWC = 65536;   // 256*256

typedef short short8 __attribute__((ext_vector_type(8)));
typedef __bf16 bf16x8 __attribute__((ext_vector_type(8)));
typedef float f32x4 __attribute__((ext_vector_type(4)));

__device__ inline unsigned short f2bf(float f) {
  __hip_bfloat16 h = __float2bfloat16(f);
  return *reinterpret_cast<unsigned short*>(&h);
}
__device__ inline float bf2f(unsigned short u) {
  __hip_bfloat16 h;
  *reinterpret_cast<unsigned short*>(&h) = u;
  return __bfloat162float(h);
}

union V8 { uint4 v; unsigned short us[8]; short s[8]; };

__device__ inline void load8f(const unsigned short* p, float* f) {
  V8 u; u.v = *reinterpret_cast<const uint4*>(p);
#pragma unroll
  for (int j = 0; j < 8; j++) f[j] = bf2f(u.us[j]);
}
__device__ inline void store8bf(unsigned short* p, const float* f) {
  V8 u;
#pragma unroll
  for (int j = 0; j < 8; j++) u.us[j] = f2bf(f[j]);
  *reinterpret_cast<uint4*>(p) = u.v;
}

// ---------------------------------------------------------------------------
// Pre-convert weights fp32 -> bf16, zero-padded rows (offsets in shorts):
// awh [288][48]->@0 [288][64]; awo [48][96]->@18432; fwi [288][48]->@23040
// [288][64]; fwo [48][144]->@41472 [48][160].
__global__ __launch_bounds__(64) void k_prep_w(
    const float* __restrict__ awh, const float* __restrict__ awo,
    const float* __restrict__ fwi, const float* __restrict__ fwo,
    unsigned short* __restrict__ wp) {
  int row = blockIdx.x, t = threadIdx.x;
  const float* src; int K, KP; unsigned short* dst;
  if (row < 288)      { src = awh + row * 48;        K = 48;  KP = 64;
                        dst = wp + row * 64; }
  else if (row < 336) { int r = row - 288; src = awo + r * 96; K = 96; KP = 96;
                        dst = wp + 18432 + r * 96; }
  else if (row < 624) { int r = row - 336; src = fwi + r * 48; K = 48; KP = 64;
                        dst = wp + 23040 + r * 64; }
  else                { int r = row - 624; src = fwo + r * 144; K = 144; KP = 160;
                        dst = wp + 41472 + r * 160; }
  for (int k = t; k < KP; k += 64) dst[k] = f2bf(k < K ? src[k] : 0.f);
}

// ---------------------------------------------------------------------------
// MFMA GEMM: out[M x N] = Wb[M x KP(bf16)] * X[K x N], 64 px/block.
// XF: 0 none (K split 96/48 s1/s2), 1 LN48 fp32 s1, 2 LN96+v-gate, 3 LN48 bf16.
// EPI: 0 write bf16[M]; 1 += fp32 res -> bf16 (M=48); 2 += bf16 res -> fp32.
// Epilogue: accs -> LDS (reuse Xs) -> cooperative 16B stores.
template <int M, int K, int KP, int XF, int EPI>
__global__ __launch_bounds__(256) void k_gemm(
    const unsigned short* __restrict__ wb, const void* __restrict__ s1,
    const unsigned short* __restrict__ s2, const float* __restrict__ lnw,
    const float* __restrict__ lnb, const void* __restrict__ res,
    void* __restrict__ out) {
  constexpr int STRIDE = KP + 8;
  constexpr int KS = KP / 32;
  constexpr int NT = (M + 63) / 64;
  __shared__ __align__(16) short Xs[64 * STRIDE];   // staging, then epilogue
  __shared__ __align__(16) short Vs[(XF == 2) ? 64 * STRIDE : 4];
  __shared__ float redS[4][64], redS2[4][64], mus[64], invs[64];

  int tid = threadIdx.x;
  unsigned bid = blockIdx.x;
  int b = (int)(bid >> 10);
  int hw0 = (int)(bid & 1023) * 64;

  // stage X transposed: Xs[col][k]
  if (XF == 1) {
    const float* xp = (const float*)s1 + (size_t)b * 48 * HWC + hw0;
    for (int idx = tid; idx < 48 * 16; idx += 256) {
      int c = idx >> 4, colg = (idx & 15) * 4;
      float4 f = *reinterpret_cast<const float4*>(xp + (size_t)c * HWC + colg);
      Xs[(colg + 0) * STRIDE + c] = (short)f2bf(f.x);
      Xs[(colg + 1) * STRIDE + c] = (short)f2bf(f.y);
      Xs[(colg + 2) * STRIDE + c] = (short)f2bf(f.z);
      Xs[(colg + 3) * STRIDE + c] = (short)f2bf(f.w);
    }
  } else if (XF == 2) {
    const unsigned short* up =
        (const unsigned short*)s1 + (size_t)b * 96 * HWC + hw0;
    const unsigned short* vp = s2 + ((size_t)(b * 288 + 192)) * HWC + hw0;
    for (int idx = tid; idx < 96 * 16; idx += 256) {
      int c = idx >> 4, colg = (idx & 15) * 4;
      ushort4 uv = *reinterpret_cast<const ushort4*>(up + (size_t)c * HWC + colg);
      Xs[(colg + 0) * STRIDE + c] = (short)uv.x;
      Xs[(colg + 1) * STRIDE + c] = (short)uv.y;
      Xs[(colg + 2) * STRIDE + c] = (short)uv.z;
      Xs[(colg + 3) * STRIDE + c] = (short)uv.w;
      ushort4 vv = *reinterpret_cast<const ushort4*>(vp + (size_t)c * HWC + colg);
      Vs[(colg + 0) * STRIDE + c] = (short)vv.x;
      Vs[(colg + 1) * STRIDE + c] = (short)vv.y;
      Vs[(colg + 2) * STRIDE + c] = (short)vv.z;
      Vs[(colg + 3) * STRIDE + c] = (short)vv.w;
    }
  } else if (XF == 3) {
    const unsigned short* xp =
        (const unsigned short*)s1 + (size_t)b * 48 * HWC + hw0;
    for (int idx = tid; idx < 48 * 16; idx += 256) {
      int c = idx >> 4, colg = (idx & 15) * 4;
      ushort4 uv = *reinterpret_cast<const ushort4*>(xp + (size_t)c * HWC + colg);
      Xs[(colg + 0) * STRIDE + c] = (short)uv.x;
      Xs[(colg + 1) * STRIDE + c] = (short)uv.y;
      Xs[(colg + 2) * STRIDE + c] = (short)uv.z;
      Xs[(colg + 3) * STRIDE + c] = (short)uv.w;
    }
  } else {
    const unsigned short* p1 =
        (const unsigned short*)s1 + (size_t)b * 96 * HWC + hw0;
    const unsigned short* p2 = s2 + (size_t)b * 48 * HWC + hw0;
    for (int idx = tid; idx < K * 16; idx += 256) {
      int c = idx >> 4, colg = (idx & 15) * 4;
      const unsigned short* p =
          (c < 96) ? (p1 + (size_t)c * HWC + colg)
                   : (p2 + (size_t)(c - 96) * HWC + colg);
      ushort4 uv = *reinterpret_cast<const ushort4*>(p);
      Xs[(colg + 0) * STRIDE + c] = (short)uv.x;
      Xs[(colg + 1) * STRIDE + c] = (short)uv.y;
      Xs[(colg + 2) * STRIDE + c] = (short)uv.z;
      Xs[(colg + 3) * STRIDE + c] = (short)uv.w;
    }
  }

  if constexpr (KP > K) {
    constexpr int PAD = KP - K;
    for (int idx = tid; idx < 64 * PAD; idx += 256) {
      int col = idx / PAD, c = K + (idx % PAD);
      Xs[col * STRIDE + c] = 0;
    }
  }

  if (XF != 0) {
    constexpr int KC = (XF == 2) ? 96 : 48;
    __syncthreads();
    {
      int col = tid & 63, q = tid >> 6;
      float s = 0.f, s2 = 0.f;
      for (int c = q * (KC / 4); c < (q + 1) * (KC / 4); c++) {
        float v = bf2f((unsigned short)Xs[col * STRIDE + c]);
        s += v; s2 += v * v;
      }
      redS[q][col] = s; redS2[q][col] = s2;
    }
    __syncthreads();
    if (tid < 64) {
      float ss = redS[0][tid] + redS[1][tid] + redS[2][tid] + redS[3][tid];
      float ss2 = redS2[0][tid] + redS2[1][tid] + redS2[2][tid] + redS2[3][tid];
      float mu = ss * (1.f / KC);
      float var = ss2 * (1.f / KC) - mu * mu;
      mus[tid] = mu; invs[tid] = rsqrtf(var + 1e-5f);
    }
    __syncthreads();
    for (int idx = tid; idx < KC * 64; idx += 256) {
      int c = idx >> 6, col = idx & 63;
      float v = bf2f((unsigned short)Xs[col * STRIDE + c]);
      v = (v - mus[col]) * invs[col] * lnw[c] + lnb[c];
      if (XF == 2) v *= bf2f((unsigned short)Vs[col * STRIDE + c]);
      Xs[col * STRIDE + c] = (short)f2bf(v);
    }
  }
  __syncthreads();

  int lane = tid & 63, wvi = tid >> 6;
  int quad = lane >> 4, mc = lane & 15;
  int kbase = quad * 8;

  // B fragments to registers (Xs free for epilogue reuse afterwards)
  short8 bfr[4][KS];
#pragma unroll
  for (int ns = 0; ns < 4; ns++)
#pragma unroll
    for (int ks = 0; ks < KS; ks++)
      bfr[ns][ks] = *reinterpret_cast<const short8*>(
          Xs + (ns * 16 + mc) * STRIDE + ks * 32 + kbase);

  short* Es = Xs;   // epilogue tile [64ch][72]
#pragma unroll
  for (int t = 0; t < NT; t++) {
    int mb = (wvi + 4 * t) * 16;
    f32x4 accs[4];
    if (mb < M) {
      short8 afr[KS];
#pragma unroll
      for (int ks = 0; ks < KS; ks++)
        afr[ks] = *reinterpret_cast<const short8*>(
            wb + (size_t)(mb + mc) * KP + ks * 32 + kbase);
#pragma unroll
      for (int ns = 0; ns < 4; ns++) {
        f32x4 acc = {0.f, 0.f, 0.f, 0.f};
#pragma unroll
        for (int ks = 0; ks < KS; ks++)
          acc = __builtin_amdgcn_mfma_f32_16x16x32_bf16(
              __builtin_bit_cast(bf16x8, afr[ks]),
              __builtin_bit_cast(bf16x8, bfr[ns][ks]), acc, 0, 0, 0);
        accs[ns] = acc;
      }
    }
    __syncthreads();   // Xs free / previous writeback done
    if (mb < M) {
      int chl = wvi * 16 + quad * 4;
#pragma unroll
      for (int ns = 0; ns < 4; ns++)
#pragma unroll
        for (int r = 0; r < 4; r++)
          Es[(chl + r) * 72 + ns * 16 + mc] = (short)f2bf(accs[ns][r]);
    }
    __syncthreads();
#pragma unroll
    for (int i = 0; i < 2; i++) {
      int chl = (tid >> 3) + 32 * i;
      int px0 = (tid & 7) * 8;
      int m = 64 * t + chl;
      if (m < M) {
        V8 ev;
        ev.v = *reinterpret_cast<const uint4*>(Es + chl * 72 + px0);
        size_t off = ((size_t)(b * ((EPI == 0) ? M : 48) + m)) * HWC + hw0 + px0;
        if (EPI == 0) {
          *reinterpret_cast<uint4*>((unsigned short*)out + off) = ev.v;
        } else if (EPI == 1) {
          const float* rp = (const float*)res + off;
          float4 ra = *reinterpret_cast<const float4*>(rp);
          float4 rb = *reinterpret_cast<const float4*>(rp + 4);
          V8 pk;
          pk.us[0] = f2bf(ra.x + bf2f(ev.us[0]));
          pk.us[1] = f2bf(ra.y + bf2f(ev.us[1]));
          pk.us[2] = f2bf(ra.z + bf2f(ev.us[2]));
          pk.us[3] = f2bf(ra.w + bf2f(ev.us[3]));
          pk.us[4] = f2bf(rb.x + bf2f(ev.us[4]));
          pk.us[5] = f2bf(rb.y + bf2f(ev.us[5]));
          pk.us[6] = f2bf(rb.z + bf2f(ev.us[6]));
          pk.us[7] = f2bf(rb.w + bf2f(ev.us[7]));
          *reinterpret_cast<uint4*>((unsigned short*)out + off) = pk.v;
        } else {
          V8 rv;
          rv.v = *reinterpret_cast<const uint4*>((const unsigned short*)res + off);
          float* op = (float*)out + off;
          float4 oa, ob;
          oa.x = bf2f(rv.us[0]) + bf2f(ev.us[0]);
          oa.y = bf2f(rv.us[1]) + bf2f(ev.us[1]);
          oa.z = bf2f(rv.us[2]) + bf2f(ev.us[2]);
          oa.w = bf2f(rv.us[3]) + bf2f(ev.us[3]);
          ob.x = bf2f(rv.us[4]) + bf2f(ev.us[4]);
          ob.y = bf2f(rv.us[5]) + bf2f(ev.us[5]);
          ob.z = bf2f(rv.us[6]) + bf2f(ev.us[6]);
          ob.w = bf2f(rv.us[7]) + bf2f(ev.us[7]);
          *reinterpret_cast<float4*>(op) = oa;
          *reinterpret_cast<float4*>(op + 4) = ob;
        }
      }
    }
  }
}

// ---------------------------------------------------------------------------
// depthwise 3x3 SAME for the 96 v-channels (192..287), LDS-free.
__global__ __launch_bounds__(256) void k_dwconv3v(
    const unsigned short* __restrict__ in, const float* __restrict__ dw,
    unsigned short* __restrict__ out) {
  int tid = threadIdx.x;
  unsigned bid = blockIdx.x;
  int y0 = (int)(bid & 31) * 8;
  unsigned t = bid >> 5;
  int c = 192 + (int)(t % 96u);
  int b = (int)(t / 96u);
  const unsigned short* ip = in + ((size_t)(b * 288 + c)) * HWC;
  float wv[9];
#pragma unroll
  for (int k = 0; k < 9; k++) wv[k] = dw[c * 9 + k];
  int r = tid >> 5, seg = tid & 31, lane = tid & 63;
  int y = y0 + r;
  float f[3][8];
#pragma unroll
  for (int dy = 0; dy < 3; dy++) {
    int yy = y + dy - 1;
    if (yy >= 0 && yy < 256) {
      load8f(ip + yy * 256 + seg * 8, f[dy]);
    } else {
#pragma unroll
      for (int j = 0; j < 8; j++) f[dy][j] = 0.f;
    }
  }
  float o[8];
#pragma unroll
  for (int dy = 0; dy < 3; dy++) {
    float lv = __shfl(f[dy][7], lane - 1, 64);
    float rv = __shfl(f[dy][0], lane + 1, 64);
    if (seg == 0) lv = 0.f;
    if (seg == 31) rv = 0.f;
#pragma unroll
    for (int j = 0; j < 8; j++) {
      float xl = (j == 0) ? lv : f[dy][j - 1];
      float xr = (j == 7) ? rv : f[dy][j + 1];
      float v = xl * wv[dy * 3] + f[dy][j] * wv[dy * 3 + 1] + xr * wv[dy * 3 + 2];
      o[j] = (dy == 0) ? v : o[j] + v;
    }
  }
  store8bf(out + ((size_t)(b * 288 + c)) * HWC + y * 256 + seg * 8, o);
}

// ---------------------------------------------------------------------------
// FSAS fused: dwconv3(hidden) for q,k computed on the fly (shuffle halo,
// strips are full-width so halo is vertical only), then per-patch 8x8
// circular convolution q (*) k. Stride-9 LDS groups (conflict-free).
__global__ __launch_bounds__(256) void k_fsas_fused(
    const unsigned short* __restrict__ hid, const float* __restrict__ dw,
    unsigned short* __restrict__ out) {
  __shared__ float qs[8][296];
  __shared__ float kt[8][296];
  int tid = threadIdx.x;
  unsigned bid = blockIdx.x;                 // b*96*32 + c*32 + py
  int py = (int)(bid & 31);
  int c = (int)((bid >> 5) % 96u);
  int b = (int)((bid >> 5) / 96u);
  const unsigned short* qp = hid + ((size_t)(b * 288 + c)) * HWC;
  const unsigned short* kp = hid + ((size_t)(b * 288 + 96 + c)) * HWC;
  float w1[9], w2[9];
#pragma unroll
  for (int k = 0; k < 9; k++) {
    w1[k] = dw[c * 9 + k];
    w2[k] = dw[(96 + c) * 9 + k];
  }
  int r = tid >> 5, seg = tid & 31, lane = tid & 63;
  int y = py * 8 + r;
  float f1[3][8], f2[3][8];
#pragma unroll
  for (int dy = 0; dy < 3; dy++) {
    int yy = y + dy - 1;
    if (yy >= 0 && yy < 256) {
      load8f(qp + yy * 256 + seg * 8, f1[dy]);
      load8f(kp + yy * 256 + seg * 8, f2[dy]);
    } else {
#pragma unroll
      for (int j = 0; j < 8; j++) { f1[dy][j] = 0.f; f2[dy][j] = 0.f; }
    }
  }
  float d1[8], d2[8];
#pragma unroll
  for (int j = 0; j < 8; j++) { d1[j] = 0.f; d2[j] = 0.f; }
#pragma unroll
  for (int dy = 0; dy < 3; dy++) {
    float lv1 = __shfl(f1[dy][7], lane - 1, 64);
    float rv1 = __shfl(f1[dy][0], lane + 1, 64);
    float lv2 = __shfl(f2[dy][7], lane - 1, 64);
    float rv2 = __shfl(f2[dy][0], lane + 1, 64);
    if (seg == 0) { lv1 = 0.f; lv2 = 0.f; }
    if (seg == 31) { rv1 = 0.f; rv2 = 0.f; }
#pragma unroll
    for (int j = 0; j < 8; j++) {
      float xl1 = (j == 0) ? lv1 : f1[dy][j - 1];
      float xr1 = (j == 7) ? rv1 : f1[dy][j + 1];
      float xl2 = (j == 0) ? lv2 : f2[dy][j - 1];
      float xr2 = (j == 7) ? rv2 : f2[dy][j + 1];
      d1[j] += xl1 * w1[dy * 3] + f1[dy][j] * w1[dy * 3 + 1] + xr1 * w1[dy * 3 + 2];
      d2[j] += xl2 * w2[dy * 3] + f2[dy][j] * w2[dy * 3 + 1] + xr2 * w2[dy * 3 + 2];
    }
  }
#pragma unroll
  for (int j = 0; j < 8; j++) {
    qs[r][seg * 9 + j] = d1[j];
    kt[r][seg * 9 + j] = d2[j];
  }
  __syncthreads();
  int p = tid >> 3, a = tid & 7;
  float acc[8];
#pragma unroll
  for (int j = 0; j < 8; j++) acc[j] = 0.f;
#pragma unroll
  for (int i = 0; i < 8; i++) {
    float q8[8], k8[8];
#pragma unroll
    for (int j = 0; j < 8; j++) q8[j] = qs[i][p * 9 + j];
    int ar = (a - i) & 7;
#pragma unroll
    for (int j = 0; j < 8; j++) k8[j] = kt[ar][p * 9 + j];
#pragma unroll
    for (int j = 0; j < 8; j++)
#pragma unroll
      for (int bb = 0; bb < 8; bb++) acc[bb] += q8[j] * k8[(bb - j) & 7];
  }
  store8bf(out + ((size_t)(b * 96 + c)) * HWC + (py * 8 + a) * 256 + p * 8,
           acc);
}

// ---------------------------------------------------------------------------
// Cmat[c][m][k] (bf16): 64x64 circulant of s_c = irfft2(ffn_fft[c]) (numpy c2r
// semantics: v=0,4 columns symmetrized).
__device__ const float c_cos8[8] = {
    1.f, 0.70710678118654752f, 0.f, -0.70710678118654752f,
    -1.f, -0.70710678118654752f, 0.f, 0.70710678118654752f};

__global__ __launch_bounds__(64) void k_make_cmat(
    const float* __restrict__ fftw, unsigned short* __restrict__ cmat) {
  __shared__ float sf[64];
  int c = blockIdx.x;
  int a = threadIdx.x >> 3, b2 = threadIdx.x & 7;
  const float* W = fftw + c * 40;  // [8][5]
  float acc = 0.f;
  for (int u = 0; u < 8; u++) {
    for (int v = 0; v < 8; v++) {
      float wv;
      if (v <= 4) {
        if (v == 0 || v == 4)
          wv = 0.5f * (W[u * 5 + v] + W[((8 - u) & 7) * 5 + v]);
        else
          wv = W[u * 5 + v];
      } else {
        wv = W[((8 - u) & 7) * 5 + (8 - v)];
      }
      acc += wv * c_cos8[(u * a + v * b2) & 7];
    }
  }
  sf[threadIdx.x] = acc * (1.f / 64.f);
  __syncthreads();
  unsigned short* cp = cmat + (size_t)c * 4096 + threadIdx.x * 64;
  for (int k8 = 0; k8 < 64; k8 += 8) {
    float v[8];
    int ka = k8 >> 3;
    int ia = ((a - ka) & 7) * 8;
#pragma unroll
    for (int j = 0; j < 8; j++) v[j] = sf[ia + ((b2 - j) & 7)];
    store8bf(cp + k8, v);
  }
}

// ---------------------------------------------------------------------------
// DFFN spectral: z = C_c * y per patch, MFMA. IN-PLACE on y.
__global__ __launch_bounds__(256) void k_patchconv_mfma(
    unsigned short* y, const unsigned short* __restrict__ cmat) {
  __shared__ __align__(16) short Bs[32 * 72];
  __shared__ __align__(16) short As[64 * 72];
  int tid = threadIdx.x;
  unsigned bid = blockIdx.x;                 // b*288*32 + c*32 + py
  int py = (int)(bid & 31);
  int c = (int)((bid >> 5) % 288u);
  int b = (int)((bid >> 5) / 288u);
  unsigned short* yp = y + ((size_t)(b * 288 + c)) * HWC + py * 2048;
  {
    int rr = tid >> 5, seg = tid & 31;
    *reinterpret_cast<uint4*>(Bs + seg * 72 + rr * 8) =
        *reinterpret_cast<const uint4*>(yp + rr * 256 + seg * 8);
  }
  {
    const unsigned short* cp = cmat + (size_t)c * 4096;
    int m = tid >> 2, kq = (tid & 3) * 16;
    *reinterpret_cast<uint4*>(As + m * 72 + kq) =
        *reinterpret_cast<const uint4*>(cp + m * 64 + kq);
    *reinterpret_cast<uint4*>(As + m * 72 + kq + 8) =
        *reinterpret_cast<const uint4*>(cp + m * 64 + kq + 8);
  }
  __syncthreads();
  int lane = tid & 63, wvi = tid >> 6;
  int quad = lane >> 4, mc = lane & 15;
  int kbase = quad * 8;
  short8 afr[2];
#pragma unroll
  for (int ks = 0; ks < 2; ks++)
    afr[ks] = *reinterpret_cast<const short8*>(
        As + (wvi * 16 + mc) * 72 + ks * 32 + kbase);
#pragma unroll
  for (int nt = 0; nt < 2; nt++) {
    short8 bfr[2];
#pragma unroll
    for (int ks = 0; ks < 2; ks++)
      bfr[ks] = *reinterpret_cast<const short8*>(
          Bs + (nt * 16 + mc) * 72 + ks * 32 + kbase);
    f32x4 acc = {0.f, 0.f, 0.f, 0.f};
#pragma unroll
    for (int ks = 0; ks < 2; ks++)
      acc = __builtin_amdgcn_mfma_f32_16x16x32_bf16(
          __builtin_bit_cast(bf16x8, afr[ks]),
          __builtin_bit_cast(bf16x8, bfr[ks]), acc, 0, 0, 0);
    int p = nt * 16 + mc;
    int m0 = wvi * 16 + quad * 4;
    int a = m0 >> 3, b8 = m0 & 7;
    ushort4 pk;
    pk.x = f2bf(acc[0]); pk.y = f2bf(acc[1]);
    pk.z = f2bf(acc[2]); pk.w = f2bf(acc[3]);
    *reinterpret_cast<ushort4*>(yp + a * 256 + p * 8 + b8) = pk;
  }
}

// ---------------------------------------------------------------------------
// dwconv3 + exact GELU gate -> g bf16 (split g1[0:96) / g2[96:144)). LDS-free.
__global__ __launch_bounds__(256) void k_ffn_gate(
    const unsigned short* __restrict__ z, const float* __restrict__ dwf,
    unsigned short* __restrict__ g1, unsigned short* __restrict__ g2) {
  int tid = threadIdx.x;
  unsigned bid = blockIdx.x;
  int y0 = (int)(bid & 31) * 8;
  unsigned t = bid >> 5;
  int c = (int)(t % 144u);
  int b = (int)(t / 144u);
  const unsigned short* zp1 = z + ((size_t)(b * 288 + c)) * HWC;
  const unsigned short* zp2 = z + ((size_t)(b * 288 + 144 + c)) * HWC;
  float w1[9], w2[9];
#pragma unroll
  for (int k = 0; k < 9; k++) {
    w1[k] = dwf[c * 9 + k];
    w2[k] = dwf[(144 + c) * 9 + k];
  }
  int r = tid >> 5, seg = tid & 31, lane = tid & 63;
  int y = y0 + r;
  float f1[3][8], f2[3][8];
#pragma unroll
  for (int dy = 0; dy < 3; dy++) {
    int yy = y + dy - 1;
    if (yy >= 0 && yy < 256) {
      load8f(zp1 + yy * 256 + seg * 8, f1[dy]);
      load8f(zp2 + yy * 256 + seg * 8, f2[dy]);
    } else {
#pragma unroll
      for (int j = 0; j < 8; j++) { f1[dy][j] = 0.f; f2[dy][j] = 0.f; }
    }
  }
  float d1[8], d2[8];
#pragma unroll
  for (int j = 0; j < 8; j++) { d1[j] = 0.f; d2[j] = 0.f; }
#pragma unroll
  for (int dy = 0; dy < 3; dy++) {
    float lv1 = __shfl(f1[dy][7], lane - 1, 64);
    float rv1 = __shfl(f1[dy][0], lane + 1, 64);
    float lv2 = __shfl(f2[dy][7], lane - 1, 64);
    float rv2 = __shfl(f2[dy][0], lane + 1, 64);
    if (seg == 0) { lv1 = 0.f; lv2 = 0.f; }
    if (seg == 31) { rv1 = 0.f; rv2 = 0.f; }
#pragma unroll
    for (int j = 0; j < 8; j++) {
      float xl1 = (j == 0) ? lv1 : f1[dy][j - 1];
      float xr1 = (j == 7) ? rv1 : f1[dy][j + 1];
      float xl2 = (j == 0) ? lv2 : f2[dy][j - 1];
      float xr2 = (j == 7) ? rv2 : f2[dy][j + 1];
      d1[j] += xl1 * w1[dy * 3] + f1[dy][j] * w1[dy * 3 + 1] + xr1 * w1[dy * 3 + 2];
      d2[j] += xl2 * w2[dy * 3] + f2[dy][j] * w2[dy * 3 + 1] + xr2 * w2[dy * 3 + 2];
    }
  }
  float o[8];
#pragma unroll
  for (int j = 0; j < 8; j++)
    o[j] = 0.5f * d1[j] * (1.f + erff(d1[j] * 0.70710678118654752f)) * d2[j];
  unsigned short* gp = (c < 96)
      ? g1 + ((size_t)(b * 96 + c)) * HWC
      : g2 + ((size_t)(b * 48 + (c - 96))) * HWC;
  store8bf(gp + y * 256 + seg * 8, o);
}

// ---------------------------------------------------------------------------
extern "C" void kernel_launch(void* const* d_in, const int* in_sizes, int n_in,
                              void* d_out, int out_size, void* d_ws,
                              size_t ws_size, hipStream_t stream) {
  (void)in_sizes; (void)n_in; (void)out_size; (void)ws_size;
  const float* x   = (const float*)d_in[0];
  const float* n1w = (const float*)d_in[1];
  const float* n1b = (const float*)d_in[2];
  const float* awh = (const float*)d_in[3];   // [288,48]
  const float* adw = (const float*)d_in[4];   // [288,1,3,3]
  const float* anw = (const float*)d_in[5];   // [96]
  const float* anb = (const float*)d_in[6];
  const float* awo = (const float*)d_in[7];   // [48,96]
  const float* n2w = (const float*)d_in[8];
  const float* n2b = (const float*)d_in[9];
  const float* fwi = (const float*)d_in[10];  // [288,48]
  const float* fff = (const float*)d_in[11];  // [288,1,1,8,5]
  const float* fdw = (const float*)d_in[12];  // [288,1,3,3]
  const float* fwo = (const float*)d_in[13];  // [48,144]

  unsigned short* QKV  = (unsigned short*)d_ws;                       // 75.5 MB
  unsigned short* HID  = (unsigned short*)((char*)d_ws + 75497472);   // 75.5 MB
  unsigned short* U    = (unsigned short*)((char*)d_ws + 150994944);  // 25.2 MB
  unsigned short* X1   = (unsigned short*)((char*)d_ws + 176160768);  // 12.6 MB
  unsigned short* G2   = (unsigned short*)((char*)d_ws + 188743680);  // 12.6 MB
  unsigned short* CMAT = G2;  // 2.36 MB; dead before ffn_gate writes g2
  unsigned short* WP   = (unsigned short*)((char*)d_ws + 201326592);  // 96 KB
  unsigned short* WA = WP;             // awh padded [288][64]
  unsigned short* WO = WP + 18432;     // awo [48][96]
  unsigned short* WI = WP + 23040;     // fwi padded [288][64]
  unsigned short* WF = WP + 41472;     // fwo padded [48][160]

  k_prep_w<<<672, 64, 0, stream>>>(awh, awo, fwi, fwo, WP);
  k_make_cmat<<<288, 64, 0, stream>>>(fff, CMAT);
  // FSAS: hidden = W_h * LN1(x)  [LN fused]
  k_gemm<288, 48, 64, 1, 0><<<2048, 256, 0, stream>>>(WA, x, nullptr, n1w,
                                                      n1b, nullptr, HID);
  k_dwconv3v<<<2 * 96 * 32, 256, 0, stream>>>(HID, adw, QKV);      // v only
  k_fsas_fused<<<2 * 96 * 32, 256, 0, stream>>>(HID, adw, U);      // q,k fused
  // x1 = x + W_o * (LN(out96) * v)   [LN+gate fused in staging]
  k_gemm<48, 96, 96, 2, 1><<<2048, 256, 0, stream>>>(WO, U, QKV, anw, anb, x,
                                                     X1);
  // DFFN: y = W_in * LN(x1)  [LN fused]
  k_gemm<288, 48, 64, 3, 0><<<2048, 256, 0, stream>>>(WI, X1, nullptr, n2w,
                                                      n2b, nullptr, QKV);
  // z = C_c * y per patch (MFMA circulant), in-place
  k_patchconv_mfma<<<2 * 288 * 32, 256, 0, stream>>>(QKV, CMAT);
  k_ffn_gate<<<2 * 144 * 32, 256, 0, stream>>>(QKV, fdw, U, G2);
  // out = x1 + W_out * g  (g split U/G2), fp32 output
  k_gemm<48, 144, 160, 0, 2><<<2048, 256, 0, stream>>>(WF, U, G2, nullptr,
                                                       nullptr, X1,
                                                       (float*)d_out);
}